// Round 1
// baseline (1765.597 us; speedup 1.0000x reference)
//
#include <hip/hip_runtime.h>
#include <cfloat>

#define NBATCH 8
#define NPTS   4096
#define KNN    16

__device__ __forceinline__ float relu_f(float x) { return x > 0.f ? x : 0.f; }

// ---------------------------------------------------------------------------
// K1: KNN top-16 (self-inclusive), stable ties -> lower index (lax.top_k)
// grid (NPTS/64, NBATCH), block 256 = 64 points x 4 j-slices
// ---------------------------------------------------------------------------
__global__ __launch_bounds__(256)
void knn_kernel(const float* __restrict__ pts, int* __restrict__ idxout)
{
    __shared__ float4 sp[NPTS];   // 64KB: (x,y,z,xx); aliased for merge later
    const int b   = blockIdx.y;
    const int tid = threadIdx.x;
    const float* pb = pts + (size_t)b * 3 * NPTS;

    for (int j = tid; j < NPTS; j += 256) {
        float x = pb[j], y = pb[NPTS + j], z = pb[2 * NPTS + j];
        float xx = __fadd_rn(__fadd_rn(__fmul_rn(x, x), __fmul_rn(y, y)), __fmul_rn(z, z));
        sp[j] = make_float4(x, y, z, xx);
    }
    __syncthreads();

    const int ptl = tid >> 2;            // local point 0..63
    const int r   = tid & 3;             // j-slice
    const int n   = blockIdx.x * 64 + ptl;
    const float4 self = sp[n];
    const float negxx = -self.w;

    float bd[16]; int bi[16];
#pragma unroll
    for (int s = 0; s < 16; ++s) { bd[s] = -FLT_MAX; bi[s] = 0; }

    const int j0 = r * (NPTS / 4);
    for (int j = j0; j < j0 + NPTS / 4; ++j) {
        float4 c = sp[j];
        float dot = __fadd_rn(__fadd_rn(__fmul_rn(self.x, c.x), __fmul_rn(self.y, c.y)),
                              __fmul_rn(self.z, c.z));
        float inner = __fmul_rn(-2.f, dot);
        float pd = __fsub_rn(__fsub_rn(negxx, inner), c.w);
        if (pd > bd[15]) {
            // unrolled stable insertion: original bd[s-1]/bd[s] read each step
#pragma unroll
            for (int s = 15; s >= 1; --s) {
                if (pd > bd[s - 1])      { bd[s] = bd[s - 1]; bi[s] = bi[s - 1]; }
                else if (pd > bd[s])     { bd[s] = pd;        bi[s] = j;         }
            }
            if (pd > bd[0]) { bd[0] = pd; bi[0] = j; }
        }
    }
    __syncthreads();

    // merge space aliased onto sp (48KB used)
    float* mv  = (float*)sp;                 // [64*4][16]
    int*   mi  = (int*)(mv + 64 * 64);
    float* m2v = (float*)(mi + 64 * 64);     // [64*2][16]
    int*   m2i = (int*)(m2v + 64 * 32);
    {
        float* dv = mv + (ptl * 4 + r) * 16;
        int*   di = mi + (ptl * 4 + r) * 16;
#pragma unroll
        for (int s = 0; s < 16; ++s) { dv[s] = bd[s]; di[s] = bi[s]; }
    }
    __syncthreads();
    if (r < 2) {  // merge slice pair (2r, 2r+1); A has lower j so ties take A
        const float* av = mv + (ptl * 4 + 2 * r) * 16;
        const int*   ai = mi + (ptl * 4 + 2 * r) * 16;
        const float* bv = av + 16;
        const int*   bj = ai + 16;
        float* ov = m2v + (ptl * 2 + r) * 16;
        int*   oi = m2i + (ptl * 2 + r) * 16;
        int ia = 0, ib = 0;
#pragma unroll
        for (int o = 0; o < 16; ++o) {
            float va = av[ia], vb = bv[ib];
            bool takeA = va >= vb;
            ov[o] = takeA ? va : vb;
            oi[o] = takeA ? ai[ia] : bj[ib];
            ia += takeA; ib += !takeA;
        }
    }
    __syncthreads();
    if (r == 0) {
        const float* av = m2v + (ptl * 2) * 16;
        const int*   ai = m2i + (ptl * 2) * 16;
        const float* bv = av + 16;
        const int*   bj = ai + 16;
        int* out = idxout + ((size_t)b * NPTS + n) * KNN;
        int ia = 0, ib = 0;
#pragma unroll
        for (int o = 0; o < 16; ++o) {
            bool takeA = av[ia] >= bv[ib];
            out[o] = takeA ? ai[ia] : bj[ib];
            ia += takeA; ib += !takeA;
        }
    }
}

// ---------------------------------------------------------------------------
// K2: local_cov (12ch) + mlp1 (12->64->64->64, ReLU each) -> h3 [B][N][64]
// grid (64, 8), block 256 = 64 points x 4 threads (16 ch each)
// ---------------------------------------------------------------------------
__global__ __launch_bounds__(256)
void cov_mlp1_kernel(const float* __restrict__ pts, const int* __restrict__ idx,
                     const float* __restrict__ w1, const float* __restrict__ b1,
                     const float* __restrict__ w2, const float* __restrict__ b2,
                     const float* __restrict__ w3, const float* __restrict__ b3,
                     float* __restrict__ h3out)
{
    __shared__ float cov[64 * 16];
    __shared__ float hA[64 * 68];
    __shared__ float hB[64 * 68];
    const int b = blockIdx.y, tid = threadIdx.x;
    const int ptl = tid >> 2, r = tid & 3;
    const int n0 = blockIdx.x * 64;

    if (tid < 64) {
        const int n = n0 + tid;
        const int* ip = idx + ((size_t)b * NPTS + n) * KNN;
        int j0 = ip[0], j1 = ip[1];
        const float* pb = pts + (size_t)b * 3 * NPTS;
        float px = pb[n],  py = pb[NPTS + n],  pz = pb[2 * NPTS + n];
        float ax = pb[j0], ay = pb[NPTS + j0], az = pb[2 * NPTS + j0];
        float bx = pb[j1], by = pb[NPTS + j1], bz = pb[2 * NPTS + j1];
        float* cv = cov + tid * 16;
        cv[0] = px; cv[1] = py; cv[2] = pz;
        cv[3] = ax * bx; cv[4]  = ax * by; cv[5]  = ax * bz;
        cv[6] = ay * bx; cv[7]  = ay * by; cv[8]  = ay * bz;
        cv[9] = az * bx; cv[10] = az * by; cv[11] = az * bz;
        cv[12] = 0.f; cv[13] = 0.f; cv[14] = 0.f; cv[15] = 0.f;
    }
    __syncthreads();
    {   // 12 -> 64
        const float4* xr = (const float4*)(cov + ptl * 16);
        float4 x0 = xr[0], x1 = xr[1], x2 = xr[2];
        for (int cc = 0; cc < 16; ++cc) {
            int c = r * 16 + cc;
            const float4* wr = (const float4*)(w1 + c * 12);
            float4 wa = wr[0], wb = wr[1], wc = wr[2];
            float acc = b1[c];
            acc += wa.x * x0.x + wa.y * x0.y + wa.z * x0.z + wa.w * x0.w;
            acc += wb.x * x1.x + wb.y * x1.y + wb.z * x1.z + wb.w * x1.w;
            acc += wc.x * x2.x + wc.y * x2.y + wc.z * x2.z;   // cov[11] is last real
            hA[ptl * 68 + c] = relu_f(acc);
        }
    }
    __syncthreads();
    {   // 64 -> 64
        const float4* xr = (const float4*)(hA + ptl * 68);
        for (int cc = 0; cc < 16; ++cc) {
            int c = r * 16 + cc;
            const float4* wr = (const float4*)(w2 + c * 64);
            float a0 = b2[c], a1 = 0.f, a2 = 0.f, a3 = 0.f;
#pragma unroll
            for (int k4 = 0; k4 < 16; ++k4) {
                float4 w = wr[k4], x = xr[k4];
                a0 += w.x * x.x; a1 += w.y * x.y; a2 += w.z * x.z; a3 += w.w * x.w;
            }
            hB[ptl * 68 + c] = relu_f((a0 + a1) + (a2 + a3));
        }
    }
    __syncthreads();
    {   // 64 -> 64 -> global
        const float4* xr = (const float4*)(hB + ptl * 68);
        float* out = h3out + ((size_t)b * NPTS + n0 + ptl) * 64;
        for (int cc = 0; cc < 16; ++cc) {
            int c = r * 16 + cc;
            const float4* wr = (const float4*)(w3 + c * 64);
            float a0 = b3[c], a1 = 0.f, a2 = 0.f, a3 = 0.f;
#pragma unroll
            for (int k4 = 0; k4 < 16; ++k4) {
                float4 w = wr[k4], x = xr[k4];
                a0 += w.x * x.x; a1 += w.y * x.y; a2 += w.z * x.z; a3 += w.w * x.w;
            }
            out[c] = relu_f((a0 + a1) + (a2 + a3));
        }
    }
}

// ---------------------------------------------------------------------------
// K3/K5: neighbor max-pool over 16 neighbors, feature dim D
// ---------------------------------------------------------------------------
template <int D>
__global__ __launch_bounds__(256)
void maxpool_kernel(const float* __restrict__ f, const int* __restrict__ idx,
                    float* __restrict__ out)
{
    const int b = blockIdx.y, tid = threadIdx.x;
    const int n = blockIdx.x * (256 / D) + tid / D;
    const int d = tid % D;
    const int* ip = idx + ((size_t)b * NPTS + n) * KNN;
    const float* fb = f + (size_t)b * NPTS * D;
    float v = -FLT_MAX;
#pragma unroll
    for (int k = 0; k < KNN; ++k) {
        int j = ip[k];
        v = fmaxf(v, fb[(size_t)j * D + d]);
    }
    out[((size_t)b * NPTS + n) * D + d] = v;
}

// ---------------------------------------------------------------------------
// K4: t1 = L1(64->64) (no relu); y1 = relu(C1(64->128))
// grid (64, 8), block 256 = 64 points x 4 threads
// ---------------------------------------------------------------------------
__global__ __launch_bounds__(256)
void lin_conv1_kernel(const float* __restrict__ xin,
                      const float* __restrict__ l1w, const float* __restrict__ l1b,
                      const float* __restrict__ c1w, const float* __restrict__ c1b,
                      float* __restrict__ yout)
{
    __shared__ float sx[64 * 68];
    __shared__ float t1[64 * 68];
    const int b = blockIdx.y, tid = threadIdx.x;
    const int n0 = blockIdx.x * 64;
    const int ptl = tid >> 2, r = tid & 3;

    for (int i = tid; i < 64 * 64; i += 256) {
        int p = i >> 6, k = i & 63;
        sx[p * 68 + k] = xin[((size_t)b * NPTS + n0 + p) * 64 + k];
    }
    __syncthreads();
    {
        const float4* xr = (const float4*)(sx + ptl * 68);
        for (int cc = 0; cc < 16; ++cc) {
            int c = r * 16 + cc;
            const float4* wr = (const float4*)(l1w + c * 64);
            float a0 = l1b[c], a1 = 0.f, a2 = 0.f, a3 = 0.f;
#pragma unroll
            for (int k4 = 0; k4 < 16; ++k4) {
                float4 w = wr[k4], x = xr[k4];
                a0 += w.x * x.x; a1 += w.y * x.y; a2 += w.z * x.z; a3 += w.w * x.w;
            }
            t1[ptl * 68 + c] = (a0 + a1) + (a2 + a3);   // no relu
        }
    }
    __syncthreads();
    {
        const float4* xr = (const float4*)(t1 + ptl * 68);
        float* out = yout + ((size_t)b * NPTS + n0 + ptl) * 128;
        for (int cc = 0; cc < 32; ++cc) {
            int c = r * 32 + cc;
            const float4* wr = (const float4*)(c1w + c * 64);
            float a0 = c1b[c], a1 = 0.f, a2 = 0.f, a3 = 0.f;
#pragma unroll
            for (int k4 = 0; k4 < 16; ++k4) {
                float4 w = wr[k4], x = xr[k4];
                a0 += w.x * x.x; a1 += w.y * x.y; a2 += w.z * x.z; a3 += w.w * x.w;
            }
            out[c] = relu_f((a0 + a1) + (a2 + a3));
        }
    }
}

// ---------------------------------------------------------------------------
// K6: t2 = L2(128->128) (no relu)
// grid (64, 8), block 256 = 64 points x 4 threads (32 ch each)
// ---------------------------------------------------------------------------
__global__ __launch_bounds__(256)
void lin2_kernel(const float* __restrict__ xin, const float* __restrict__ w,
                 const float* __restrict__ bias, float* __restrict__ out)
{
    __shared__ float sx[64 * 132];
    const int b = blockIdx.y, tid = threadIdx.x;
    const int n0 = blockIdx.x * 64;
    const int ptl = tid >> 2, r = tid & 3;

    for (int i = tid; i < 64 * 128; i += 256) {
        int p = i >> 7, k = i & 127;
        sx[p * 132 + k] = xin[((size_t)b * NPTS + n0 + p) * 128 + k];
    }
    __syncthreads();
    const float4* xr = (const float4*)(sx + ptl * 132);
    float* op = out + ((size_t)b * NPTS + n0 + ptl) * 128;
    for (int cc = 0; cc < 32; ++cc) {
        int c = r * 32 + cc;
        const float4* wr = (const float4*)(w + c * 128);
        float a0 = bias[c], a1 = 0.f, a2 = 0.f, a3 = 0.f;
#pragma unroll
        for (int k4 = 0; k4 < 32; ++k4) {
            float4 ww = wr[k4], x = xr[k4];
            a0 += ww.x * x.x; a1 += ww.y * x.y; a2 += ww.z * x.z; a3 += ww.w * x.w;
        }
        op[c] = (a0 + a1) + (a2 + a3);
    }
}

// ---------------------------------------------------------------------------
// K7: conv2 (128->1024) fused with per-block max over 64 points
// grid (64 ptchunks, 4 chgroups, 8 batch), block 256 (one channel each)
// W row (128 floats) held in VGPRs; X broadcast-read from LDS.
// ---------------------------------------------------------------------------
__global__ __launch_bounds__(256)
void conv2max_kernel(const float* __restrict__ xin, const float* __restrict__ w,
                     const float* __restrict__ bias, float* __restrict__ pmax)
{
    __shared__ __align__(16) float sx[64 * 128];
    const int chunk = blockIdx.x, g = blockIdx.y, b = blockIdx.z;
    const int tid = threadIdx.x;
    const int n0 = chunk * 64;

    for (int i = tid; i < 64 * 128; i += 256)
        sx[i] = xin[((size_t)b * NPTS + n0) * 128 + i];
    __syncthreads();

    const int ch = g * 256 + tid;
    const float4* wr = (const float4*)(w + (size_t)ch * 128);
    float4 wv[32];
#pragma unroll
    for (int j = 0; j < 32; ++j) wv[j] = wr[j];

    const float4* x4 = (const float4*)sx;
    float mx = -FLT_MAX;
    for (int p = 0; p < 64; ++p) {
        const float4* xp = x4 + p * 32;
        float a0 = 0.f, a1 = 0.f, a2 = 0.f, a3 = 0.f;
#pragma unroll
        for (int j = 0; j < 32; ++j) {
            float4 x = xp[j];
            a0 += wv[j].x * x.x; a1 += wv[j].y * x.y;
            a2 += wv[j].z * x.z; a3 += wv[j].w * x.w;
        }
        mx = fmaxf(mx, (a0 + a1) + (a2 + a3));
    }
    mx += bias[ch];
    pmax[((size_t)b * 64 + chunk) * 1024 + ch] = mx;
}

// ---------------------------------------------------------------------------
// K8: reduce partial maxes over 64 chunks -> gmax [B][1024]
// ---------------------------------------------------------------------------
__global__ __launch_bounds__(256)
void gmax_kernel(const float* __restrict__ pmax, float* __restrict__ gmax)
{
    int t = blockIdx.x * 256 + threadIdx.x;   // 0..8191
    int b = t >> 10, ch = t & 1023;
    const float* pp = pmax + (size_t)b * 64 * 1024 + ch;
    float v = -FLT_MAX;
    for (int c = 0; c < 64; ++c) v = fmaxf(v, pp[c * 1024]);
    gmax[t] = v;
}

// ---------------------------------------------------------------------------
// K9: mlp2: relu(W1(512x1024)x + b1) -> W2(512x512)h + b2 -> out [8][512]
// grid 8, block 512
// ---------------------------------------------------------------------------
__global__ __launch_bounds__(512)
void mlp2_kernel(const float* __restrict__ gmax,
                 const float* __restrict__ w1, const float* __restrict__ b1,
                 const float* __restrict__ w2, const float* __restrict__ b2,
                 float* __restrict__ out)
{
    __shared__ __align__(16) float sg[1024];
    __shared__ __align__(16) float sh[512];
    const int b = blockIdx.x, tid = threadIdx.x;
    for (int i = tid; i < 1024; i += 512) sg[i] = gmax[b * 1024 + i];
    __syncthreads();
    {
        const float4* xr = (const float4*)sg;
        const float4* wr = (const float4*)(w1 + (size_t)tid * 1024);
        float a0 = 0.f, a1 = 0.f, a2 = 0.f, a3 = 0.f;
        for (int k = 0; k < 256; ++k) {
            float4 w = wr[k], x = xr[k];
            a0 += w.x * x.x; a1 += w.y * x.y; a2 += w.z * x.z; a3 += w.w * x.w;
        }
        sh[tid] = relu_f(b1[tid] + ((a0 + a1) + (a2 + a3)));
    }
    __syncthreads();
    {
        const float4* xr = (const float4*)sh;
        const float4* wr = (const float4*)(w2 + (size_t)tid * 512);
        float a0 = 0.f, a1 = 0.f, a2 = 0.f, a3 = 0.f;
        for (int k = 0; k < 128; ++k) {
            float4 w = wr[k], x = xr[k];
            a0 += w.x * x.x; a1 += w.y * x.y; a2 += w.z * x.z; a3 += w.w * x.w;
        }
        out[b * 512 + tid] = b2[tid] + ((a0 + a1) + (a2 + a3));
    }
}

// ---------------------------------------------------------------------------
extern "C" void kernel_launch(void* const* d_in, const int* in_sizes, int n_in,
                              void* d_out, int out_size, void* d_ws, size_t ws_size,
                              hipStream_t stream)
{
    const float* pts  = (const float*)d_in[0];
    const float* m1w1 = (const float*)d_in[1];
    const float* m1b1 = (const float*)d_in[2];
    const float* m1w2 = (const float*)d_in[3];
    const float* m1b2 = (const float*)d_in[4];
    const float* m1w3 = (const float*)d_in[5];
    const float* m1b3 = (const float*)d_in[6];
    const float* l1w  = (const float*)d_in[7];
    const float* l1b  = (const float*)d_in[8];
    const float* c1w  = (const float*)d_in[9];
    const float* c1b  = (const float*)d_in[10];
    const float* l2w  = (const float*)d_in[11];
    const float* l2b  = (const float*)d_in[12];
    const float* c2w  = (const float*)d_in[13];
    const float* c2b  = (const float*)d_in[14];
    const float* m2w1 = (const float*)d_in[15];
    const float* m2b1 = (const float*)d_in[16];
    const float* m2w2 = (const float*)d_in[17];
    const float* m2b2 = (const float*)d_in[18];

    char* ws = (char*)d_ws;
    size_t off = 0;
    int*   idx   = (int*)(ws + off);   off += (size_t)NBATCH * NPTS * KNN * 4;   // 2MB
    float* h3    = (float*)(ws + off); off += (size_t)NBATCH * NPTS * 64 * 4;    // 8MB
    float* mp1   = (float*)(ws + off); off += (size_t)NBATCH * NPTS * 64 * 4;    // 8MB
    float* y1    = (float*)(ws + off); off += (size_t)NBATCH * NPTS * 128 * 4;   // 16MB
    float* mp2   = (float*)(ws + off); off += (size_t)NBATCH * NPTS * 128 * 4;   // 16MB
    float* pmaxb = (float*)(ws + off); off += (size_t)NBATCH * 64 * 1024 * 4;    // 2MB
    float* gmx   = (float*)(ws + off); off += (size_t)NBATCH * 1024 * 4;
    float* t2    = y1;  // y1 dead after maxpool128; reuse its space

    knn_kernel<<<dim3(NPTS / 64, NBATCH), 256, 0, stream>>>(pts, idx);
    cov_mlp1_kernel<<<dim3(64, NBATCH), 256, 0, stream>>>(pts, idx, m1w1, m1b1,
                                                          m1w2, m1b2, m1w3, m1b3, h3);
    maxpool_kernel<64><<<dim3(NPTS / 4, NBATCH), 256, 0, stream>>>(h3, idx, mp1);
    lin_conv1_kernel<<<dim3(64, NBATCH), 256, 0, stream>>>(mp1, l1w, l1b, c1w, c1b, y1);
    maxpool_kernel<128><<<dim3(NPTS / 2, NBATCH), 256, 0, stream>>>(y1, idx, mp2);
    lin2_kernel<<<dim3(64, NBATCH), 256, 0, stream>>>(mp2, l2w, l2b, t2);
    conv2max_kernel<<<dim3(64, 4, NBATCH), 256, 0, stream>>>(t2, c2w, c2b, pmaxb);
    gmax_kernel<<<dim3(32), 256, 0, stream>>>(pmaxb, gmx);
    mlp2_kernel<<<dim3(NBATCH), 512, 0, stream>>>(gmx, m2w1, m2b1, m2w2, m2b2,
                                                  (float*)d_out);
}

// Round 2
// 965.373 us; speedup vs baseline: 1.8289x; 1.8289x over previous
//
#include <hip/hip_runtime.h>
#include <cfloat>

#define NBATCH 8
#define NPTS   4096
#define KNN    16

__device__ __forceinline__ float relu_f(float x) { return x > 0.f ? x : 0.f; }

// ---------------------------------------------------------------------------
// K1: KNN top-16, exact two-pass (med3 value-select + threshold rescan).
// grid (NPTS/64, NBATCH), block 256 = 64 points x 4 j-slices.
// Pass1: branchless sorted top-16 of pd values per thread (1 max + 15 med3).
// Merge 4 slices -> exact 16th-largest threshold per point.
// Pass2: rescan (identical FP ops), collect (pd,idx) >= thr via LDS atomics,
// final exact sort by (pd desc, idx asc) -> matches lax.top_k exactly.
// ---------------------------------------------------------------------------
__global__ __launch_bounds__(256)
void knn_kernel(const float* __restrict__ pts, int* __restrict__ idxout)
{
    __shared__ float4 tile[1024];     // 16KB candidate tile (x,y,z,xx)
    __shared__ float  kl[64 * 64];    // 16KB pass1 lists; aliased in pass2
    __shared__ float  thr[64];
    __shared__ int    cnt[64];

    const int b = blockIdx.y, tid = threadIdx.x;
    const int ptl = tid >> 2, r = tid & 3;
    const int n = blockIdx.x * 64 + ptl;
    const float* pb = pts + (size_t)b * 3 * NPTS;

    const float sx = pb[n], sy = pb[NPTS + n], sz = pb[2 * NPTS + n];
    const float negxx = -__fadd_rn(__fadd_rn(__fmul_rn(sx, sx), __fmul_rn(sy, sy)),
                                   __fmul_rn(sz, sz));

    float k16[16];
#pragma unroll
    for (int s = 0; s < 16; ++s) k16[s] = -FLT_MAX;

    const int base = r * 256;
    const int rot  = 2 * r;            // bank-group phase rotation per slice

    // ---- PASS 1: values-only top-16 per thread ----
    for (int t = 0; t < 4; ++t) {
        if (t) __syncthreads();
        for (int i = tid; i < 1024; i += 256) {
            int j = t * 1024 + i;
            float x = pb[j], y = pb[NPTS + j], z = pb[2 * NPTS + j];
            float xx = __fadd_rn(__fadd_rn(__fmul_rn(x, x), __fmul_rn(y, y)),
                                 __fmul_rn(z, z));
            tile[i] = make_float4(x, y, z, xx);
        }
        __syncthreads();
#pragma unroll 4
        for (int ii = 0; ii < 256; ++ii) {
            int i = base + ((ii + rot) & 255);
            float4 c = tile[i];
            float dot = __fadd_rn(__fadd_rn(__fmul_rn(sx, c.x), __fmul_rn(sy, c.y)),
                                  __fmul_rn(sz, c.z));
            float inner = __fmul_rn(-2.f, dot);
            float pd = __fsub_rn(__fsub_rn(negxx, inner), c.w);
            // sorted (desc) insert via med3: writes s=15..1 read old s-1 values
            float old0 = k16[0];
#pragma unroll
            for (int s = 15; s >= 1; --s)
                k16[s] = __builtin_amdgcn_fmed3f(k16[s - 1], k16[s], pd);
            k16[0] = fmaxf(old0, pd);
        }
    }

#pragma unroll
    for (int s = 0; s < 16; ++s) kl[ptl * 64 + r * 16 + s] = k16[s];
    __syncthreads();
    if (r == 0) {   // merge 4 sorted-desc lists; tv = 16th largest of union
        const float* L = kl + ptl * 64;
        int i0 = 0, i1 = 16, i2 = 32, i3 = 48;
        float tv = 0.f;
        for (int o = 0; o < 16; ++o) {
            float v0 = L[i0], v1 = L[i1], v2 = L[i2], v3 = L[i3];
            tv = fmaxf(fmaxf(v0, v1), fmaxf(v2, v3));
            if (v0 == tv) ++i0;
            else if (v1 == tv) ++i1;
            else if (v2 == tv) ++i2;
            else ++i3;
        }
        thr[ptl] = tv;
        cnt[ptl] = 0;
    }
    __syncthreads();
    const float myThr = thr[ptl];

    // ---- PASS 2: collect (pd, idx) with pd >= thr (aliases kl space) ----
    float* pv = kl;                        // [64][24] values
    int*   pi = (int*)(kl + 64 * 24);      // [64][24] indices

    for (int tt = 0; tt < 4; ++tt) {
        int t = 3 - tt;                    // tile 3 still resident from pass 1
        if (tt) {
            __syncthreads();
            for (int i = tid; i < 1024; i += 256) {
                int j = t * 1024 + i;
                float x = pb[j], y = pb[NPTS + j], z = pb[2 * NPTS + j];
                float xx = __fadd_rn(__fadd_rn(__fmul_rn(x, x), __fmul_rn(y, y)),
                                     __fmul_rn(z, z));
                tile[i] = make_float4(x, y, z, xx);
            }
            __syncthreads();
        }
        for (int ii = 0; ii < 256; ++ii) {
            int i = base + ((ii + rot) & 255);
            float4 c = tile[i];
            float dot = __fadd_rn(__fadd_rn(__fmul_rn(sx, c.x), __fmul_rn(sy, c.y)),
                                  __fmul_rn(sz, c.z));
            float inner = __fmul_rn(-2.f, dot);
            float pd = __fsub_rn(__fsub_rn(negxx, inner), c.w);
            if (pd >= myThr) {
                int pos = atomicAdd(&cnt[ptl], 1);
                if (pos < 24) { pv[ptl * 24 + pos] = pd; pi[ptl * 24 + pos] = t * 1024 + i; }
            }
        }
    }
    __syncthreads();

    if (tid < 64) {   // wave 0: one lane per point, exact top-16 sort
        int c = cnt[tid]; if (c > 24) c = 24;
        float* v  = pv + tid * 24;
        int*   ix = pi + tid * 24;
        int* out = idxout + ((size_t)b * NPTS + blockIdx.x * 64 + tid) * KNN;
        for (int o = 0; o < 16; ++o) {
            int best = o;
            for (int q = o + 1; q < c; ++q) {
                float vq = v[q], vb = v[best];
                if (vq > vb || (vq == vb && ix[q] < ix[best])) best = q;
            }
            float tv = v[o]; v[o] = v[best]; v[best] = tv;
            int   ti = ix[o]; ix[o] = ix[best]; ix[best] = ti;
            out[o] = ix[o];
        }
    }
}

// ---------------------------------------------------------------------------
// K2: local_cov (12ch) + mlp1 (12->64->64->64, ReLU each) -> h3 [B][N][64]
// ---------------------------------------------------------------------------
__global__ __launch_bounds__(256)
void cov_mlp1_kernel(const float* __restrict__ pts, const int* __restrict__ idx,
                     const float* __restrict__ w1, const float* __restrict__ b1,
                     const float* __restrict__ w2, const float* __restrict__ b2,
                     const float* __restrict__ w3, const float* __restrict__ b3,
                     float* __restrict__ h3out)
{
    __shared__ float cov[64 * 16];
    __shared__ float hA[64 * 68];
    __shared__ float hB[64 * 68];
    const int b = blockIdx.y, tid = threadIdx.x;
    const int ptl = tid >> 2, r = tid & 3;
    const int n0 = blockIdx.x * 64;

    if (tid < 64) {
        const int n = n0 + tid;
        const int* ip = idx + ((size_t)b * NPTS + n) * KNN;
        int j0 = ip[0], j1 = ip[1];
        const float* pb = pts + (size_t)b * 3 * NPTS;
        float px = pb[n],  py = pb[NPTS + n],  pz = pb[2 * NPTS + n];
        float ax = pb[j0], ay = pb[NPTS + j0], az = pb[2 * NPTS + j0];
        float bx = pb[j1], by = pb[NPTS + j1], bz = pb[2 * NPTS + j1];
        float* cv = cov + tid * 16;
        cv[0] = px; cv[1] = py; cv[2] = pz;
        cv[3] = ax * bx; cv[4]  = ax * by; cv[5]  = ax * bz;
        cv[6] = ay * bx; cv[7]  = ay * by; cv[8]  = ay * bz;
        cv[9] = az * bx; cv[10] = az * by; cv[11] = az * bz;
        cv[12] = 0.f; cv[13] = 0.f; cv[14] = 0.f; cv[15] = 0.f;
    }
    __syncthreads();
    {   // 12 -> 64
        const float4* xr = (const float4*)(cov + ptl * 16);
        float4 x0 = xr[0], x1 = xr[1], x2 = xr[2];
        for (int cc = 0; cc < 16; ++cc) {
            int c = r * 16 + cc;
            const float4* wr = (const float4*)(w1 + c * 12);
            float4 wa = wr[0], wb = wr[1], wc = wr[2];
            float acc = b1[c];
            acc += wa.x * x0.x + wa.y * x0.y + wa.z * x0.z + wa.w * x0.w;
            acc += wb.x * x1.x + wb.y * x1.y + wb.z * x1.z + wb.w * x1.w;
            acc += wc.x * x2.x + wc.y * x2.y + wc.z * x2.z;
            hA[ptl * 68 + c] = relu_f(acc);
        }
    }
    __syncthreads();
    {   // 64 -> 64
        const float4* xr = (const float4*)(hA + ptl * 68);
        for (int cc = 0; cc < 16; ++cc) {
            int c = r * 16 + cc;
            const float4* wr = (const float4*)(w2 + c * 64);
            float a0 = b2[c], a1 = 0.f, a2 = 0.f, a3 = 0.f;
#pragma unroll
            for (int k4 = 0; k4 < 16; ++k4) {
                float4 w = wr[k4], x = xr[k4];
                a0 += w.x * x.x; a1 += w.y * x.y; a2 += w.z * x.z; a3 += w.w * x.w;
            }
            hB[ptl * 68 + c] = relu_f((a0 + a1) + (a2 + a3));
        }
    }
    __syncthreads();
    {   // 64 -> 64 -> global
        const float4* xr = (const float4*)(hB + ptl * 68);
        float* out = h3out + ((size_t)b * NPTS + n0 + ptl) * 64;
        for (int cc = 0; cc < 16; ++cc) {
            int c = r * 16 + cc;
            const float4* wr = (const float4*)(w3 + c * 64);
            float a0 = b3[c], a1 = 0.f, a2 = 0.f, a3 = 0.f;
#pragma unroll
            for (int k4 = 0; k4 < 16; ++k4) {
                float4 w = wr[k4], x = xr[k4];
                a0 += w.x * x.x; a1 += w.y * x.y; a2 += w.z * x.z; a3 += w.w * x.w;
            }
            out[c] = relu_f((a0 + a1) + (a2 + a3));
        }
    }
}

// ---------------------------------------------------------------------------
// K3/K5: neighbor max-pool, float4 per thread. DV4 = D/4 (16 or 32).
// ---------------------------------------------------------------------------
template <int DV4>
__global__ __launch_bounds__(256)
void maxpool4_kernel(const float4* __restrict__ f, const int* __restrict__ idx,
                     float4* __restrict__ out)
{
    constexpr int SH = (DV4 == 16) ? 4 : 5;
    int t = blockIdx.x * 256 + threadIdx.x;
    int d4 = t & (DV4 - 1);
    int n  = (t >> SH) & (NPTS - 1);
    int b  = t >> (SH + 12);
    const int* ip = idx + ((size_t)b * NPTS + n) * KNN;
    const float4* fb = f + (size_t)b * NPTS * DV4;
    float4 v = make_float4(-FLT_MAX, -FLT_MAX, -FLT_MAX, -FLT_MAX);
#pragma unroll
    for (int k = 0; k < KNN; ++k) {
        float4 c = fb[(size_t)ip[k] * DV4 + d4];
        v.x = fmaxf(v.x, c.x); v.y = fmaxf(v.y, c.y);
        v.z = fmaxf(v.z, c.z); v.w = fmaxf(v.w, c.w);
    }
    out[t] = v;
}

// ---------------------------------------------------------------------------
// K4: t1 = L1(64->64) (no relu); y1 = relu(C1(64->128))
// ---------------------------------------------------------------------------
__global__ __launch_bounds__(256)
void lin_conv1_kernel(const float* __restrict__ xin,
                      const float* __restrict__ l1w, const float* __restrict__ l1b,
                      const float* __restrict__ c1w, const float* __restrict__ c1b,
                      float* __restrict__ yout)
{
    __shared__ float sx[64 * 68];
    __shared__ float t1[64 * 68];
    const int b = blockIdx.y, tid = threadIdx.x;
    const int n0 = blockIdx.x * 64;
    const int ptl = tid >> 2, r = tid & 3;

    for (int i = tid; i < 64 * 64; i += 256) {
        int p = i >> 6, k = i & 63;
        sx[p * 68 + k] = xin[((size_t)b * NPTS + n0 + p) * 64 + k];
    }
    __syncthreads();
    {
        const float4* xr = (const float4*)(sx + ptl * 68);
        for (int cc = 0; cc < 16; ++cc) {
            int c = r * 16 + cc;
            const float4* wr = (const float4*)(l1w + c * 64);
            float a0 = l1b[c], a1 = 0.f, a2 = 0.f, a3 = 0.f;
#pragma unroll
            for (int k4 = 0; k4 < 16; ++k4) {
                float4 w = wr[k4], x = xr[k4];
                a0 += w.x * x.x; a1 += w.y * x.y; a2 += w.z * x.z; a3 += w.w * x.w;
            }
            t1[ptl * 68 + c] = (a0 + a1) + (a2 + a3);
        }
    }
    __syncthreads();
    {
        const float4* xr = (const float4*)(t1 + ptl * 68);
        float* out = yout + ((size_t)b * NPTS + n0 + ptl) * 128;
        for (int cc = 0; cc < 32; ++cc) {
            int c = r * 32 + cc;
            const float4* wr = (const float4*)(c1w + c * 64);
            float a0 = c1b[c], a1 = 0.f, a2 = 0.f, a3 = 0.f;
#pragma unroll
            for (int k4 = 0; k4 < 16; ++k4) {
                float4 w = wr[k4], x = xr[k4];
                a0 += w.x * x.x; a1 += w.y * x.y; a2 += w.z * x.z; a3 += w.w * x.w;
            }
            out[c] = relu_f((a0 + a1) + (a2 + a3));
        }
    }
}

// ---------------------------------------------------------------------------
// K6: t2 = L2(128->128) (no relu)
// ---------------------------------------------------------------------------
__global__ __launch_bounds__(256)
void lin2_kernel(const float* __restrict__ xin, const float* __restrict__ w,
                 const float* __restrict__ bias, float* __restrict__ out)
{
    __shared__ float sx[64 * 132];
    const int b = blockIdx.y, tid = threadIdx.x;
    const int n0 = blockIdx.x * 64;
    const int ptl = tid >> 2, r = tid & 3;

    for (int i = tid; i < 64 * 128; i += 256) {
        int p = i >> 7, k = i & 127;
        sx[p * 132 + k] = xin[((size_t)b * NPTS + n0 + p) * 128 + k];
    }
    __syncthreads();
    const float4* xr = (const float4*)(sx + ptl * 132);
    float* op = out + ((size_t)b * NPTS + n0 + ptl) * 128;
    for (int cc = 0; cc < 32; ++cc) {
        int c = r * 32 + cc;
        const float4* wr = (const float4*)(w + c * 128);
        float a0 = bias[c], a1 = 0.f, a2 = 0.f, a3 = 0.f;
#pragma unroll
        for (int k4 = 0; k4 < 32; ++k4) {
            float4 ww = wr[k4], x = xr[k4];
            a0 += ww.x * x.x; a1 += ww.y * x.y; a2 += ww.z * x.z; a3 += ww.w * x.w;
        }
        op[c] = (a0 + a1) + (a2 + a3);
    }
}

// ---------------------------------------------------------------------------
// K7: conv2 (128->1024) + per-block max over 64 points, 4x4 register tile.
// grid (64 ptchunks, 16 chgroups, 8 batch), block 256.
// Thread (pq,cq): points pq*4+i, channels cq+16*j (stride-16 for 2-way-free
// LDS banks with the 132-float padded rows). 8 FMA per ds_read_b128.
// ---------------------------------------------------------------------------
__global__ __launch_bounds__(256)
void conv2max_kernel(const float* __restrict__ xin, const float* __restrict__ w,
                     const float* __restrict__ bias, float* __restrict__ pmax)
{
    __shared__ __align__(16) float Xs[64 * 132];
    __shared__ __align__(16) float Ws[64 * 132];
    const int chunk = blockIdx.x, g = blockIdx.y, b = blockIdx.z;
    const int tid = threadIdx.x;

    for (int i = tid; i < 64 * 32; i += 256) {
        int p = i >> 5, k4 = i & 31;
        ((float4*)(Xs + p * 132))[k4] =
            ((const float4*)(xin + ((size_t)b * NPTS + chunk * 64 + p) * 128))[k4];
        ((float4*)(Ws + p * 132))[k4] =
            ((const float4*)(w + (size_t)(g * 64 + p) * 128))[k4];
    }
    __syncthreads();

    const int pq = tid >> 4, cq = tid & 15;
    const float4* X4 = (const float4*)Xs;   // row stride 33 float4
    const float4* W4 = (const float4*)Ws;
    float acc[4][4];
#pragma unroll
    for (int i = 0; i < 4; ++i)
#pragma unroll
        for (int j = 0; j < 4; ++j) acc[i][j] = 0.f;

    for (int k4 = 0; k4 < 32; ++k4) {
        float4 xa[4], wb[4];
#pragma unroll
        for (int i = 0; i < 4; ++i) xa[i] = X4[(pq * 4 + i) * 33 + k4];
#pragma unroll
        for (int j = 0; j < 4; ++j) wb[j] = W4[(cq + 16 * j) * 33 + k4];
#pragma unroll
        for (int i = 0; i < 4; ++i)
#pragma unroll
            for (int j = 0; j < 4; ++j) {
                acc[i][j] += xa[i].x * wb[j].x + xa[i].y * wb[j].y
                           + xa[i].z * wb[j].z + xa[i].w * wb[j].w;
            }
    }
#pragma unroll
    for (int j = 0; j < 4; ++j) {
        float m = fmaxf(fmaxf(acc[0][j], acc[1][j]), fmaxf(acc[2][j], acc[3][j]));
        int c = g * 64 + cq + 16 * j;
        pmax[((size_t)b * 64 + chunk) * 1024 + c] = m + bias[c];
    }
}

// ---------------------------------------------------------------------------
// K8: reduce partial maxes over 64 chunks -> gmax [B][1024]
// ---------------------------------------------------------------------------
__global__ __launch_bounds__(256)
void gmax_kernel(const float* __restrict__ pmax, float* __restrict__ gmax)
{
    int t = blockIdx.x * 256 + threadIdx.x;   // 0..8191
    int b = t >> 10, ch = t & 1023;
    const float* pp = pmax + (size_t)b * 64 * 1024 + ch;
    float v = -FLT_MAX;
    for (int c = 0; c < 64; ++c) v = fmaxf(v, pp[c * 1024]);
    gmax[t] = v;
}

// ---------------------------------------------------------------------------
// K9a/K9b: mlp2 split wide. grid (4, 8), block 128.
// ---------------------------------------------------------------------------
__global__ __launch_bounds__(128)
void mlp2a_kernel(const float* __restrict__ g, const float* __restrict__ w1,
                  const float* __restrict__ b1, float* __restrict__ h)
{
    __shared__ __align__(16) float sg[1024];
    const int b = blockIdx.y, tid = threadIdx.x;
    for (int i = tid; i < 1024; i += 128) sg[i] = g[b * 1024 + i];
    __syncthreads();
    const int ch = blockIdx.x * 128 + tid;
    const float4* xr = (const float4*)sg;
    const float4* wr = (const float4*)(w1 + (size_t)ch * 1024);
    float a0 = 0.f, a1 = 0.f, a2 = 0.f, a3 = 0.f;
    for (int k = 0; k < 256; ++k) {
        float4 w = wr[k], x = xr[k];
        a0 += w.x * x.x; a1 += w.y * x.y; a2 += w.z * x.z; a3 += w.w * x.w;
    }
    h[b * 512 + ch] = relu_f(b1[ch] + ((a0 + a1) + (a2 + a3)));
}

__global__ __launch_bounds__(128)
void mlp2b_kernel(const float* __restrict__ h, const float* __restrict__ w2,
                  const float* __restrict__ b2, float* __restrict__ out)
{
    __shared__ __align__(16) float sh[512];
    const int b = blockIdx.y, tid = threadIdx.x;
    for (int i = tid; i < 512; i += 128) sh[i] = h[b * 512 + i];
    __syncthreads();
    const int ch = blockIdx.x * 128 + tid;
    const float4* xr = (const float4*)sh;
    const float4* wr = (const float4*)(w2 + (size_t)ch * 512);
    float a0 = 0.f, a1 = 0.f, a2 = 0.f, a3 = 0.f;
    for (int k = 0; k < 128; ++k) {
        float4 w = wr[k], x = xr[k];
        a0 += w.x * x.x; a1 += w.y * x.y; a2 += w.z * x.z; a3 += w.w * x.w;
    }
    out[b * 512 + ch] = b2[ch] + ((a0 + a1) + (a2 + a3));
}

// ---------------------------------------------------------------------------
extern "C" void kernel_launch(void* const* d_in, const int* in_sizes, int n_in,
                              void* d_out, int out_size, void* d_ws, size_t ws_size,
                              hipStream_t stream)
{
    const float* pts  = (const float*)d_in[0];
    const float* m1w1 = (const float*)d_in[1];
    const float* m1b1 = (const float*)d_in[2];
    const float* m1w2 = (const float*)d_in[3];
    const float* m1b2 = (const float*)d_in[4];
    const float* m1w3 = (const float*)d_in[5];
    const float* m1b3 = (const float*)d_in[6];
    const float* l1w  = (const float*)d_in[7];
    const float* l1b  = (const float*)d_in[8];
    const float* c1w  = (const float*)d_in[9];
    const float* c1b  = (const float*)d_in[10];
    const float* l2w  = (const float*)d_in[11];
    const float* l2b  = (const float*)d_in[12];
    const float* c2w  = (const float*)d_in[13];
    const float* c2b  = (const float*)d_in[14];
    const float* m2w1 = (const float*)d_in[15];
    const float* m2b1 = (const float*)d_in[16];
    const float* m2w2 = (const float*)d_in[17];
    const float* m2b2 = (const float*)d_in[18];

    char* ws = (char*)d_ws;
    size_t off = 0;
    int*   idx   = (int*)(ws + off);   off += (size_t)NBATCH * NPTS * KNN * 4;   // 2MB
    float* h3    = (float*)(ws + off); off += (size_t)NBATCH * NPTS * 64 * 4;    // 8MB
    float* mp1   = (float*)(ws + off); off += (size_t)NBATCH * NPTS * 64 * 4;    // 8MB
    float* y1    = (float*)(ws + off); off += (size_t)NBATCH * NPTS * 128 * 4;   // 16MB
    float* mp2   = (float*)(ws + off); off += (size_t)NBATCH * NPTS * 128 * 4;   // 16MB
    float* pmaxb = (float*)(ws + off); off += (size_t)NBATCH * 64 * 1024 * 4;    // 2MB
    float* gmx   = (float*)(ws + off); off += (size_t)NBATCH * 1024 * 4;
    float* hbuf  = (float*)(ws + off); off += (size_t)NBATCH * 512 * 4;
    float* t2    = y1;  // y1 dead after maxpool128; reuse its space

    knn_kernel<<<dim3(NPTS / 64, NBATCH), 256, 0, stream>>>(pts, idx);
    cov_mlp1_kernel<<<dim3(64, NBATCH), 256, 0, stream>>>(pts, idx, m1w1, m1b1,
                                                          m1w2, m1b2, m1w3, m1b3, h3);
    maxpool4_kernel<16><<<dim3(NBATCH * NPTS * 16 / 256), 256, 0, stream>>>(
        (const float4*)h3, idx, (float4*)mp1);
    lin_conv1_kernel<<<dim3(64, NBATCH), 256, 0, stream>>>(mp1, l1w, l1b, c1w, c1b, y1);
    maxpool4_kernel<32><<<dim3(NBATCH * NPTS * 32 / 256), 256, 0, stream>>>(
        (const float4*)y1, idx, (float4*)mp2);
    lin2_kernel<<<dim3(64, NBATCH), 256, 0, stream>>>(mp2, l2w, l2b, t2);
    conv2max_kernel<<<dim3(64, 16, NBATCH), 256, 0, stream>>>(t2, c2w, c2b, pmaxb);
    gmax_kernel<<<dim3(32), 256, 0, stream>>>(pmaxb, gmx);
    mlp2a_kernel<<<dim3(4, NBATCH), 128, 0, stream>>>(gmx, m2w1, m2b1, hbuf);
    mlp2b_kernel<<<dim3(4, NBATCH), 128, 0, stream>>>(hbuf, m2w2, m2b2, (float*)d_out);
}

// Round 3
// 481.777 us; speedup vs baseline: 3.6648x; 2.0038x over previous
//
#include <hip/hip_runtime.h>
#include <cfloat>

#define NBATCH 8
#define NPTS   4096
#define KNN    16

__device__ __forceinline__ float relu_f(float x) { return x > 0.f ? x : 0.f; }

// ---------------------------------------------------------------------------
// K1: KNN top-16, exact two-pass (med3 value-select + threshold rescan).
// (unchanged from R2 — correct and off the critical path pending next profile)
// ---------------------------------------------------------------------------
__global__ __launch_bounds__(256)
void knn_kernel(const float* __restrict__ pts, int* __restrict__ idxout)
{
    __shared__ float4 tile[1024];
    __shared__ float  kl[64 * 64];
    __shared__ float  thr[64];
    __shared__ int    cnt[64];

    const int b = blockIdx.y, tid = threadIdx.x;
    const int ptl = tid >> 2, r = tid & 3;
    const int n = blockIdx.x * 64 + ptl;
    const float* pb = pts + (size_t)b * 3 * NPTS;

    const float sx = pb[n], sy = pb[NPTS + n], sz = pb[2 * NPTS + n];
    const float negxx = -__fadd_rn(__fadd_rn(__fmul_rn(sx, sx), __fmul_rn(sy, sy)),
                                   __fmul_rn(sz, sz));

    float k16[16];
#pragma unroll
    for (int s = 0; s < 16; ++s) k16[s] = -FLT_MAX;

    const int base = r * 256;
    const int rot  = 2 * r;

    for (int t = 0; t < 4; ++t) {
        if (t) __syncthreads();
        for (int i = tid; i < 1024; i += 256) {
            int j = t * 1024 + i;
            float x = pb[j], y = pb[NPTS + j], z = pb[2 * NPTS + j];
            float xx = __fadd_rn(__fadd_rn(__fmul_rn(x, x), __fmul_rn(y, y)),
                                 __fmul_rn(z, z));
            tile[i] = make_float4(x, y, z, xx);
        }
        __syncthreads();
#pragma unroll 4
        for (int ii = 0; ii < 256; ++ii) {
            int i = base + ((ii + rot) & 255);
            float4 c = tile[i];
            float dot = __fadd_rn(__fadd_rn(__fmul_rn(sx, c.x), __fmul_rn(sy, c.y)),
                                  __fmul_rn(sz, c.z));
            float inner = __fmul_rn(-2.f, dot);
            float pd = __fsub_rn(__fsub_rn(negxx, inner), c.w);
            float old0 = k16[0];
#pragma unroll
            for (int s = 15; s >= 1; --s)
                k16[s] = __builtin_amdgcn_fmed3f(k16[s - 1], k16[s], pd);
            k16[0] = fmaxf(old0, pd);
        }
    }

#pragma unroll
    for (int s = 0; s < 16; ++s) kl[ptl * 64 + r * 16 + s] = k16[s];
    __syncthreads();
    if (r == 0) {
        const float* L = kl + ptl * 64;
        int i0 = 0, i1 = 16, i2 = 32, i3 = 48;
        float tv = 0.f;
        for (int o = 0; o < 16; ++o) {
            float v0 = L[i0], v1 = L[i1], v2 = L[i2], v3 = L[i3];
            tv = fmaxf(fmaxf(v0, v1), fmaxf(v2, v3));
            if (v0 == tv) ++i0;
            else if (v1 == tv) ++i1;
            else if (v2 == tv) ++i2;
            else ++i3;
        }
        thr[ptl] = tv;
        cnt[ptl] = 0;
    }
    __syncthreads();
    const float myThr = thr[ptl];

    float* pv = kl;
    int*   pi = (int*)(kl + 64 * 24);

    for (int tt = 0; tt < 4; ++tt) {
        int t = 3 - tt;
        if (tt) {
            __syncthreads();
            for (int i = tid; i < 1024; i += 256) {
                int j = t * 1024 + i;
                float x = pb[j], y = pb[NPTS + j], z = pb[2 * NPTS + j];
                float xx = __fadd_rn(__fadd_rn(__fmul_rn(x, x), __fmul_rn(y, y)),
                                     __fmul_rn(z, z));
                tile[i] = make_float4(x, y, z, xx);
            }
            __syncthreads();
        }
        for (int ii = 0; ii < 256; ++ii) {
            int i = base + ((ii + rot) & 255);
            float4 c = tile[i];
            float dot = __fadd_rn(__fadd_rn(__fmul_rn(sx, c.x), __fmul_rn(sy, c.y)),
                                  __fmul_rn(sz, c.z));
            float inner = __fmul_rn(-2.f, dot);
            float pd = __fsub_rn(__fsub_rn(negxx, inner), c.w);
            if (pd >= myThr) {
                int pos = atomicAdd(&cnt[ptl], 1);
                if (pos < 24) { pv[ptl * 24 + pos] = pd; pi[ptl * 24 + pos] = t * 1024 + i; }
            }
        }
    }
    __syncthreads();

    if (tid < 64) {
        int c = cnt[tid]; if (c > 24) c = 24;
        float* v  = pv + tid * 24;
        int*   ix = pi + tid * 24;
        int* out = idxout + ((size_t)b * NPTS + blockIdx.x * 64 + tid) * KNN;
        for (int o = 0; o < 16; ++o) {
            int best = o;
            for (int q = o + 1; q < c; ++q) {
                float vq = v[q], vb = v[best];
                if (vq > vb || (vq == vb && ix[q] < ix[best])) best = q;
            }
            float tv = v[o]; v[o] = v[best]; v[best] = tv;
            int   ti = ix[o]; ix[o] = ix[best]; ix[best] = ti;
            out[o] = ix[o];
        }
    }
}

// ---------------------------------------------------------------------------
// K2: local_cov + mlp1 (12->64->64->64), all weights staged in LDS,
// 4x4 register tile per thread per layer. grid (64, 8), block 256.
// ---------------------------------------------------------------------------
__global__ __launch_bounds__(256)
void cov_mlp1_kernel(const float* __restrict__ pts, const int* __restrict__ idx,
                     const float* __restrict__ w1, const float* __restrict__ b1,
                     const float* __restrict__ w2, const float* __restrict__ b2,
                     const float* __restrict__ w3, const float* __restrict__ b3,
                     float* __restrict__ h3out)
{
    __shared__ __align__(16) float cov[64 * 16];
    __shared__ __align__(16) float w1s[64 * 16];
    __shared__ __align__(16) float w2s[64 * 68];
    __shared__ __align__(16) float w3s[64 * 68];
    __shared__ __align__(16) float hA[64 * 68];
    __shared__ __align__(16) float hB[64 * 68];

    const int b = blockIdx.y, tid = threadIdx.x;
    const int n0 = blockIdx.x * 64;
    const int pq = tid >> 4, cq = tid & 15;

    // stage weights
    for (int i = tid; i < 64 * 4; i += 256) {      // w1: rows of 12 -> pad 16
        int p = i >> 2, k4 = i & 3;
        float4 v = make_float4(0.f, 0.f, 0.f, 0.f);
        if (k4 < 3) v = *(const float4*)(w1 + p * 12 + k4 * 4);
        ((float4*)(w1s + p * 16))[k4] = v;
    }
    for (int i = tid; i < 64 * 16; i += 256) {     // w2, w3: 64x64 -> pad 68
        int p = i >> 4, k4 = i & 15;
        ((float4*)(w2s + p * 68))[k4] = ((const float4*)(w2 + p * 64))[k4];
        ((float4*)(w3s + p * 68))[k4] = ((const float4*)(w3 + p * 64))[k4];
    }
    // cov features (one thread per point)
    if (tid < 64) {
        const int n = n0 + tid;
        const int* ip = idx + ((size_t)b * NPTS + n) * KNN;
        int j0 = ip[0], j1 = ip[1];
        const float* pb = pts + (size_t)b * 3 * NPTS;
        float px = pb[n],  py = pb[NPTS + n],  pz = pb[2 * NPTS + n];
        float ax = pb[j0], ay = pb[NPTS + j0], az = pb[2 * NPTS + j0];
        float bx = pb[j1], by = pb[NPTS + j1], bz = pb[2 * NPTS + j1];
        float* cv = cov + tid * 16;
        cv[0] = px; cv[1] = py; cv[2] = pz;
        cv[3] = ax * bx; cv[4]  = ax * by; cv[5]  = ax * bz;
        cv[6] = ay * bx; cv[7]  = ay * by; cv[8]  = ay * bz;
        cv[9] = az * bx; cv[10] = az * by; cv[11] = az * bz;
        cv[12] = 0.f; cv[13] = 0.f; cv[14] = 0.f; cv[15] = 0.f;
    }
    __syncthreads();

    // ---- layer1: 12(16)->64, K tiles of 4 ----
    {
        float acc[4][4];
#pragma unroll
        for (int i = 0; i < 4; ++i)
#pragma unroll
            for (int j = 0; j < 4; ++j) acc[i][j] = 0.f;
        const float4* X4 = (const float4*)cov;
        const float4* W4 = (const float4*)w1s;
#pragma unroll
        for (int k4 = 0; k4 < 4; ++k4) {
            float4 xa[4], wb[4];
#pragma unroll
            for (int i = 0; i < 4; ++i) xa[i] = X4[(pq * 4 + i) * 4 + k4];
#pragma unroll
            for (int j = 0; j < 4; ++j) wb[j] = W4[(cq + 16 * j) * 4 + k4];
#pragma unroll
            for (int i = 0; i < 4; ++i)
#pragma unroll
                for (int j = 0; j < 4; ++j)
                    acc[i][j] += xa[i].x * wb[j].x + xa[i].y * wb[j].y
                               + xa[i].z * wb[j].z + xa[i].w * wb[j].w;
        }
#pragma unroll
        for (int j = 0; j < 4; ++j) {
            int c = cq + 16 * j;
            float bias = b1[c];
#pragma unroll
            for (int i = 0; i < 4; ++i)
                hA[(pq * 4 + i) * 68 + c] = relu_f(acc[i][j] + bias);
        }
    }
    __syncthreads();

    // ---- layer2: 64->64 ----
    {
        float acc[4][4];
#pragma unroll
        for (int i = 0; i < 4; ++i)
#pragma unroll
            for (int j = 0; j < 4; ++j) acc[i][j] = 0.f;
        const float4* X4 = (const float4*)hA;
        const float4* W4 = (const float4*)w2s;
        for (int k4 = 0; k4 < 16; ++k4) {
            float4 xa[4], wb[4];
#pragma unroll
            for (int i = 0; i < 4; ++i) xa[i] = X4[(pq * 4 + i) * 17 + k4];
#pragma unroll
            for (int j = 0; j < 4; ++j) wb[j] = W4[(cq + 16 * j) * 17 + k4];
#pragma unroll
            for (int i = 0; i < 4; ++i)
#pragma unroll
                for (int j = 0; j < 4; ++j)
                    acc[i][j] += xa[i].x * wb[j].x + xa[i].y * wb[j].y
                               + xa[i].z * wb[j].z + xa[i].w * wb[j].w;
        }
#pragma unroll
        for (int j = 0; j < 4; ++j) {
            int c = cq + 16 * j;
            float bias = b2[c];
#pragma unroll
            for (int i = 0; i < 4; ++i)
                hB[(pq * 4 + i) * 68 + c] = relu_f(acc[i][j] + bias);
        }
    }
    __syncthreads();

    // ---- layer3: 64->64 -> global ----
    {
        float acc[4][4];
#pragma unroll
        for (int i = 0; i < 4; ++i)
#pragma unroll
            for (int j = 0; j < 4; ++j) acc[i][j] = 0.f;
        const float4* X4 = (const float4*)hB;
        const float4* W4 = (const float4*)w3s;
        for (int k4 = 0; k4 < 16; ++k4) {
            float4 xa[4], wb[4];
#pragma unroll
            for (int i = 0; i < 4; ++i) xa[i] = X4[(pq * 4 + i) * 17 + k4];
#pragma unroll
            for (int j = 0; j < 4; ++j) wb[j] = W4[(cq + 16 * j) * 17 + k4];
#pragma unroll
            for (int i = 0; i < 4; ++i)
#pragma unroll
                for (int j = 0; j < 4; ++j)
                    acc[i][j] += xa[i].x * wb[j].x + xa[i].y * wb[j].y
                               + xa[i].z * wb[j].z + xa[i].w * wb[j].w;
        }
#pragma unroll
        for (int j = 0; j < 4; ++j) {
            int c = cq + 16 * j;
            float bias = b3[c];
#pragma unroll
            for (int i = 0; i < 4; ++i)
                h3out[((size_t)b * NPTS + n0 + pq * 4 + i) * 64 + c] =
                    relu_f(acc[i][j] + bias);
        }
    }
}

// ---------------------------------------------------------------------------
// K3/K5: neighbor max-pool, float4 per thread. DV4 = D/4 (16 or 32).
// ---------------------------------------------------------------------------
template <int DV4>
__global__ __launch_bounds__(256)
void maxpool4_kernel(const float4* __restrict__ f, const int* __restrict__ idx,
                     float4* __restrict__ out)
{
    constexpr int SH = (DV4 == 16) ? 4 : 5;
    int t = blockIdx.x * 256 + threadIdx.x;
    int d4 = t & (DV4 - 1);
    int n  = (t >> SH) & (NPTS - 1);
    int b  = t >> (SH + 12);
    const int* ip = idx + ((size_t)b * NPTS + n) * KNN;
    const float4* fb = f + (size_t)b * NPTS * DV4;
    float4 v = make_float4(-FLT_MAX, -FLT_MAX, -FLT_MAX, -FLT_MAX);
#pragma unroll
    for (int k = 0; k < KNN; ++k) {
        float4 c = fb[(size_t)ip[k] * DV4 + d4];
        v.x = fmaxf(v.x, c.x); v.y = fmaxf(v.y, c.y);
        v.z = fmaxf(v.z, c.z); v.w = fmaxf(v.w, c.w);
    }
    out[t] = v;
}

// ---------------------------------------------------------------------------
// K4: t1 = L1(64->64) (no relu); y1 = relu(C1(64->128))
// X + weights staged in LDS, 4x4 register tile. grid (64, 8), block 256.
// ---------------------------------------------------------------------------
__global__ __launch_bounds__(256)
void lin_conv1_kernel(const float* __restrict__ xin,
                      const float* __restrict__ l1w, const float* __restrict__ l1b,
                      const float* __restrict__ c1w, const float* __restrict__ c1b,
                      float* __restrict__ yout)
{
    __shared__ __align__(16) float sx[64 * 68];
    __shared__ __align__(16) float wbuf[64 * 68];
    __shared__ __align__(16) float t1[64 * 68];
    const int b = blockIdx.y, tid = threadIdx.x;
    const int n0 = blockIdx.x * 64;
    const int pq = tid >> 4, cq = tid & 15;

    for (int i = tid; i < 64 * 16; i += 256) {
        int p = i >> 4, k4 = i & 15;
        ((float4*)(sx + p * 68))[k4] =
            ((const float4*)(xin + ((size_t)b * NPTS + n0 + p) * 64))[k4];
        ((float4*)(wbuf + p * 68))[k4] = ((const float4*)(l1w + p * 64))[k4];
    }
    __syncthreads();

    {   // L1: 64->64, no relu, +bias -> t1
        float acc[4][4];
#pragma unroll
        for (int i = 0; i < 4; ++i)
#pragma unroll
            for (int j = 0; j < 4; ++j) acc[i][j] = 0.f;
        const float4* X4 = (const float4*)sx;
        const float4* W4 = (const float4*)wbuf;
        for (int k4 = 0; k4 < 16; ++k4) {
            float4 xa[4], wb[4];
#pragma unroll
            for (int i = 0; i < 4; ++i) xa[i] = X4[(pq * 4 + i) * 17 + k4];
#pragma unroll
            for (int j = 0; j < 4; ++j) wb[j] = W4[(cq + 16 * j) * 17 + k4];
#pragma unroll
            for (int i = 0; i < 4; ++i)
#pragma unroll
                for (int j = 0; j < 4; ++j)
                    acc[i][j] += xa[i].x * wb[j].x + xa[i].y * wb[j].y
                               + xa[i].z * wb[j].z + xa[i].w * wb[j].w;
        }
#pragma unroll
        for (int j = 0; j < 4; ++j) {
            int c = cq + 16 * j;
            float bias = l1b[c];
#pragma unroll
            for (int i = 0; i < 4; ++i)
                t1[(pq * 4 + i) * 68 + c] = acc[i][j] + bias;
        }
    }

    // C1: 64->128, two 64-ch passes staged into wbuf
    for (int g = 0; g < 2; ++g) {
        __syncthreads();   // previous wbuf reads done
        for (int i = tid; i < 64 * 16; i += 256) {
            int p = i >> 4, k4 = i & 15;
            ((float4*)(wbuf + p * 68))[k4] =
                ((const float4*)(c1w + (size_t)(g * 64 + p) * 64))[k4];
        }
        __syncthreads();
        float acc[4][4];
#pragma unroll
        for (int i = 0; i < 4; ++i)
#pragma unroll
            for (int j = 0; j < 4; ++j) acc[i][j] = 0.f;
        const float4* X4 = (const float4*)t1;
        const float4* W4 = (const float4*)wbuf;
        for (int k4 = 0; k4 < 16; ++k4) {
            float4 xa[4], wb[4];
#pragma unroll
            for (int i = 0; i < 4; ++i) xa[i] = X4[(pq * 4 + i) * 17 + k4];
#pragma unroll
            for (int j = 0; j < 4; ++j) wb[j] = W4[(cq + 16 * j) * 17 + k4];
#pragma unroll
            for (int i = 0; i < 4; ++i)
#pragma unroll
                for (int j = 0; j < 4; ++j)
                    acc[i][j] += xa[i].x * wb[j].x + xa[i].y * wb[j].y
                               + xa[i].z * wb[j].z + xa[i].w * wb[j].w;
        }
#pragma unroll
        for (int j = 0; j < 4; ++j) {
            int c = g * 64 + cq + 16 * j;
            float bias = c1b[c];
#pragma unroll
            for (int i = 0; i < 4; ++i)
                yout[((size_t)b * NPTS + n0 + pq * 4 + i) * 128 + c] =
                    relu_f(acc[i][j] + bias);
        }
    }
}

// ---------------------------------------------------------------------------
// K6: t2 = L2(128->128) (no relu). conv2max-style tiling.
// grid (64 ptchunks, 2 chgroups, 8 batch), block 256.
// ---------------------------------------------------------------------------
__global__ __launch_bounds__(256)
void lin2_kernel(const float* __restrict__ xin, const float* __restrict__ w,
                 const float* __restrict__ bias, float* __restrict__ out)
{
    __shared__ __align__(16) float Xs[64 * 132];
    __shared__ __align__(16) float Ws[64 * 132];
    const int chunk = blockIdx.x, g = blockIdx.y, b = blockIdx.z;
    const int tid = threadIdx.x;

    for (int i = tid; i < 64 * 32; i += 256) {
        int p = i >> 5, k4 = i & 31;
        ((float4*)(Xs + p * 132))[k4] =
            ((const float4*)(xin + ((size_t)b * NPTS + chunk * 64 + p) * 128))[k4];
        ((float4*)(Ws + p * 132))[k4] =
            ((const float4*)(w + (size_t)(g * 64 + p) * 128))[k4];
    }
    __syncthreads();

    const int pq = tid >> 4, cq = tid & 15;
    const float4* X4 = (const float4*)Xs;
    const float4* W4 = (const float4*)Ws;
    float acc[4][4];
#pragma unroll
    for (int i = 0; i < 4; ++i)
#pragma unroll
        for (int j = 0; j < 4; ++j) acc[i][j] = 0.f;

    for (int k4 = 0; k4 < 32; ++k4) {
        float4 xa[4], wb[4];
#pragma unroll
        for (int i = 0; i < 4; ++i) xa[i] = X4[(pq * 4 + i) * 33 + k4];
#pragma unroll
        for (int j = 0; j < 4; ++j) wb[j] = W4[(cq + 16 * j) * 33 + k4];
#pragma unroll
        for (int i = 0; i < 4; ++i)
#pragma unroll
            for (int j = 0; j < 4; ++j)
                acc[i][j] += xa[i].x * wb[j].x + xa[i].y * wb[j].y
                           + xa[i].z * wb[j].z + xa[i].w * wb[j].w;
    }
#pragma unroll
    for (int j = 0; j < 4; ++j) {
        int c = g * 64 + cq + 16 * j;
        float bv = bias[c];
#pragma unroll
        for (int i = 0; i < 4; ++i)
            out[((size_t)b * NPTS + chunk * 64 + pq * 4 + i) * 128 + c] =
                acc[i][j] + bv;
    }
}

// ---------------------------------------------------------------------------
// K7: conv2 (128->1024) + per-block max over 64 points, 4x4 register tile.
// ---------------------------------------------------------------------------
__global__ __launch_bounds__(256)
void conv2max_kernel(const float* __restrict__ xin, const float* __restrict__ w,
                     const float* __restrict__ bias, float* __restrict__ pmax)
{
    __shared__ __align__(16) float Xs[64 * 132];
    __shared__ __align__(16) float Ws[64 * 132];
    const int chunk = blockIdx.x, g = blockIdx.y, b = blockIdx.z;
    const int tid = threadIdx.x;

    for (int i = tid; i < 64 * 32; i += 256) {
        int p = i >> 5, k4 = i & 31;
        ((float4*)(Xs + p * 132))[k4] =
            ((const float4*)(xin + ((size_t)b * NPTS + chunk * 64 + p) * 128))[k4];
        ((float4*)(Ws + p * 132))[k4] =
            ((const float4*)(w + (size_t)(g * 64 + p) * 128))[k4];
    }
    __syncthreads();

    const int pq = tid >> 4, cq = tid & 15;
    const float4* X4 = (const float4*)Xs;
    const float4* W4 = (const float4*)Ws;
    float acc[4][4];
#pragma unroll
    for (int i = 0; i < 4; ++i)
#pragma unroll
        for (int j = 0; j < 4; ++j) acc[i][j] = 0.f;

    for (int k4 = 0; k4 < 32; ++k4) {
        float4 xa[4], wb[4];
#pragma unroll
        for (int i = 0; i < 4; ++i) xa[i] = X4[(pq * 4 + i) * 33 + k4];
#pragma unroll
        for (int j = 0; j < 4; ++j) wb[j] = W4[(cq + 16 * j) * 33 + k4];
#pragma unroll
        for (int i = 0; i < 4; ++i)
#pragma unroll
            for (int j = 0; j < 4; ++j)
                acc[i][j] += xa[i].x * wb[j].x + xa[i].y * wb[j].y
                           + xa[i].z * wb[j].z + xa[i].w * wb[j].w;
    }
#pragma unroll
    for (int j = 0; j < 4; ++j) {
        float m = fmaxf(fmaxf(acc[0][j], acc[1][j]), fmaxf(acc[2][j], acc[3][j]));
        int c = g * 64 + cq + 16 * j;
        pmax[((size_t)b * 64 + chunk) * 1024 + c] = m + bias[c];
    }
}

// ---------------------------------------------------------------------------
// K8: reduce partial maxes over 64 chunks -> gmax [B][1024]
// ---------------------------------------------------------------------------
__global__ __launch_bounds__(256)
void gmax_kernel(const float* __restrict__ pmax, float* __restrict__ gmax)
{
    int t = blockIdx.x * 256 + threadIdx.x;
    int b = t >> 10, ch = t & 1023;
    const float* pp = pmax + (size_t)b * 64 * 1024 + ch;
    float v = -FLT_MAX;
    for (int c = 0; c < 64; ++c) v = fmaxf(v, pp[c * 1024]);
    gmax[t] = v;
}

// ---------------------------------------------------------------------------
// K9a/K9b: mlp2 split wide. grid (4, 8), block 128.
// ---------------------------------------------------------------------------
__global__ __launch_bounds__(128)
void mlp2a_kernel(const float* __restrict__ g, const float* __restrict__ w1,
                  const float* __restrict__ b1, float* __restrict__ h)
{
    __shared__ __align__(16) float sg[1024];
    const int b = blockIdx.y, tid = threadIdx.x;
    for (int i = tid; i < 1024; i += 128) sg[i] = g[b * 1024 + i];
    __syncthreads();
    const int ch = blockIdx.x * 128 + tid;
    const float4* xr = (const float4*)sg;
    const float4* wr = (const float4*)(w1 + (size_t)ch * 1024);
    float a0 = 0.f, a1 = 0.f, a2 = 0.f, a3 = 0.f;
    for (int k = 0; k < 256; ++k) {
        float4 w = wr[k], x = xr[k];
        a0 += w.x * x.x; a1 += w.y * x.y; a2 += w.z * x.z; a3 += w.w * x.w;
    }
    h[b * 512 + ch] = relu_f(b1[ch] + ((a0 + a1) + (a2 + a3)));
}

__global__ __launch_bounds__(128)
void mlp2b_kernel(const float* __restrict__ h, const float* __restrict__ w2,
                  const float* __restrict__ b2, float* __restrict__ out)
{
    __shared__ __align__(16) float sh[512];
    const int b = blockIdx.y, tid = threadIdx.x;
    for (int i = tid; i < 512; i += 128) sh[i] = h[b * 512 + i];
    __syncthreads();
    const int ch = blockIdx.x * 128 + tid;
    const float4* xr = (const float4*)sh;
    const float4* wr = (const float4*)(w2 + (size_t)ch * 512);
    float a0 = 0.f, a1 = 0.f, a2 = 0.f, a3 = 0.f;
    for (int k = 0; k < 128; ++k) {
        float4 w = wr[k], x = xr[k];
        a0 += w.x * x.x; a1 += w.y * x.y; a2 += w.z * x.z; a3 += w.w * x.w;
    }
    out[b * 512 + ch] = b2[ch] + ((a0 + a1) + (a2 + a3));
}

// ---------------------------------------------------------------------------
extern "C" void kernel_launch(void* const* d_in, const int* in_sizes, int n_in,
                              void* d_out, int out_size, void* d_ws, size_t ws_size,
                              hipStream_t stream)
{
    const float* pts  = (const float*)d_in[0];
    const float* m1w1 = (const float*)d_in[1];
    const float* m1b1 = (const float*)d_in[2];
    const float* m1w2 = (const float*)d_in[3];
    const float* m1b2 = (const float*)d_in[4];
    const float* m1w3 = (const float*)d_in[5];
    const float* m1b3 = (const float*)d_in[6];
    const float* l1w  = (const float*)d_in[7];
    const float* l1b  = (const float*)d_in[8];
    const float* c1w  = (const float*)d_in[9];
    const float* c1b  = (const float*)d_in[10];
    const float* l2w  = (const float*)d_in[11];
    const float* l2b  = (const float*)d_in[12];
    const float* c2w  = (const float*)d_in[13];
    const float* c2b  = (const float*)d_in[14];
    const float* m2w1 = (const float*)d_in[15];
    const float* m2b1 = (const float*)d_in[16];
    const float* m2w2 = (const float*)d_in[17];
    const float* m2b2 = (const float*)d_in[18];

    char* ws = (char*)d_ws;
    size_t off = 0;
    int*   idx   = (int*)(ws + off);   off += (size_t)NBATCH * NPTS * KNN * 4;
    float* h3    = (float*)(ws + off); off += (size_t)NBATCH * NPTS * 64 * 4;
    float* mp1   = (float*)(ws + off); off += (size_t)NBATCH * NPTS * 64 * 4;
    float* y1    = (float*)(ws + off); off += (size_t)NBATCH * NPTS * 128 * 4;
    float* mp2   = (float*)(ws + off); off += (size_t)NBATCH * NPTS * 128 * 4;
    float* pmaxb = (float*)(ws + off); off += (size_t)NBATCH * 64 * 1024 * 4;
    float* gmx   = (float*)(ws + off); off += (size_t)NBATCH * 1024 * 4;
    float* hbuf  = (float*)(ws + off); off += (size_t)NBATCH * 512 * 4;
    float* t2    = y1;  // y1 dead after maxpool128; reuse its space

    knn_kernel<<<dim3(NPTS / 64, NBATCH), 256, 0, stream>>>(pts, idx);
    cov_mlp1_kernel<<<dim3(64, NBATCH), 256, 0, stream>>>(pts, idx, m1w1, m1b1,
                                                          m1w2, m1b2, m1w3, m1b3, h3);
    maxpool4_kernel<16><<<dim3(NBATCH * NPTS * 16 / 256), 256, 0, stream>>>(
        (const float4*)h3, idx, (float4*)mp1);
    lin_conv1_kernel<<<dim3(64, NBATCH), 256, 0, stream>>>(mp1, l1w, l1b, c1w, c1b, y1);
    maxpool4_kernel<32><<<dim3(NBATCH * NPTS * 32 / 256), 256, 0, stream>>>(
        (const float4*)y1, idx, (float4*)mp2);
    lin2_kernel<<<dim3(64, 2, NBATCH), 256, 0, stream>>>(mp2, l2w, l2b, t2);
    conv2max_kernel<<<dim3(64, 16, NBATCH), 256, 0, stream>>>(t2, c2w, c2b, pmaxb);
    gmax_kernel<<<dim3(32), 256, 0, stream>>>(pmaxb, gmx);
    mlp2a_kernel<<<dim3(4, NBATCH), 128, 0, stream>>>(gmx, m2w1, m2b1, hbuf);
    mlp2b_kernel<<<dim3(4, NBATCH), 128, 0, stream>>>(hbuf, m2w2, m2b2, (float*)d_out);
}

// Round 4
// 411.892 us; speedup vs baseline: 4.2866x; 1.1697x over previous
//
#include <hip/hip_runtime.h>
#include <cfloat>

#define NBATCH 8
#define NPTS   4096
#define KNN    16
#define PPB    32   // points per knn block
#define NSL    8    // j-slices per point

__device__ __forceinline__ float relu_f(float x) { return x > 0.f ? x : 0.f; }

// ---------------------------------------------------------------------------
// K1: KNN top-16, exact two-pass (med3 value-select + threshold rescan).
// grid (NPTS/32, NBATCH), block 256 = 32 points x 8 j-slices.
// Padded tile rows [8][129] float4 give each slice a distinct 4-bank phase
// (516*r mod 32 = 4r) -> conflict-free broadcast reads, no rotation math.
// Distance uses pd' = 2*dot - xx_j (drops the row-constant -xx_i: ranking
// within a row is unchanged; pass1/pass2 use identical FP ops so the
// threshold rescan is exact).
// ---------------------------------------------------------------------------
__global__ __launch_bounds__(256)
void knn_kernel(const float* __restrict__ pts, int* __restrict__ idxout)
{
    __shared__ __align__(16) float4 tile[NSL * 129];      // 16.5KB
    __shared__ float  kl[PPB * NSL * 16];                 // 16KB; aliased pass2
    __shared__ float  thr[PPB];
    __shared__ int    cnt[PPB];

    const int b = blockIdx.y, tid = threadIdx.x;
    const int ptl = tid >> 3, r = tid & 7;
    const int n = blockIdx.x * PPB + ptl;
    const float* pb = pts + (size_t)b * 3 * NPTS;

    const float sx = pb[n], sy = pb[NPTS + n], sz = pb[2 * NPTS + n];

    float k16[16];
#pragma unroll
    for (int s = 0; s < 16; ++s) k16[s] = -FLT_MAX;

    const float4* slice = tile + r * 129;

    // ---- PASS 1: values-only top-16 per thread (512 candidates each) ----
    for (int t = 0; t < 4; ++t) {
        if (t) __syncthreads();
        for (int i = tid; i < 1024; i += 256) {
            int j = t * 1024 + i;
            float x = pb[j], y = pb[NPTS + j], z = pb[2 * NPTS + j];
            float xx = __fadd_rn(__fadd_rn(__fmul_rn(x, x), __fmul_rn(y, y)),
                                 __fmul_rn(z, z));
            tile[(i >> 7) * 129 + (i & 127)] = make_float4(x, y, z, xx);
        }
        __syncthreads();
#pragma unroll 8
        for (int ii = 0; ii < 128; ++ii) {
            float4 c = slice[ii];
            float dt = __fmaf_rn(sx, c.x, __fmaf_rn(sy, c.y, __fmul_rn(sz, c.z)));
            float pd = __fmaf_rn(2.f, dt, -c.w);
            float old0 = k16[0];
#pragma unroll
            for (int s = 15; s >= 1; --s)
                k16[s] = __builtin_amdgcn_fmed3f(k16[s - 1], k16[s], pd);
            k16[0] = fmaxf(old0, pd);
        }
    }

#pragma unroll
    for (int s = 0; s < 16; ++s) kl[(ptl * NSL + r) * 16 + s] = k16[s];
    __syncthreads();

    if (r == 0) {   // 8-way merge of sorted-desc lists; tv = 16th largest
        const float* L = kl + ptl * 128;
        int p0 = 0, p1 = 0, p2 = 0, p3 = 0, p4 = 0, p5 = 0, p6 = 0, p7 = 0;
        float tv = 0.f;
        for (int o = 0; o < 16; ++o) {
            float v0 = L[p0], v1 = L[16 + p1], v2 = L[32 + p2], v3 = L[48 + p3];
            float v4 = L[64 + p4], v5 = L[80 + p5], v6 = L[96 + p6], v7 = L[112 + p7];
            float m = fmaxf(fmaxf(fmaxf(v0, v1), fmaxf(v2, v3)),
                            fmaxf(fmaxf(v4, v5), fmaxf(v6, v7)));
            tv = m;
            if      (v0 == m) ++p0;
            else if (v1 == m) ++p1;
            else if (v2 == m) ++p2;
            else if (v3 == m) ++p3;
            else if (v4 == m) ++p4;
            else if (v5 == m) ++p5;
            else if (v6 == m) ++p6;
            else              ++p7;
        }
        thr[ptl] = tv;
        cnt[ptl] = 0;
    }
    __syncthreads();
    const float myThr = thr[ptl];

    // ---- PASS 2: collect (pd, idx) with pd >= thr (aliases kl space) ----
    float* pv = kl;                        // [PPB][24] values
    int*   pi = (int*)(kl + PPB * 24);     // [PPB][24] indices

    for (int tt = 0; tt < 4; ++tt) {
        int t = 3 - tt;                    // tile 3 still resident from pass 1
        if (tt) {
            __syncthreads();
            for (int i = tid; i < 1024; i += 256) {
                int j = t * 1024 + i;
                float x = pb[j], y = pb[NPTS + j], z = pb[2 * NPTS + j];
                float xx = __fadd_rn(__fadd_rn(__fmul_rn(x, x), __fmul_rn(y, y)),
                                     __fmul_rn(z, z));
                tile[(i >> 7) * 129 + (i & 127)] = make_float4(x, y, z, xx);
            }
            __syncthreads();
        }
#pragma unroll 8
        for (int ii = 0; ii < 128; ++ii) {
            float4 c = slice[ii];
            float dt = __fmaf_rn(sx, c.x, __fmaf_rn(sy, c.y, __fmul_rn(sz, c.z)));
            float pd = __fmaf_rn(2.f, dt, -c.w);
            if (pd >= myThr) {
                int pos = atomicAdd(&cnt[ptl], 1);
                if (pos < 24) {
                    pv[ptl * 24 + pos] = pd;
                    pi[ptl * 24 + pos] = t * 1024 + r * 128 + ii;
                }
            }
        }
    }
    __syncthreads();

    if (tid < PPB) {   // one lane per point: exact top-16 sort
        int c = cnt[tid]; if (c > 24) c = 24;
        float* v  = pv + tid * 24;
        int*   ix = pi + tid * 24;
        int* out = idxout + ((size_t)b * NPTS + blockIdx.x * PPB + tid) * KNN;
        for (int o = 0; o < 16; ++o) {
            int best = o;
            for (int q = o + 1; q < c; ++q) {
                float vq = v[q], vb = v[best];
                if (vq > vb || (vq == vb && ix[q] < ix[best])) best = q;
            }
            float tv = v[o]; v[o] = v[best]; v[best] = tv;
            int   ti = ix[o]; ix[o] = ix[best]; ix[best] = ti;
            out[o] = ix[o];
        }
    }
}

// ---------------------------------------------------------------------------
// K2: local_cov + mlp1 (12->64->64->64), all weights staged in LDS,
// 4x4 register tile per thread per layer. grid (64, 8), block 256.
// ---------------------------------------------------------------------------
__global__ __launch_bounds__(256)
void cov_mlp1_kernel(const float* __restrict__ pts, const int* __restrict__ idx,
                     const float* __restrict__ w1, const float* __restrict__ b1,
                     const float* __restrict__ w2, const float* __restrict__ b2,
                     const float* __restrict__ w3, const float* __restrict__ b3,
                     float* __restrict__ h3out)
{
    __shared__ __align__(16) float cov[64 * 16];
    __shared__ __align__(16) float w1s[64 * 16];
    __shared__ __align__(16) float w2s[64 * 68];
    __shared__ __align__(16) float w3s[64 * 68];
    __shared__ __align__(16) float hA[64 * 68];
    __shared__ __align__(16) float hB[64 * 68];

    const int b = blockIdx.y, tid = threadIdx.x;
    const int n0 = blockIdx.x * 64;
    const int pq = tid >> 4, cq = tid & 15;

    for (int i = tid; i < 64 * 4; i += 256) {
        int p = i >> 2, k4 = i & 3;
        float4 v = make_float4(0.f, 0.f, 0.f, 0.f);
        if (k4 < 3) v = *(const float4*)(w1 + p * 12 + k4 * 4);
        ((float4*)(w1s + p * 16))[k4] = v;
    }
    for (int i = tid; i < 64 * 16; i += 256) {
        int p = i >> 4, k4 = i & 15;
        ((float4*)(w2s + p * 68))[k4] = ((const float4*)(w2 + p * 64))[k4];
        ((float4*)(w3s + p * 68))[k4] = ((const float4*)(w3 + p * 64))[k4];
    }
    if (tid < 64) {
        const int n = n0 + tid;
        const int* ip = idx + ((size_t)b * NPTS + n) * KNN;
        int j0 = ip[0], j1 = ip[1];
        const float* pb = pts + (size_t)b * 3 * NPTS;
        float px = pb[n],  py = pb[NPTS + n],  pz = pb[2 * NPTS + n];
        float ax = pb[j0], ay = pb[NPTS + j0], az = pb[2 * NPTS + j0];
        float bx = pb[j1], by = pb[NPTS + j1], bz = pb[2 * NPTS + j1];
        float* cv = cov + tid * 16;
        cv[0] = px; cv[1] = py; cv[2] = pz;
        cv[3] = ax * bx; cv[4]  = ax * by; cv[5]  = ax * bz;
        cv[6] = ay * bx; cv[7]  = ay * by; cv[8]  = ay * bz;
        cv[9] = az * bx; cv[10] = az * by; cv[11] = az * bz;
        cv[12] = 0.f; cv[13] = 0.f; cv[14] = 0.f; cv[15] = 0.f;
    }
    __syncthreads();

    {   // layer1: 12(16)->64
        float acc[4][4];
#pragma unroll
        for (int i = 0; i < 4; ++i)
#pragma unroll
            for (int j = 0; j < 4; ++j) acc[i][j] = 0.f;
        const float4* X4 = (const float4*)cov;
        const float4* W4 = (const float4*)w1s;
#pragma unroll
        for (int k4 = 0; k4 < 4; ++k4) {
            float4 xa[4], wb[4];
#pragma unroll
            for (int i = 0; i < 4; ++i) xa[i] = X4[(pq * 4 + i) * 4 + k4];
#pragma unroll
            for (int j = 0; j < 4; ++j) wb[j] = W4[(cq + 16 * j) * 4 + k4];
#pragma unroll
            for (int i = 0; i < 4; ++i)
#pragma unroll
                for (int j = 0; j < 4; ++j)
                    acc[i][j] += xa[i].x * wb[j].x + xa[i].y * wb[j].y
                               + xa[i].z * wb[j].z + xa[i].w * wb[j].w;
        }
#pragma unroll
        for (int j = 0; j < 4; ++j) {
            int c = cq + 16 * j;
            float bias = b1[c];
#pragma unroll
            for (int i = 0; i < 4; ++i)
                hA[(pq * 4 + i) * 68 + c] = relu_f(acc[i][j] + bias);
        }
    }
    __syncthreads();

    {   // layer2: 64->64
        float acc[4][4];
#pragma unroll
        for (int i = 0; i < 4; ++i)
#pragma unroll
            for (int j = 0; j < 4; ++j) acc[i][j] = 0.f;
        const float4* X4 = (const float4*)hA;
        const float4* W4 = (const float4*)w2s;
        for (int k4 = 0; k4 < 16; ++k4) {
            float4 xa[4], wb[4];
#pragma unroll
            for (int i = 0; i < 4; ++i) xa[i] = X4[(pq * 4 + i) * 17 + k4];
#pragma unroll
            for (int j = 0; j < 4; ++j) wb[j] = W4[(cq + 16 * j) * 17 + k4];
#pragma unroll
            for (int i = 0; i < 4; ++i)
#pragma unroll
                for (int j = 0; j < 4; ++j)
                    acc[i][j] += xa[i].x * wb[j].x + xa[i].y * wb[j].y
                               + xa[i].z * wb[j].z + xa[i].w * wb[j].w;
        }
#pragma unroll
        for (int j = 0; j < 4; ++j) {
            int c = cq + 16 * j;
            float bias = b2[c];
#pragma unroll
            for (int i = 0; i < 4; ++i)
                hB[(pq * 4 + i) * 68 + c] = relu_f(acc[i][j] + bias);
        }
    }
    __syncthreads();

    {   // layer3: 64->64 -> global
        float acc[4][4];
#pragma unroll
        for (int i = 0; i < 4; ++i)
#pragma unroll
            for (int j = 0; j < 4; ++j) acc[i][j] = 0.f;
        const float4* X4 = (const float4*)hB;
        const float4* W4 = (const float4*)w3s;
        for (int k4 = 0; k4 < 16; ++k4) {
            float4 xa[4], wb[4];
#pragma unroll
            for (int i = 0; i < 4; ++i) xa[i] = X4[(pq * 4 + i) * 17 + k4];
#pragma unroll
            for (int j = 0; j < 4; ++j) wb[j] = W4[(cq + 16 * j) * 17 + k4];
#pragma unroll
            for (int i = 0; i < 4; ++i)
#pragma unroll
                for (int j = 0; j < 4; ++j)
                    acc[i][j] += xa[i].x * wb[j].x + xa[i].y * wb[j].y
                               + xa[i].z * wb[j].z + xa[i].w * wb[j].w;
        }
#pragma unroll
        for (int j = 0; j < 4; ++j) {
            int c = cq + 16 * j;
            float bias = b3[c];
#pragma unroll
            for (int i = 0; i < 4; ++i)
                h3out[((size_t)b * NPTS + n0 + pq * 4 + i) * 64 + c] =
                    relu_f(acc[i][j] + bias);
        }
    }
}

// ---------------------------------------------------------------------------
// K3/K5: neighbor max-pool, float4 per thread. DV4 = D/4 (16 or 32).
// ---------------------------------------------------------------------------
template <int DV4>
__global__ __launch_bounds__(256)
void maxpool4_kernel(const float4* __restrict__ f, const int* __restrict__ idx,
                     float4* __restrict__ out)
{
    constexpr int SH = (DV4 == 16) ? 4 : 5;
    int t = blockIdx.x * 256 + threadIdx.x;
    int d4 = t & (DV4 - 1);
    int n  = (t >> SH) & (NPTS - 1);
    int b  = t >> (SH + 12);
    const int* ip = idx + ((size_t)b * NPTS + n) * KNN;
    const float4* fb = f + (size_t)b * NPTS * DV4;
    float4 v = make_float4(-FLT_MAX, -FLT_MAX, -FLT_MAX, -FLT_MAX);
#pragma unroll
    for (int k = 0; k < KNN; ++k) {
        float4 c = fb[(size_t)ip[k] * DV4 + d4];
        v.x = fmaxf(v.x, c.x); v.y = fmaxf(v.y, c.y);
        v.z = fmaxf(v.z, c.z); v.w = fmaxf(v.w, c.w);
    }
    out[t] = v;
}

// ---------------------------------------------------------------------------
// K4: t1 = L1(64->64) (no relu); y1 = relu(C1(64->128))
// ---------------------------------------------------------------------------
__global__ __launch_bounds__(256)
void lin_conv1_kernel(const float* __restrict__ xin,
                      const float* __restrict__ l1w, const float* __restrict__ l1b,
                      const float* __restrict__ c1w, const float* __restrict__ c1b,
                      float* __restrict__ yout)
{
    __shared__ __align__(16) float sx[64 * 68];
    __shared__ __align__(16) float wbuf[64 * 68];
    __shared__ __align__(16) float t1[64 * 68];
    const int b = blockIdx.y, tid = threadIdx.x;
    const int n0 = blockIdx.x * 64;
    const int pq = tid >> 4, cq = tid & 15;

    for (int i = tid; i < 64 * 16; i += 256) {
        int p = i >> 4, k4 = i & 15;
        ((float4*)(sx + p * 68))[k4] =
            ((const float4*)(xin + ((size_t)b * NPTS + n0 + p) * 64))[k4];
        ((float4*)(wbuf + p * 68))[k4] = ((const float4*)(l1w + p * 64))[k4];
    }
    __syncthreads();

    {   // L1: 64->64, no relu, +bias -> t1
        float acc[4][4];
#pragma unroll
        for (int i = 0; i < 4; ++i)
#pragma unroll
            for (int j = 0; j < 4; ++j) acc[i][j] = 0.f;
        const float4* X4 = (const float4*)sx;
        const float4* W4 = (const float4*)wbuf;
        for (int k4 = 0; k4 < 16; ++k4) {
            float4 xa[4], wb[4];
#pragma unroll
            for (int i = 0; i < 4; ++i) xa[i] = X4[(pq * 4 + i) * 17 + k4];
#pragma unroll
            for (int j = 0; j < 4; ++j) wb[j] = W4[(cq + 16 * j) * 17 + k4];
#pragma unroll
            for (int i = 0; i < 4; ++i)
#pragma unroll
                for (int j = 0; j < 4; ++j)
                    acc[i][j] += xa[i].x * wb[j].x + xa[i].y * wb[j].y
                               + xa[i].z * wb[j].z + xa[i].w * wb[j].w;
        }
#pragma unroll
        for (int j = 0; j < 4; ++j) {
            int c = cq + 16 * j;
            float bias = l1b[c];
#pragma unroll
            for (int i = 0; i < 4; ++i)
                t1[(pq * 4 + i) * 68 + c] = acc[i][j] + bias;
        }
    }

    for (int g = 0; g < 2; ++g) {
        __syncthreads();
        for (int i = tid; i < 64 * 16; i += 256) {
            int p = i >> 4, k4 = i & 15;
            ((float4*)(wbuf + p * 68))[k4] =
                ((const float4*)(c1w + (size_t)(g * 64 + p) * 64))[k4];
        }
        __syncthreads();
        float acc[4][4];
#pragma unroll
        for (int i = 0; i < 4; ++i)
#pragma unroll
            for (int j = 0; j < 4; ++j) acc[i][j] = 0.f;
        const float4* X4 = (const float4*)t1;
        const float4* W4 = (const float4*)wbuf;
        for (int k4 = 0; k4 < 16; ++k4) {
            float4 xa[4], wb[4];
#pragma unroll
            for (int i = 0; i < 4; ++i) xa[i] = X4[(pq * 4 + i) * 17 + k4];
#pragma unroll
            for (int j = 0; j < 4; ++j) wb[j] = W4[(cq + 16 * j) * 17 + k4];
#pragma unroll
            for (int i = 0; i < 4; ++i)
#pragma unroll
                for (int j = 0; j < 4; ++j)
                    acc[i][j] += xa[i].x * wb[j].x + xa[i].y * wb[j].y
                               + xa[i].z * wb[j].z + xa[i].w * wb[j].w;
        }
#pragma unroll
        for (int j = 0; j < 4; ++j) {
            int c = g * 64 + cq + 16 * j;
            float bias = c1b[c];
#pragma unroll
            for (int i = 0; i < 4; ++i)
                yout[((size_t)b * NPTS + n0 + pq * 4 + i) * 128 + c] =
                    relu_f(acc[i][j] + bias);
        }
    }
}

// ---------------------------------------------------------------------------
// K6: t2 = L2(128->128) (no relu). grid (64, 2, 8), block 256.
// ---------------------------------------------------------------------------
__global__ __launch_bounds__(256)
void lin2_kernel(const float* __restrict__ xin, const float* __restrict__ w,
                 const float* __restrict__ bias, float* __restrict__ out)
{
    __shared__ __align__(16) float Xs[64 * 132];
    __shared__ __align__(16) float Ws[64 * 132];
    const int chunk = blockIdx.x, g = blockIdx.y, b = blockIdx.z;
    const int tid = threadIdx.x;

    for (int i = tid; i < 64 * 32; i += 256) {
        int p = i >> 5, k4 = i & 31;
        ((float4*)(Xs + p * 132))[k4] =
            ((const float4*)(xin + ((size_t)b * NPTS + chunk * 64 + p) * 128))[k4];
        ((float4*)(Ws + p * 132))[k4] =
            ((const float4*)(w + (size_t)(g * 64 + p) * 128))[k4];
    }
    __syncthreads();

    const int pq = tid >> 4, cq = tid & 15;
    const float4* X4 = (const float4*)Xs;
    const float4* W4 = (const float4*)Ws;
    float acc[4][4];
#pragma unroll
    for (int i = 0; i < 4; ++i)
#pragma unroll
        for (int j = 0; j < 4; ++j) acc[i][j] = 0.f;

    for (int k4 = 0; k4 < 32; ++k4) {
        float4 xa[4], wb[4];
#pragma unroll
        for (int i = 0; i < 4; ++i) xa[i] = X4[(pq * 4 + i) * 33 + k4];
#pragma unroll
        for (int j = 0; j < 4; ++j) wb[j] = W4[(cq + 16 * j) * 33 + k4];
#pragma unroll
        for (int i = 0; i < 4; ++i)
#pragma unroll
            for (int j = 0; j < 4; ++j)
                acc[i][j] += xa[i].x * wb[j].x + xa[i].y * wb[j].y
                           + xa[i].z * wb[j].z + xa[i].w * wb[j].w;
    }
#pragma unroll
    for (int j = 0; j < 4; ++j) {
        int c = g * 64 + cq + 16 * j;
        float bv = bias[c];
#pragma unroll
        for (int i = 0; i < 4; ++i)
            out[((size_t)b * NPTS + chunk * 64 + pq * 4 + i) * 128 + c] =
                acc[i][j] + bv;
    }
}

// ---------------------------------------------------------------------------
// K7: conv2 (128->1024) + per-block max over 64 points, 4x4 register tile.
// ---------------------------------------------------------------------------
__global__ __launch_bounds__(256)
void conv2max_kernel(const float* __restrict__ xin, const float* __restrict__ w,
                     const float* __restrict__ bias, float* __restrict__ pmax)
{
    __shared__ __align__(16) float Xs[64 * 132];
    __shared__ __align__(16) float Ws[64 * 132];
    const int chunk = blockIdx.x, g = blockIdx.y, b = blockIdx.z;
    const int tid = threadIdx.x;

    for (int i = tid; i < 64 * 32; i += 256) {
        int p = i >> 5, k4 = i & 31;
        ((float4*)(Xs + p * 132))[k4] =
            ((const float4*)(xin + ((size_t)b * NPTS + chunk * 64 + p) * 128))[k4];
        ((float4*)(Ws + p * 132))[k4] =
            ((const float4*)(w + (size_t)(g * 64 + p) * 128))[k4];
    }
    __syncthreads();

    const int pq = tid >> 4, cq = tid & 15;
    const float4* X4 = (const float4*)Xs;
    const float4* W4 = (const float4*)Ws;
    float acc[4][4];
#pragma unroll
    for (int i = 0; i < 4; ++i)
#pragma unroll
        for (int j = 0; j < 4; ++j) acc[i][j] = 0.f;

    for (int k4 = 0; k4 < 32; ++k4) {
        float4 xa[4], wb[4];
#pragma unroll
        for (int i = 0; i < 4; ++i) xa[i] = X4[(pq * 4 + i) * 33 + k4];
#pragma unroll
        for (int j = 0; j < 4; ++j) wb[j] = W4[(cq + 16 * j) * 33 + k4];
#pragma unroll
        for (int i = 0; i < 4; ++i)
#pragma unroll
            for (int j = 0; j < 4; ++j)
                acc[i][j] += xa[i].x * wb[j].x + xa[i].y * wb[j].y
                           + xa[i].z * wb[j].z + xa[i].w * wb[j].w;
    }
#pragma unroll
    for (int j = 0; j < 4; ++j) {
        float m = fmaxf(fmaxf(acc[0][j], acc[1][j]), fmaxf(acc[2][j], acc[3][j]));
        int c = g * 64 + cq + 16 * j;
        pmax[((size_t)b * 64 + chunk) * 1024 + c] = m + bias[c];
    }
}

// ---------------------------------------------------------------------------
// K8: reduce partial maxes over 64 chunks -> gmax [B][1024]
// ---------------------------------------------------------------------------
__global__ __launch_bounds__(256)
void gmax_kernel(const float* __restrict__ pmax, float* __restrict__ gmax)
{
    int t = blockIdx.x * 256 + threadIdx.x;
    int b = t >> 10, ch = t & 1023;
    const float* pp = pmax + (size_t)b * 64 * 1024 + ch;
    float v = -FLT_MAX;
    for (int c = 0; c < 64; ++c) v = fmaxf(v, pp[c * 1024]);
    gmax[t] = v;
}

// ---------------------------------------------------------------------------
// K9a/K9b: mlp2 split wide. grid (4, 8), block 128.
// ---------------------------------------------------------------------------
__global__ __launch_bounds__(128)
void mlp2a_kernel(const float* __restrict__ g, const float* __restrict__ w1,
                  const float* __restrict__ b1, float* __restrict__ h)
{
    __shared__ __align__(16) float sg[1024];
    const int b = blockIdx.y, tid = threadIdx.x;
    for (int i = tid; i < 1024; i += 128) sg[i] = g[b * 1024 + i];
    __syncthreads();
    const int ch = blockIdx.x * 128 + tid;
    const float4* xr = (const float4*)sg;
    const float4* wr = (const float4*)(w1 + (size_t)ch * 1024);
    float a0 = 0.f, a1 = 0.f, a2 = 0.f, a3 = 0.f;
    for (int k = 0; k < 256; ++k) {
        float4 w = wr[k], x = xr[k];
        a0 += w.x * x.x; a1 += w.y * x.y; a2 += w.z * x.z; a3 += w.w * x.w;
    }
    h[b * 512 + ch] = relu_f(b1[ch] + ((a0 + a1) + (a2 + a3)));
}

__global__ __launch_bounds__(128)
void mlp2b_kernel(const float* __restrict__ h, const float* __restrict__ w2,
                  const float* __restrict__ b2, float* __restrict__ out)
{
    __shared__ __align__(16) float sh[512];
    const int b = blockIdx.y, tid = threadIdx.x;
    for (int i = tid; i < 512; i += 128) sh[i] = h[b * 512 + i];
    __syncthreads();
    const int ch = blockIdx.x * 128 + tid;
    const float4* xr = (const float4*)sh;
    const float4* wr = (const float4*)(w2 + (size_t)ch * 512);
    float a0 = 0.f, a1 = 0.f, a2 = 0.f, a3 = 0.f;
    for (int k = 0; k < 128; ++k) {
        float4 w = wr[k], x = xr[k];
        a0 += w.x * x.x; a1 += w.y * x.y; a2 += w.z * x.z; a3 += w.w * x.w;
    }
    out[b * 512 + ch] = b2[ch] + ((a0 + a1) + (a2 + a3));
}

// ---------------------------------------------------------------------------
extern "C" void kernel_launch(void* const* d_in, const int* in_sizes, int n_in,
                              void* d_out, int out_size, void* d_ws, size_t ws_size,
                              hipStream_t stream)
{
    const float* pts  = (const float*)d_in[0];
    const float* m1w1 = (const float*)d_in[1];
    const float* m1b1 = (const float*)d_in[2];
    const float* m1w2 = (const float*)d_in[3];
    const float* m1b2 = (const float*)d_in[4];
    const float* m1w3 = (const float*)d_in[5];
    const float* m1b3 = (const float*)d_in[6];
    const float* l1w  = (const float*)d_in[7];
    const float* l1b  = (const float*)d_in[8];
    const float* c1w  = (const float*)d_in[9];
    const float* c1b  = (const float*)d_in[10];
    const float* l2w  = (const float*)d_in[11];
    const float* l2b  = (const float*)d_in[12];
    const float* c2w  = (const float*)d_in[13];
    const float* c2b  = (const float*)d_in[14];
    const float* m2w1 = (const float*)d_in[15];
    const float* m2b1 = (const float*)d_in[16];
    const float* m2w2 = (const float*)d_in[17];
    const float* m2b2 = (const float*)d_in[18];

    char* ws = (char*)d_ws;
    size_t off = 0;
    int*   idx   = (int*)(ws + off);   off += (size_t)NBATCH * NPTS * KNN * 4;
    float* h3    = (float*)(ws + off); off += (size_t)NBATCH * NPTS * 64 * 4;
    float* mp1   = (float*)(ws + off); off += (size_t)NBATCH * NPTS * 64 * 4;
    float* y1    = (float*)(ws + off); off += (size_t)NBATCH * NPTS * 128 * 4;
    float* mp2   = (float*)(ws + off); off += (size_t)NBATCH * NPTS * 128 * 4;
    float* pmaxb = (float*)(ws + off); off += (size_t)NBATCH * 64 * 1024 * 4;
    float* gmx   = (float*)(ws + off); off += (size_t)NBATCH * 1024 * 4;
    float* hbuf  = (float*)(ws + off); off += (size_t)NBATCH * 512 * 4;
    float* t2    = y1;  // y1 dead after maxpool128; reuse its space

    knn_kernel<<<dim3(NPTS / PPB, NBATCH), 256, 0, stream>>>(pts, idx);
    cov_mlp1_kernel<<<dim3(64, NBATCH), 256, 0, stream>>>(pts, idx, m1w1, m1b1,
                                                          m1w2, m1b2, m1w3, m1b3, h3);
    maxpool4_kernel<16><<<dim3(NBATCH * NPTS * 16 / 256), 256, 0, stream>>>(
        (const float4*)h3, idx, (float4*)mp1);
    lin_conv1_kernel<<<dim3(64, NBATCH), 256, 0, stream>>>(mp1, l1w, l1b, c1w, c1b, y1);
    maxpool4_kernel<32><<<dim3(NBATCH * NPTS * 32 / 256), 256, 0, stream>>>(
        (const float4*)y1, idx, (float4*)mp2);
    lin2_kernel<<<dim3(64, 2, NBATCH), 256, 0, stream>>>(mp2, l2w, l2b, t2);
    conv2max_kernel<<<dim3(64, 16, NBATCH), 256, 0, stream>>>(t2, c2w, c2b, pmaxb);
    gmax_kernel<<<dim3(32), 256, 0, stream>>>(pmaxb, gmx);
    mlp2a_kernel<<<dim3(4, NBATCH), 128, 0, stream>>>(gmx, m2w1, m2b1, hbuf);
    mlp2b_kernel<<<dim3(4, NBATCH), 128, 0, stream>>>(hbuf, m2w2, m2b2, (float*)d_out);
}

// Round 5
// 379.743 us; speedup vs baseline: 4.6495x; 1.0847x over previous
//
#include <hip/hip_runtime.h>
#include <cfloat>

#define NBATCH 8
#define NPTS   4096
#define KNN    16
#define PPB    32   // points per knn block
#define NSL    8    // j-slices per point

__device__ __forceinline__ float relu_f(float x) { return x > 0.f ? x : 0.f; }

// ---------------------------------------------------------------------------
// K1: KNN top-16, exact two-pass (med3 value-select + threshold rescan).
// grid (NPTS/32, NBATCH), block 256 = 32 points x 8 j-slices. (unchanged)
// ---------------------------------------------------------------------------
__global__ __launch_bounds__(256)
void knn_kernel(const float* __restrict__ pts, int* __restrict__ idxout)
{
    __shared__ __align__(16) float4 tile[NSL * 129];      // 16.5KB
    __shared__ float  kl[PPB * NSL * 16];                 // 16KB; aliased pass2
    __shared__ float  thr[PPB];
    __shared__ int    cnt[PPB];

    const int b = blockIdx.y, tid = threadIdx.x;
    const int ptl = tid >> 3, r = tid & 7;
    const int n = blockIdx.x * PPB + ptl;
    const float* pb = pts + (size_t)b * 3 * NPTS;

    const float sx = pb[n], sy = pb[NPTS + n], sz = pb[2 * NPTS + n];

    float k16[16];
#pragma unroll
    for (int s = 0; s < 16; ++s) k16[s] = -FLT_MAX;

    const float4* slice = tile + r * 129;

    // ---- PASS 1: values-only top-16 per thread (512 candidates each) ----
    for (int t = 0; t < 4; ++t) {
        if (t) __syncthreads();
        for (int i = tid; i < 1024; i += 256) {
            int j = t * 1024 + i;
            float x = pb[j], y = pb[NPTS + j], z = pb[2 * NPTS + j];
            float xx = __fadd_rn(__fadd_rn(__fmul_rn(x, x), __fmul_rn(y, y)),
                                 __fmul_rn(z, z));
            tile[(i >> 7) * 129 + (i & 127)] = make_float4(x, y, z, xx);
        }
        __syncthreads();
#pragma unroll 8
        for (int ii = 0; ii < 128; ++ii) {
            float4 c = slice[ii];
            float dt = __fmaf_rn(sx, c.x, __fmaf_rn(sy, c.y, __fmul_rn(sz, c.z)));
            float pd = __fmaf_rn(2.f, dt, -c.w);
            float old0 = k16[0];
#pragma unroll
            for (int s = 15; s >= 1; --s)
                k16[s] = __builtin_amdgcn_fmed3f(k16[s - 1], k16[s], pd);
            k16[0] = fmaxf(old0, pd);
        }
    }

#pragma unroll
    for (int s = 0; s < 16; ++s) kl[(ptl * NSL + r) * 16 + s] = k16[s];
    __syncthreads();

    if (r == 0) {   // 8-way merge of sorted-desc lists; tv = 16th largest
        const float* L = kl + ptl * 128;
        int p0 = 0, p1 = 0, p2 = 0, p3 = 0, p4 = 0, p5 = 0, p6 = 0, p7 = 0;
        float tv = 0.f;
        for (int o = 0; o < 16; ++o) {
            float v0 = L[p0], v1 = L[16 + p1], v2 = L[32 + p2], v3 = L[48 + p3];
            float v4 = L[64 + p4], v5 = L[80 + p5], v6 = L[96 + p6], v7 = L[112 + p7];
            float m = fmaxf(fmaxf(fmaxf(v0, v1), fmaxf(v2, v3)),
                            fmaxf(fmaxf(v4, v5), fmaxf(v6, v7)));
            tv = m;
            if      (v0 == m) ++p0;
            else if (v1 == m) ++p1;
            else if (v2 == m) ++p2;
            else if (v3 == m) ++p3;
            else if (v4 == m) ++p4;
            else if (v5 == m) ++p5;
            else if (v6 == m) ++p6;
            else              ++p7;
        }
        thr[ptl] = tv;
        cnt[ptl] = 0;
    }
    __syncthreads();
    const float myThr = thr[ptl];

    // ---- PASS 2: collect (pd, idx) with pd >= thr (aliases kl space) ----
    float* pv = kl;                        // [PPB][24] values
    int*   pi = (int*)(kl + PPB * 24);     // [PPB][24] indices

    for (int tt = 0; tt < 4; ++tt) {
        int t = 3 - tt;                    // tile 3 still resident from pass 1
        if (tt) {
            __syncthreads();
            for (int i = tid; i < 1024; i += 256) {
                int j = t * 1024 + i;
                float x = pb[j], y = pb[NPTS + j], z = pb[2 * NPTS + j];
                float xx = __fadd_rn(__fadd_rn(__fmul_rn(x, x), __fmul_rn(y, y)),
                                     __fmul_rn(z, z));
                tile[(i >> 7) * 129 + (i & 127)] = make_float4(x, y, z, xx);
            }
            __syncthreads();
        }
#pragma unroll 8
        for (int ii = 0; ii < 128; ++ii) {
            float4 c = slice[ii];
            float dt = __fmaf_rn(sx, c.x, __fmaf_rn(sy, c.y, __fmul_rn(sz, c.z)));
            float pd = __fmaf_rn(2.f, dt, -c.w);
            if (pd >= myThr) {
                int pos = atomicAdd(&cnt[ptl], 1);
                if (pos < 24) {
                    pv[ptl * 24 + pos] = pd;
                    pi[ptl * 24 + pos] = t * 1024 + r * 128 + ii;
                }
            }
        }
    }
    __syncthreads();

    if (tid < PPB) {   // one lane per point: exact top-16 sort
        int c = cnt[tid]; if (c > 24) c = 24;
        float* v  = pv + tid * 24;
        int*   ix = pi + tid * 24;
        int* out = idxout + ((size_t)b * NPTS + blockIdx.x * PPB + tid) * KNN;
        for (int o = 0; o < 16; ++o) {
            int best = o;
            for (int q = o + 1; q < c; ++q) {
                float vq = v[q], vb = v[best];
                if (vq > vb || (vq == vb && ix[q] < ix[best])) best = q;
            }
            float tv = v[o]; v[o] = v[best]; v[best] = tv;
            int   ti = ix[o]; ix[o] = ix[best]; ix[best] = ti;
            out[o] = ix[o];
        }
    }
}

// ---------------------------------------------------------------------------
// K2: local_cov + mlp1 (12->64->64->64), weights in LDS, 4x4 tiles. (unchanged)
// ---------------------------------------------------------------------------
__global__ __launch_bounds__(256)
void cov_mlp1_kernel(const float* __restrict__ pts, const int* __restrict__ idx,
                     const float* __restrict__ w1, const float* __restrict__ b1,
                     const float* __restrict__ w2, const float* __restrict__ b2,
                     const float* __restrict__ w3, const float* __restrict__ b3,
                     float* __restrict__ h3out)
{
    __shared__ __align__(16) float cov[64 * 16];
    __shared__ __align__(16) float w1s[64 * 16];
    __shared__ __align__(16) float w2s[64 * 68];
    __shared__ __align__(16) float w3s[64 * 68];
    __shared__ __align__(16) float hA[64 * 68];
    __shared__ __align__(16) float hB[64 * 68];

    const int b = blockIdx.y, tid = threadIdx.x;
    const int n0 = blockIdx.x * 64;
    const int pq = tid >> 4, cq = tid & 15;

    for (int i = tid; i < 64 * 4; i += 256) {
        int p = i >> 2, k4 = i & 3;
        float4 v = make_float4(0.f, 0.f, 0.f, 0.f);
        if (k4 < 3) v = *(const float4*)(w1 + p * 12 + k4 * 4);
        ((float4*)(w1s + p * 16))[k4] = v;
    }
    for (int i = tid; i < 64 * 16; i += 256) {
        int p = i >> 4, k4 = i & 15;
        ((float4*)(w2s + p * 68))[k4] = ((const float4*)(w2 + p * 64))[k4];
        ((float4*)(w3s + p * 68))[k4] = ((const float4*)(w3 + p * 64))[k4];
    }
    if (tid < 64) {
        const int n = n0 + tid;
        const int* ip = idx + ((size_t)b * NPTS + n) * KNN;
        int j0 = ip[0], j1 = ip[1];
        const float* pb = pts + (size_t)b * 3 * NPTS;
        float px = pb[n],  py = pb[NPTS + n],  pz = pb[2 * NPTS + n];
        float ax = pb[j0], ay = pb[NPTS + j0], az = pb[2 * NPTS + j0];
        float bx = pb[j1], by = pb[NPTS + j1], bz = pb[2 * NPTS + j1];
        float* cv = cov + tid * 16;
        cv[0] = px; cv[1] = py; cv[2] = pz;
        cv[3] = ax * bx; cv[4]  = ax * by; cv[5]  = ax * bz;
        cv[6] = ay * bx; cv[7]  = ay * by; cv[8]  = ay * bz;
        cv[9] = az * bx; cv[10] = az * by; cv[11] = az * bz;
        cv[12] = 0.f; cv[13] = 0.f; cv[14] = 0.f; cv[15] = 0.f;
    }
    __syncthreads();

    {   // layer1: 12(16)->64
        float acc[4][4];
#pragma unroll
        for (int i = 0; i < 4; ++i)
#pragma unroll
            for (int j = 0; j < 4; ++j) acc[i][j] = 0.f;
        const float4* X4 = (const float4*)cov;
        const float4* W4 = (const float4*)w1s;
#pragma unroll
        for (int k4 = 0; k4 < 4; ++k4) {
            float4 xa[4], wb[4];
#pragma unroll
            for (int i = 0; i < 4; ++i) xa[i] = X4[(pq * 4 + i) * 4 + k4];
#pragma unroll
            for (int j = 0; j < 4; ++j) wb[j] = W4[(cq + 16 * j) * 4 + k4];
#pragma unroll
            for (int i = 0; i < 4; ++i)
#pragma unroll
                for (int j = 0; j < 4; ++j)
                    acc[i][j] += xa[i].x * wb[j].x + xa[i].y * wb[j].y
                               + xa[i].z * wb[j].z + xa[i].w * wb[j].w;
        }
#pragma unroll
        for (int j = 0; j < 4; ++j) {
            int c = cq + 16 * j;
            float bias = b1[c];
#pragma unroll
            for (int i = 0; i < 4; ++i)
                hA[(pq * 4 + i) * 68 + c] = relu_f(acc[i][j] + bias);
        }
    }
    __syncthreads();

    {   // layer2: 64->64
        float acc[4][4];
#pragma unroll
        for (int i = 0; i < 4; ++i)
#pragma unroll
            for (int j = 0; j < 4; ++j) acc[i][j] = 0.f;
        const float4* X4 = (const float4*)hA;
        const float4* W4 = (const float4*)w2s;
        for (int k4 = 0; k4 < 16; ++k4) {
            float4 xa[4], wb[4];
#pragma unroll
            for (int i = 0; i < 4; ++i) xa[i] = X4[(pq * 4 + i) * 17 + k4];
#pragma unroll
            for (int j = 0; j < 4; ++j) wb[j] = W4[(cq + 16 * j) * 17 + k4];
#pragma unroll
            for (int i = 0; i < 4; ++i)
#pragma unroll
                for (int j = 0; j < 4; ++j)
                    acc[i][j] += xa[i].x * wb[j].x + xa[i].y * wb[j].y
                               + xa[i].z * wb[j].z + xa[i].w * wb[j].w;
        }
#pragma unroll
        for (int j = 0; j < 4; ++j) {
            int c = cq + 16 * j;
            float bias = b2[c];
#pragma unroll
            for (int i = 0; i < 4; ++i)
                hB[(pq * 4 + i) * 68 + c] = relu_f(acc[i][j] + bias);
        }
    }
    __syncthreads();

    {   // layer3: 64->64 -> global
        float acc[4][4];
#pragma unroll
        for (int i = 0; i < 4; ++i)
#pragma unroll
            for (int j = 0; j < 4; ++j) acc[i][j] = 0.f;
        const float4* X4 = (const float4*)hB;
        const float4* W4 = (const float4*)w3s;
        for (int k4 = 0; k4 < 16; ++k4) {
            float4 xa[4], wb[4];
#pragma unroll
            for (int i = 0; i < 4; ++i) xa[i] = X4[(pq * 4 + i) * 17 + k4];
#pragma unroll
            for (int j = 0; j < 4; ++j) wb[j] = W4[(cq + 16 * j) * 17 + k4];
#pragma unroll
            for (int i = 0; i < 4; ++i)
#pragma unroll
                for (int j = 0; j < 4; ++j)
                    acc[i][j] += xa[i].x * wb[j].x + xa[i].y * wb[j].y
                               + xa[i].z * wb[j].z + xa[i].w * wb[j].w;
        }
#pragma unroll
        for (int j = 0; j < 4; ++j) {
            int c = cq + 16 * j;
            float bias = b3[c];
#pragma unroll
            for (int i = 0; i < 4; ++i)
                h3out[((size_t)b * NPTS + n0 + pq * 4 + i) * 64 + c] =
                    relu_f(acc[i][j] + bias);
        }
    }
}

// ---------------------------------------------------------------------------
// K3/K5: neighbor max-pool, float4 per thread. DV4 = D/4 (16 or 32).
// ---------------------------------------------------------------------------
template <int DV4>
__global__ __launch_bounds__(256)
void maxpool4_kernel(const float4* __restrict__ f, const int* __restrict__ idx,
                     float4* __restrict__ out)
{
    constexpr int SH = (DV4 == 16) ? 4 : 5;
    int t = blockIdx.x * 256 + threadIdx.x;
    int d4 = t & (DV4 - 1);
    int n  = (t >> SH) & (NPTS - 1);
    int b  = t >> (SH + 12);
    const int* ip = idx + ((size_t)b * NPTS + n) * KNN;
    const float4* fb = f + (size_t)b * NPTS * DV4;
    float4 v = make_float4(-FLT_MAX, -FLT_MAX, -FLT_MAX, -FLT_MAX);
#pragma unroll
    for (int k = 0; k < KNN; ++k) {
        float4 c = fb[(size_t)ip[k] * DV4 + d4];
        v.x = fmaxf(v.x, c.x); v.y = fmaxf(v.y, c.y);
        v.z = fmaxf(v.z, c.z); v.w = fmaxf(v.w, c.w);
    }
    out[t] = v;
}

// ---------------------------------------------------------------------------
// K4: t1 = L1(64->64) (no relu); y1 = relu(C1(64->128)) (unchanged)
// ---------------------------------------------------------------------------
__global__ __launch_bounds__(256)
void lin_conv1_kernel(const float* __restrict__ xin,
                      const float* __restrict__ l1w, const float* __restrict__ l1b,
                      const float* __restrict__ c1w, const float* __restrict__ c1b,
                      float* __restrict__ yout)
{
    __shared__ __align__(16) float sx[64 * 68];
    __shared__ __align__(16) float wbuf[64 * 68];
    __shared__ __align__(16) float t1[64 * 68];
    const int b = blockIdx.y, tid = threadIdx.x;
    const int n0 = blockIdx.x * 64;
    const int pq = tid >> 4, cq = tid & 15;

    for (int i = tid; i < 64 * 16; i += 256) {
        int p = i >> 4, k4 = i & 15;
        ((float4*)(sx + p * 68))[k4] =
            ((const float4*)(xin + ((size_t)b * NPTS + n0 + p) * 64))[k4];
        ((float4*)(wbuf + p * 68))[k4] = ((const float4*)(l1w + p * 64))[k4];
    }
    __syncthreads();

    {   // L1: 64->64, no relu, +bias -> t1
        float acc[4][4];
#pragma unroll
        for (int i = 0; i < 4; ++i)
#pragma unroll
            for (int j = 0; j < 4; ++j) acc[i][j] = 0.f;
        const float4* X4 = (const float4*)sx;
        const float4* W4 = (const float4*)wbuf;
        for (int k4 = 0; k4 < 16; ++k4) {
            float4 xa[4], wb[4];
#pragma unroll
            for (int i = 0; i < 4; ++i) xa[i] = X4[(pq * 4 + i) * 17 + k4];
#pragma unroll
            for (int j = 0; j < 4; ++j) wb[j] = W4[(cq + 16 * j) * 17 + k4];
#pragma unroll
            for (int i = 0; i < 4; ++i)
#pragma unroll
                for (int j = 0; j < 4; ++j)
                    acc[i][j] += xa[i].x * wb[j].x + xa[i].y * wb[j].y
                               + xa[i].z * wb[j].z + xa[i].w * wb[j].w;
        }
#pragma unroll
        for (int j = 0; j < 4; ++j) {
            int c = cq + 16 * j;
            float bias = l1b[c];
#pragma unroll
            for (int i = 0; i < 4; ++i)
                t1[(pq * 4 + i) * 68 + c] = acc[i][j] + bias;
        }
    }

    for (int g = 0; g < 2; ++g) {
        __syncthreads();
        for (int i = tid; i < 64 * 16; i += 256) {
            int p = i >> 4, k4 = i & 15;
            ((float4*)(wbuf + p * 68))[k4] =
                ((const float4*)(c1w + (size_t)(g * 64 + p) * 64))[k4];
        }
        __syncthreads();
        float acc[4][4];
#pragma unroll
        for (int i = 0; i < 4; ++i)
#pragma unroll
            for (int j = 0; j < 4; ++j) acc[i][j] = 0.f;
        const float4* X4 = (const float4*)t1;
        const float4* W4 = (const float4*)wbuf;
        for (int k4 = 0; k4 < 16; ++k4) {
            float4 xa[4], wb[4];
#pragma unroll
            for (int i = 0; i < 4; ++i) xa[i] = X4[(pq * 4 + i) * 17 + k4];
#pragma unroll
            for (int j = 0; j < 4; ++j) wb[j] = W4[(cq + 16 * j) * 17 + k4];
#pragma unroll
            for (int i = 0; i < 4; ++i)
#pragma unroll
                for (int j = 0; j < 4; ++j)
                    acc[i][j] += xa[i].x * wb[j].x + xa[i].y * wb[j].y
                               + xa[i].z * wb[j].z + xa[i].w * wb[j].w;
        }
#pragma unroll
        for (int j = 0; j < 4; ++j) {
            int c = g * 64 + cq + 16 * j;
            float bias = c1b[c];
#pragma unroll
            for (int i = 0; i < 4; ++i)
                yout[((size_t)b * NPTS + n0 + pq * 4 + i) * 128 + c] =
                    relu_f(acc[i][j] + bias);
        }
    }
}

// ---------------------------------------------------------------------------
// K6: t2 = L2(128->128) (no relu). grid (64, 2, 8), block 256. (unchanged)
// ---------------------------------------------------------------------------
__global__ __launch_bounds__(256)
void lin2_kernel(const float* __restrict__ xin, const float* __restrict__ w,
                 const float* __restrict__ bias, float* __restrict__ out)
{
    __shared__ __align__(16) float Xs[64 * 132];
    __shared__ __align__(16) float Ws[64 * 132];
    const int chunk = blockIdx.x, g = blockIdx.y, b = blockIdx.z;
    const int tid = threadIdx.x;

    for (int i = tid; i < 64 * 32; i += 256) {
        int p = i >> 5, k4 = i & 31;
        ((float4*)(Xs + p * 132))[k4] =
            ((const float4*)(xin + ((size_t)b * NPTS + chunk * 64 + p) * 128))[k4];
        ((float4*)(Ws + p * 132))[k4] =
            ((const float4*)(w + (size_t)(g * 64 + p) * 128))[k4];
    }
    __syncthreads();

    const int pq = tid >> 4, cq = tid & 15;
    const float4* X4 = (const float4*)Xs;
    const float4* W4 = (const float4*)Ws;
    float acc[4][4];
#pragma unroll
    for (int i = 0; i < 4; ++i)
#pragma unroll
        for (int j = 0; j < 4; ++j) acc[i][j] = 0.f;

    for (int k4 = 0; k4 < 32; ++k4) {
        float4 xa[4], wb[4];
#pragma unroll
        for (int i = 0; i < 4; ++i) xa[i] = X4[(pq * 4 + i) * 33 + k4];
#pragma unroll
        for (int j = 0; j < 4; ++j) wb[j] = W4[(cq + 16 * j) * 33 + k4];
#pragma unroll
        for (int i = 0; i < 4; ++i)
#pragma unroll
            for (int j = 0; j < 4; ++j)
                acc[i][j] += xa[i].x * wb[j].x + xa[i].y * wb[j].y
                           + xa[i].z * wb[j].z + xa[i].w * wb[j].w;
    }
#pragma unroll
    for (int j = 0; j < 4; ++j) {
        int c = g * 64 + cq + 16 * j;
        float bv = bias[c];
#pragma unroll
        for (int i = 0; i < 4; ++i)
            out[((size_t)b * NPTS + chunk * 64 + pq * 4 + i) * 128 + c] =
                acc[i][j] + bv;
    }
}

// ---------------------------------------------------------------------------
// K7: conv2 (128->1024) + per-block max over 128 points, 8x8 register tile.
// grid (32 ptchunks, 8 chgroups, 8 batch), block 256 (16 pq x 16 cq).
// Thread covers points pq+16i (i<8), channels cq+16j (j<8).
// K staged in two 64-halves: LDS 2 x 128x68 floats = 69.6 KB (2 blocks/CU).
// Per k4: 16 ds_read_b128 (xa 4-addr broadcast conflict-free, wb 2-way free)
// feeding 256 v_fma -> FMA-bound (~2.7x LDS issue headroom).
// ---------------------------------------------------------------------------
__global__ __launch_bounds__(256)
void conv2max_kernel(const float* __restrict__ xin, const float* __restrict__ w,
                     const float* __restrict__ bias, float* __restrict__ pmax)
{
    __shared__ __align__(16) float Xs[128 * 68];
    __shared__ __align__(16) float Ws[128 * 68];
    const int chunk = blockIdx.x, g = blockIdx.y, b = blockIdx.z;
    const int tid = threadIdx.x;
    const int pq = tid >> 4, cq = tid & 15;

    float acc[8][8];
#pragma unroll
    for (int i = 0; i < 8; ++i)
#pragma unroll
        for (int j = 0; j < 8; ++j) acc[i][j] = 0.f;

    for (int h = 0; h < 2; ++h) {
        __syncthreads();   // protect previous-half LDS reads
        for (int i = tid; i < 128 * 16; i += 256) {
            int p = i >> 4, k4 = i & 15;
            ((float4*)(Xs + p * 68))[k4] = *(const float4*)
                (xin + ((size_t)b * NPTS + chunk * 128 + p) * 128 + h * 64 + k4 * 4);
            ((float4*)(Ws + p * 68))[k4] = *(const float4*)
                (w + (size_t)(g * 128 + p) * 128 + h * 64 + k4 * 4);
        }
        __syncthreads();

        const float4* X4 = (const float4*)Xs;   // row stride 17 float4
        const float4* W4 = (const float4*)Ws;
        for (int k4 = 0; k4 < 16; ++k4) {
            float4 xa[8], wb[8];
#pragma unroll
            for (int i = 0; i < 8; ++i) xa[i] = X4[(pq + 16 * i) * 17 + k4];
#pragma unroll
            for (int j = 0; j < 8; ++j) wb[j] = W4[(cq + 16 * j) * 17 + k4];
#pragma unroll
            for (int i = 0; i < 8; ++i)
#pragma unroll
                for (int j = 0; j < 8; ++j)
                    acc[i][j] += xa[i].x * wb[j].x + xa[i].y * wb[j].y
                               + xa[i].z * wb[j].z + xa[i].w * wb[j].w;
        }
    }

    // reduce max over the 128 points of this chunk
    __syncthreads();
    float* smax = Xs;                       // reuse: [16][132]
#pragma unroll
    for (int j = 0; j < 8; ++j) {
        float m = acc[0][j];
#pragma unroll
        for (int i = 1; i < 8; ++i) m = fmaxf(m, acc[i][j]);
        smax[pq * 132 + cq + 16 * j] = m;
    }
    __syncthreads();
    if (tid < 128) {
        float v = smax[tid];
#pragma unroll
        for (int q = 1; q < 16; ++q) v = fmaxf(v, smax[q * 132 + tid]);
        int c = g * 128 + tid;
        pmax[((size_t)b * 32 + chunk) * 1024 + c] = v + bias[c];
    }
}

// ---------------------------------------------------------------------------
// K8: reduce partial maxes over 32 chunks -> gmax [B][1024]
// ---------------------------------------------------------------------------
__global__ __launch_bounds__(256)
void gmax_kernel(const float* __restrict__ pmax, float* __restrict__ gmax)
{
    int t = blockIdx.x * 256 + threadIdx.x;
    int b = t >> 10, ch = t & 1023;
    const float* pp = pmax + (size_t)b * 32 * 1024 + ch;
    float v = -FLT_MAX;
    for (int c = 0; c < 32; ++c) v = fmaxf(v, pp[c * 1024]);
    gmax[t] = v;
}

// ---------------------------------------------------------------------------
// K9a/K9b: mlp2 split wide. grid (4, 8), block 128.
// ---------------------------------------------------------------------------
__global__ __launch_bounds__(128)
void mlp2a_kernel(const float* __restrict__ g, const float* __restrict__ w1,
                  const float* __restrict__ b1, float* __restrict__ h)
{
    __shared__ __align__(16) float sg[1024];
    const int b = blockIdx.y, tid = threadIdx.x;
    for (int i = tid; i < 1024; i += 128) sg[i] = g[b * 1024 + i];
    __syncthreads();
    const int ch = blockIdx.x * 128 + tid;
    const float4* xr = (const float4*)sg;
    const float4* wr = (const float4*)(w1 + (size_t)ch * 1024);
    float a0 = 0.f, a1 = 0.f, a2 = 0.f, a3 = 0.f;
    for (int k = 0; k < 256; ++k) {
        float4 w = wr[k], x = xr[k];
        a0 += w.x * x.x; a1 += w.y * x.y; a2 += w.z * x.z; a3 += w.w * x.w;
    }
    h[b * 512 + ch] = relu_f(b1[ch] + ((a0 + a1) + (a2 + a3)));
}

__global__ __launch_bounds__(128)
void mlp2b_kernel(const float* __restrict__ h, const float* __restrict__ w2,
                  const float* __restrict__ b2, float* __restrict__ out)
{
    __shared__ __align__(16) float sh[512];
    const int b = blockIdx.y, tid = threadIdx.x;
    for (int i = tid; i < 512; i += 128) sh[i] = h[b * 512 + i];
    __syncthreads();
    const int ch = blockIdx.x * 128 + tid;
    const float4* xr = (const float4*)sh;
    const float4* wr = (const float4*)(w2 + (size_t)ch * 512);
    float a0 = 0.f, a1 = 0.f, a2 = 0.f, a3 = 0.f;
    for (int k = 0; k < 128; ++k) {
        float4 w = wr[k], x = xr[k];
        a0 += w.x * x.x; a1 += w.y * x.y; a2 += w.z * x.z; a3 += w.w * x.w;
    }
    out[b * 512 + ch] = b2[ch] + ((a0 + a1) + (a2 + a3));
}

// ---------------------------------------------------------------------------
extern "C" void kernel_launch(void* const* d_in, const int* in_sizes, int n_in,
                              void* d_out, int out_size, void* d_ws, size_t ws_size,
                              hipStream_t stream)
{
    const float* pts  = (const float*)d_in[0];
    const float* m1w1 = (const float*)d_in[1];
    const float* m1b1 = (const float*)d_in[2];
    const float* m1w2 = (const float*)d_in[3];
    const float* m1b2 = (const float*)d_in[4];
    const float* m1w3 = (const float*)d_in[5];
    const float* m1b3 = (const float*)d_in[6];
    const float* l1w  = (const float*)d_in[7];
    const float* l1b  = (const float*)d_in[8];
    const float* c1w  = (const float*)d_in[9];
    const float* c1b  = (const float*)d_in[10];
    const float* l2w  = (const float*)d_in[11];
    const float* l2b  = (const float*)d_in[12];
    const float* c2w  = (const float*)d_in[13];
    const float* c2b  = (const float*)d_in[14];
    const float* m2w1 = (const float*)d_in[15];
    const float* m2b1 = (const float*)d_in[16];
    const float* m2w2 = (const float*)d_in[17];
    const float* m2b2 = (const float*)d_in[18];

    char* ws = (char*)d_ws;
    size_t off = 0;
    int*   idx   = (int*)(ws + off);   off += (size_t)NBATCH * NPTS * KNN * 4;
    float* h3    = (float*)(ws + off); off += (size_t)NBATCH * NPTS * 64 * 4;
    float* mp1   = (float*)(ws + off); off += (size_t)NBATCH * NPTS * 64 * 4;
    float* y1    = (float*)(ws + off); off += (size_t)NBATCH * NPTS * 128 * 4;
    float* mp2   = (float*)(ws + off); off += (size_t)NBATCH * NPTS * 128 * 4;
    float* pmaxb = (float*)(ws + off); off += (size_t)NBATCH * 64 * 1024 * 4;
    float* gmx   = (float*)(ws + off); off += (size_t)NBATCH * 1024 * 4;
    float* hbuf  = (float*)(ws + off); off += (size_t)NBATCH * 512 * 4;
    float* t2    = y1;  // y1 dead after maxpool128; reuse its space

    knn_kernel<<<dim3(NPTS / PPB, NBATCH), 256, 0, stream>>>(pts, idx);
    cov_mlp1_kernel<<<dim3(64, NBATCH), 256, 0, stream>>>(pts, idx, m1w1, m1b1,
                                                          m1w2, m1b2, m1w3, m1b3, h3);
    maxpool4_kernel<16><<<dim3(NBATCH * NPTS * 16 / 256), 256, 0, stream>>>(
        (const float4*)h3, idx, (float4*)mp1);
    lin_conv1_kernel<<<dim3(64, NBATCH), 256, 0, stream>>>(mp1, l1w, l1b, c1w, c1b, y1);
    maxpool4_kernel<32><<<dim3(NBATCH * NPTS * 32 / 256), 256, 0, stream>>>(
        (const float4*)y1, idx, (float4*)mp2);
    lin2_kernel<<<dim3(64, 2, NBATCH), 256, 0, stream>>>(mp2, l2w, l2b, t2);
    conv2max_kernel<<<dim3(32, 8, NBATCH), 256, 0, stream>>>(t2, c2w, c2b, pmaxb);
    gmax_kernel<<<dim3(32), 256, 0, stream>>>(pmaxb, gmx);
    mlp2a_kernel<<<dim3(4, NBATCH), 128, 0, stream>>>(gmx, m2w1, m2b1, hbuf);
    mlp2b_kernel<<<dim3(4, NBATCH), 128, 0, stream>>>(hbuf, m2w2, m2b2, (float*)d_out);
}

// Round 6
// 350.937 us; speedup vs baseline: 5.0311x; 1.0821x over previous
//
#include <hip/hip_runtime.h>
#include <cfloat>

#define NBATCH 8
#define NPTS   4096
#define KNN    16
#define PPB    32   // points per knn block
#define NSL    8    // j-slices per point
#define CAP    24   // pass-2 collection capacity per point

__device__ __forceinline__ float relu_f(float x) { return x > 0.f ? x : 0.f; }

// ---------------------------------------------------------------------------
// K1: KNN top-16, exact two-pass. Pass1 keeps only a top-8 sorted value list
// per thread (8 med3/candidate). thr = 16th-largest of the 8x8 union -- a
// subset statistic, hence <= true 16th value: always a SAFE pass-2 threshold.
// If a slice held >8 of the true top-16 (P~3e-4/point), pass2 overflows
// CAP; detected via cnt and that point is redone with an exact serial scan
// (insertion sort, ties -> lower index = lax.top_k semantics).
// grid (NPTS/32, NBATCH), block 256 = 32 points x 8 j-slices.
// ---------------------------------------------------------------------------
__global__ __launch_bounds__(256)
void knn_kernel(const float* __restrict__ pts, int* __restrict__ idxout)
{
    __shared__ __align__(16) float4 tile[NSL * 129];      // 16.5KB
    __shared__ float  kl[PPB * NSL * 8];                  // 8KB; aliased pass2
    __shared__ float  thr[PPB];
    __shared__ int    cnt[PPB];

    const int b = blockIdx.y, tid = threadIdx.x;
    const int ptl = tid >> 3, r = tid & 7;
    const int n = blockIdx.x * PPB + ptl;
    const float* pb = pts + (size_t)b * 3 * NPTS;

    const float sx = pb[n], sy = pb[NPTS + n], sz = pb[2 * NPTS + n];

    float k8[8];
#pragma unroll
    for (int s = 0; s < 8; ++s) k8[s] = -FLT_MAX;

    const float4* slice = tile + r * 129;

    // ---- PASS 1: values-only top-8 per thread (512 candidates each) ----
    for (int t = 0; t < 4; ++t) {
        if (t) __syncthreads();
        for (int i = tid; i < 1024; i += 256) {
            int j = t * 1024 + i;
            float x = pb[j], y = pb[NPTS + j], z = pb[2 * NPTS + j];
            float xx = __fadd_rn(__fadd_rn(__fmul_rn(x, x), __fmul_rn(y, y)),
                                 __fmul_rn(z, z));
            tile[(i >> 7) * 129 + (i & 127)] = make_float4(x, y, z, xx);
        }
        __syncthreads();
#pragma unroll 8
        for (int ii = 0; ii < 128; ++ii) {
            float4 c = slice[ii];
            float dt = __fmaf_rn(sx, c.x, __fmaf_rn(sy, c.y, __fmul_rn(sz, c.z)));
            float pd = __fmaf_rn(2.f, dt, -c.w);
            float old0 = k8[0];
#pragma unroll
            for (int s = 7; s >= 1; --s)
                k8[s] = __builtin_amdgcn_fmed3f(k8[s - 1], k8[s], pd);
            k8[0] = fmaxf(old0, pd);
        }
    }

#pragma unroll
    for (int s = 0; s < 8; ++s) kl[(ptl * NSL + r) * 8 + s] = k8[s];
    __syncthreads();

    if (r == 0) {   // merge 8 sorted-desc 8-lists; thr = 16th pick (<= t*)
        const float* L = kl + ptl * 64;
        int p0 = 0, p1 = 0, p2 = 0, p3 = 0, p4 = 0, p5 = 0, p6 = 0, p7 = 0;
        float tv = 0.f;
        for (int o = 0; o < 16; ++o) {
            float v0 = (p0 < 8) ? L[p0]      : -FLT_MAX;
            float v1 = (p1 < 8) ? L[8 + p1]  : -FLT_MAX;
            float v2 = (p2 < 8) ? L[16 + p2] : -FLT_MAX;
            float v3 = (p3 < 8) ? L[24 + p3] : -FLT_MAX;
            float v4 = (p4 < 8) ? L[32 + p4] : -FLT_MAX;
            float v5 = (p5 < 8) ? L[40 + p5] : -FLT_MAX;
            float v6 = (p6 < 8) ? L[48 + p6] : -FLT_MAX;
            float v7 = (p7 < 8) ? L[56 + p7] : -FLT_MAX;
            float m = fmaxf(fmaxf(fmaxf(v0, v1), fmaxf(v2, v3)),
                            fmaxf(fmaxf(v4, v5), fmaxf(v6, v7)));
            tv = m;
            if      (v0 == m) ++p0;
            else if (v1 == m) ++p1;
            else if (v2 == m) ++p2;
            else if (v3 == m) ++p3;
            else if (v4 == m) ++p4;
            else if (v5 == m) ++p5;
            else if (v6 == m) ++p6;
            else              ++p7;
        }
        thr[ptl] = tv;
        cnt[ptl] = 0;
    }
    __syncthreads();
    const float myThr = thr[ptl];

    // ---- PASS 2: collect (pd, idx) with pd >= thr (aliases kl space) ----
    float* pv = kl;                        // [PPB][CAP] values (768 floats)
    int*   pi = (int*)(kl + PPB * CAP);    // [PPB][CAP] indices

    for (int tt = 0; tt < 4; ++tt) {
        int t = 3 - tt;                    // tile 3 still resident from pass 1
        if (tt) {
            __syncthreads();
            for (int i = tid; i < 1024; i += 256) {
                int j = t * 1024 + i;
                float x = pb[j], y = pb[NPTS + j], z = pb[2 * NPTS + j];
                float xx = __fadd_rn(__fadd_rn(__fmul_rn(x, x), __fmul_rn(y, y)),
                                     __fmul_rn(z, z));
                tile[(i >> 7) * 129 + (i & 127)] = make_float4(x, y, z, xx);
            }
            __syncthreads();
        }
#pragma unroll 8
        for (int ii = 0; ii < 128; ++ii) {
            float4 c = slice[ii];
            float dt = __fmaf_rn(sx, c.x, __fmaf_rn(sy, c.y, __fmul_rn(sz, c.z)));
            float pd = __fmaf_rn(2.f, dt, -c.w);
            if (pd >= myThr) {
                int pos = atomicAdd(&cnt[ptl], 1);
                if (pos < CAP) {
                    pv[ptl * CAP + pos] = pd;
                    pi[ptl * CAP + pos] = t * 1024 + r * 128 + ii;
                }
            }
        }
    }
    __syncthreads();

    if (tid < PPB) {
        const int np = blockIdx.x * PPB + tid;
        int* out = idxout + ((size_t)b * NPTS + np) * KNN;
        int c = cnt[tid];
        if (c <= CAP) {
            // exact top-16 selection sort by (pd desc, idx asc)
            float* v  = pv + tid * CAP;
            int*   ix = pi + tid * CAP;
            for (int o = 0; o < 16; ++o) {
                int best = o;
                for (int q = o + 1; q < c; ++q) {
                    float vq = v[q], vb = v[best];
                    if (vq > vb || (vq == vb && ix[q] < ix[best])) best = q;
                }
                float tv = v[o]; v[o] = v[best]; v[best] = tv;
                int   ti = ix[o]; ix[o] = ix[best]; ix[best] = ti;
                out[o] = ix[o];
            }
        } else {
            // rare overflow (slice held >8 of top-16): exact serial re-scan
            float qx = pb[np], qy = pb[NPTS + np], qz = pb[2 * NPTS + np];
            float v16[16]; int i16[16];
#pragma unroll
            for (int s = 0; s < 16; ++s) { v16[s] = -FLT_MAX; i16[s] = 0; }
            for (int j = 0; j < NPTS; ++j) {
                float x = pb[j], y = pb[NPTS + j], z = pb[2 * NPTS + j];
                float xx = __fadd_rn(__fadd_rn(__fmul_rn(x, x), __fmul_rn(y, y)),
                                     __fmul_rn(z, z));
                float dt = __fmaf_rn(qx, x, __fmaf_rn(qy, y, __fmul_rn(qz, z)));
                float pd = __fmaf_rn(2.f, dt, -xx);
                if (pd > v16[15]) {        // strict: tie keeps earlier (lower idx)
                    int s = 15;
                    while (s > 0 && pd > v16[s - 1]) {
                        v16[s] = v16[s - 1]; i16[s] = i16[s - 1]; --s;
                    }
                    v16[s] = pd; i16[s] = j;
                }
            }
            for (int o = 0; o < 16; ++o) out[o] = i16[o];
        }
    }
}

// ---------------------------------------------------------------------------
// K2: local_cov + mlp1 (12->64->64->64), weights in LDS, 4x4 tiles. (unchanged)
// ---------------------------------------------------------------------------
__global__ __launch_bounds__(256)
void cov_mlp1_kernel(const float* __restrict__ pts, const int* __restrict__ idx,
                     const float* __restrict__ w1, const float* __restrict__ b1,
                     const float* __restrict__ w2, const float* __restrict__ b2,
                     const float* __restrict__ w3, const float* __restrict__ b3,
                     float* __restrict__ h3out)
{
    __shared__ __align__(16) float cov[64 * 16];
    __shared__ __align__(16) float w1s[64 * 16];
    __shared__ __align__(16) float w2s[64 * 68];
    __shared__ __align__(16) float w3s[64 * 68];
    __shared__ __align__(16) float hA[64 * 68];
    __shared__ __align__(16) float hB[64 * 68];

    const int b = blockIdx.y, tid = threadIdx.x;
    const int n0 = blockIdx.x * 64;
    const int pq = tid >> 4, cq = tid & 15;

    for (int i = tid; i < 64 * 4; i += 256) {
        int p = i >> 2, k4 = i & 3;
        float4 v = make_float4(0.f, 0.f, 0.f, 0.f);
        if (k4 < 3) v = *(const float4*)(w1 + p * 12 + k4 * 4);
        ((float4*)(w1s + p * 16))[k4] = v;
    }
    for (int i = tid; i < 64 * 16; i += 256) {
        int p = i >> 4, k4 = i & 15;
        ((float4*)(w2s + p * 68))[k4] = ((const float4*)(w2 + p * 64))[k4];
        ((float4*)(w3s + p * 68))[k4] = ((const float4*)(w3 + p * 64))[k4];
    }
    if (tid < 64) {
        const int n = n0 + tid;
        const int* ip = idx + ((size_t)b * NPTS + n) * KNN;
        int j0 = ip[0], j1 = ip[1];
        const float* pb = pts + (size_t)b * 3 * NPTS;
        float px = pb[n],  py = pb[NPTS + n],  pz = pb[2 * NPTS + n];
        float ax = pb[j0], ay = pb[NPTS + j0], az = pb[2 * NPTS + j0];
        float bx = pb[j1], by = pb[NPTS + j1], bz = pb[2 * NPTS + j1];
        float* cv = cov + tid * 16;
        cv[0] = px; cv[1] = py; cv[2] = pz;
        cv[3] = ax * bx; cv[4]  = ax * by; cv[5]  = ax * bz;
        cv[6] = ay * bx; cv[7]  = ay * by; cv[8]  = ay * bz;
        cv[9] = az * bx; cv[10] = az * by; cv[11] = az * bz;
        cv[12] = 0.f; cv[13] = 0.f; cv[14] = 0.f; cv[15] = 0.f;
    }
    __syncthreads();

    {   // layer1: 12(16)->64
        float acc[4][4];
#pragma unroll
        for (int i = 0; i < 4; ++i)
#pragma unroll
            for (int j = 0; j < 4; ++j) acc[i][j] = 0.f;
        const float4* X4 = (const float4*)cov;
        const float4* W4 = (const float4*)w1s;
#pragma unroll
        for (int k4 = 0; k4 < 4; ++k4) {
            float4 xa[4], wb[4];
#pragma unroll
            for (int i = 0; i < 4; ++i) xa[i] = X4[(pq * 4 + i) * 4 + k4];
#pragma unroll
            for (int j = 0; j < 4; ++j) wb[j] = W4[(cq + 16 * j) * 4 + k4];
#pragma unroll
            for (int i = 0; i < 4; ++i)
#pragma unroll
                for (int j = 0; j < 4; ++j)
                    acc[i][j] += xa[i].x * wb[j].x + xa[i].y * wb[j].y
                               + xa[i].z * wb[j].z + xa[i].w * wb[j].w;
        }
#pragma unroll
        for (int j = 0; j < 4; ++j) {
            int c = cq + 16 * j;
            float bias = b1[c];
#pragma unroll
            for (int i = 0; i < 4; ++i)
                hA[(pq * 4 + i) * 68 + c] = relu_f(acc[i][j] + bias);
        }
    }
    __syncthreads();

    {   // layer2: 64->64
        float acc[4][4];
#pragma unroll
        for (int i = 0; i < 4; ++i)
#pragma unroll
            for (int j = 0; j < 4; ++j) acc[i][j] = 0.f;
        const float4* X4 = (const float4*)hA;
        const float4* W4 = (const float4*)w2s;
        for (int k4 = 0; k4 < 16; ++k4) {
            float4 xa[4], wb[4];
#pragma unroll
            for (int i = 0; i < 4; ++i) xa[i] = X4[(pq * 4 + i) * 17 + k4];
#pragma unroll
            for (int j = 0; j < 4; ++j) wb[j] = W4[(cq + 16 * j) * 17 + k4];
#pragma unroll
            for (int i = 0; i < 4; ++i)
#pragma unroll
                for (int j = 0; j < 4; ++j)
                    acc[i][j] += xa[i].x * wb[j].x + xa[i].y * wb[j].y
                               + xa[i].z * wb[j].z + xa[i].w * wb[j].w;
        }
#pragma unroll
        for (int j = 0; j < 4; ++j) {
            int c = cq + 16 * j;
            float bias = b2[c];
#pragma unroll
            for (int i = 0; i < 4; ++i)
                hB[(pq * 4 + i) * 68 + c] = relu_f(acc[i][j] + bias);
        }
    }
    __syncthreads();

    {   // layer3: 64->64 -> global
        float acc[4][4];
#pragma unroll
        for (int i = 0; i < 4; ++i)
#pragma unroll
            for (int j = 0; j < 4; ++j) acc[i][j] = 0.f;
        const float4* X4 = (const float4*)hB;
        const float4* W4 = (const float4*)w3s;
        for (int k4 = 0; k4 < 16; ++k4) {
            float4 xa[4], wb[4];
#pragma unroll
            for (int i = 0; i < 4; ++i) xa[i] = X4[(pq * 4 + i) * 17 + k4];
#pragma unroll
            for (int j = 0; j < 4; ++j) wb[j] = W4[(cq + 16 * j) * 17 + k4];
#pragma unroll
            for (int i = 0; i < 4; ++i)
#pragma unroll
                for (int j = 0; j < 4; ++j)
                    acc[i][j] += xa[i].x * wb[j].x + xa[i].y * wb[j].y
                               + xa[i].z * wb[j].z + xa[i].w * wb[j].w;
        }
#pragma unroll
        for (int j = 0; j < 4; ++j) {
            int c = cq + 16 * j;
            float bias = b3[c];
#pragma unroll
            for (int i = 0; i < 4; ++i)
                h3out[((size_t)b * NPTS + n0 + pq * 4 + i) * 64 + c] =
                    relu_f(acc[i][j] + bias);
        }
    }
}

// ---------------------------------------------------------------------------
// K3/K5: neighbor max-pool, float4 per thread. DV4 = D/4 (16 or 32).
// ---------------------------------------------------------------------------
template <int DV4>
__global__ __launch_bounds__(256)
void maxpool4_kernel(const float4* __restrict__ f, const int* __restrict__ idx,
                     float4* __restrict__ out)
{
    constexpr int SH = (DV4 == 16) ? 4 : 5;
    int t = blockIdx.x * 256 + threadIdx.x;
    int d4 = t & (DV4 - 1);
    int n  = (t >> SH) & (NPTS - 1);
    int b  = t >> (SH + 12);
    const int* ip = idx + ((size_t)b * NPTS + n) * KNN;
    const float4* fb = f + (size_t)b * NPTS * DV4;
    float4 v = make_float4(-FLT_MAX, -FLT_MAX, -FLT_MAX, -FLT_MAX);
#pragma unroll
    for (int k = 0; k < KNN; ++k) {
        float4 c = fb[(size_t)ip[k] * DV4 + d4];
        v.x = fmaxf(v.x, c.x); v.y = fmaxf(v.y, c.y);
        v.z = fmaxf(v.z, c.z); v.w = fmaxf(v.w, c.w);
    }
    out[t] = v;
}

// ---------------------------------------------------------------------------
// K4: t1 = L1(64->64) (no relu); y1 = relu(C1(64->128)) (unchanged)
// ---------------------------------------------------------------------------
__global__ __launch_bounds__(256)
void lin_conv1_kernel(const float* __restrict__ xin,
                      const float* __restrict__ l1w, const float* __restrict__ l1b,
                      const float* __restrict__ c1w, const float* __restrict__ c1b,
                      float* __restrict__ yout)
{
    __shared__ __align__(16) float sx[64 * 68];
    __shared__ __align__(16) float wbuf[64 * 68];
    __shared__ __align__(16) float t1[64 * 68];
    const int b = blockIdx.y, tid = threadIdx.x;
    const int n0 = blockIdx.x * 64;
    const int pq = tid >> 4, cq = tid & 15;

    for (int i = tid; i < 64 * 16; i += 256) {
        int p = i >> 4, k4 = i & 15;
        ((float4*)(sx + p * 68))[k4] =
            ((const float4*)(xin + ((size_t)b * NPTS + n0 + p) * 64))[k4];
        ((float4*)(wbuf + p * 68))[k4] = ((const float4*)(l1w + p * 64))[k4];
    }
    __syncthreads();

    {   // L1: 64->64, no relu, +bias -> t1
        float acc[4][4];
#pragma unroll
        for (int i = 0; i < 4; ++i)
#pragma unroll
            for (int j = 0; j < 4; ++j) acc[i][j] = 0.f;
        const float4* X4 = (const float4*)sx;
        const float4* W4 = (const float4*)wbuf;
        for (int k4 = 0; k4 < 16; ++k4) {
            float4 xa[4], wb[4];
#pragma unroll
            for (int i = 0; i < 4; ++i) xa[i] = X4[(pq * 4 + i) * 17 + k4];
#pragma unroll
            for (int j = 0; j < 4; ++j) wb[j] = W4[(cq + 16 * j) * 17 + k4];
#pragma unroll
            for (int i = 0; i < 4; ++i)
#pragma unroll
                for (int j = 0; j < 4; ++j)
                    acc[i][j] += xa[i].x * wb[j].x + xa[i].y * wb[j].y
                               + xa[i].z * wb[j].z + xa[i].w * wb[j].w;
        }
#pragma unroll
        for (int j = 0; j < 4; ++j) {
            int c = cq + 16 * j;
            float bias = l1b[c];
#pragma unroll
            for (int i = 0; i < 4; ++i)
                t1[(pq * 4 + i) * 68 + c] = acc[i][j] + bias;
        }
    }

    for (int g = 0; g < 2; ++g) {
        __syncthreads();
        for (int i = tid; i < 64 * 16; i += 256) {
            int p = i >> 4, k4 = i & 15;
            ((float4*)(wbuf + p * 68))[k4] =
                ((const float4*)(c1w + (size_t)(g * 64 + p) * 64))[k4];
        }
        __syncthreads();
        float acc[4][4];
#pragma unroll
        for (int i = 0; i < 4; ++i)
#pragma unroll
            for (int j = 0; j < 4; ++j) acc[i][j] = 0.f;
        const float4* X4 = (const float4*)t1;
        const float4* W4 = (const float4*)wbuf;
        for (int k4 = 0; k4 < 16; ++k4) {
            float4 xa[4], wb[4];
#pragma unroll
            for (int i = 0; i < 4; ++i) xa[i] = X4[(pq * 4 + i) * 17 + k4];
#pragma unroll
            for (int j = 0; j < 4; ++j) wb[j] = W4[(cq + 16 * j) * 17 + k4];
#pragma unroll
            for (int i = 0; i < 4; ++i)
#pragma unroll
                for (int j = 0; j < 4; ++j)
                    acc[i][j] += xa[i].x * wb[j].x + xa[i].y * wb[j].y
                               + xa[i].z * wb[j].z + xa[i].w * wb[j].w;
        }
#pragma unroll
        for (int j = 0; j < 4; ++j) {
            int c = g * 64 + cq + 16 * j;
            float bias = c1b[c];
#pragma unroll
            for (int i = 0; i < 4; ++i)
                yout[((size_t)b * NPTS + n0 + pq * 4 + i) * 128 + c] =
                    relu_f(acc[i][j] + bias);
        }
    }
}

// ---------------------------------------------------------------------------
// K6: t2 = L2(128->128) (no relu). grid (64, 2, 8), block 256. (unchanged)
// ---------------------------------------------------------------------------
__global__ __launch_bounds__(256)
void lin2_kernel(const float* __restrict__ xin, const float* __restrict__ w,
                 const float* __restrict__ bias, float* __restrict__ out)
{
    __shared__ __align__(16) float Xs[64 * 132];
    __shared__ __align__(16) float Ws[64 * 132];
    const int chunk = blockIdx.x, g = blockIdx.y, b = blockIdx.z;
    const int tid = threadIdx.x;

    for (int i = tid; i < 64 * 32; i += 256) {
        int p = i >> 5, k4 = i & 31;
        ((float4*)(Xs + p * 132))[k4] =
            ((const float4*)(xin + ((size_t)b * NPTS + chunk * 64 + p) * 128))[k4];
        ((float4*)(Ws + p * 132))[k4] =
            ((const float4*)(w + (size_t)(g * 64 + p) * 128))[k4];
    }
    __syncthreads();

    const int pq = tid >> 4, cq = tid & 15;
    const float4* X4 = (const float4*)Xs;
    const float4* W4 = (const float4*)Ws;
    float acc[4][4];
#pragma unroll
    for (int i = 0; i < 4; ++i)
#pragma unroll
        for (int j = 0; j < 4; ++j) acc[i][j] = 0.f;

    for (int k4 = 0; k4 < 32; ++k4) {
        float4 xa[4], wb[4];
#pragma unroll
        for (int i = 0; i < 4; ++i) xa[i] = X4[(pq * 4 + i) * 33 + k4];
#pragma unroll
        for (int j = 0; j < 4; ++j) wb[j] = W4[(cq + 16 * j) * 33 + k4];
#pragma unroll
        for (int i = 0; i < 4; ++i)
#pragma unroll
            for (int j = 0; j < 4; ++j)
                acc[i][j] += xa[i].x * wb[j].x + xa[i].y * wb[j].y
                           + xa[i].z * wb[j].z + xa[i].w * wb[j].w;
    }
#pragma unroll
    for (int j = 0; j < 4; ++j) {
        int c = g * 64 + cq + 16 * j;
        float bv = bias[c];
#pragma unroll
        for (int i = 0; i < 4; ++i)
            out[((size_t)b * NPTS + chunk * 64 + pq * 4 + i) * 128 + c] =
                acc[i][j] + bv;
    }
}

// ---------------------------------------------------------------------------
// K7: conv2 (128->1024) + per-block max over 128 points, 8x8 register tile
// with 2-deep k4 register double-buffer (load k4+1 while FMAing k4).
// grid (32 ptchunks, 8 chgroups, 8 batch), block 256 (16 pq x 16 cq).
// Final-step prefetch reads the pad element (in-bounds, unused).
// ---------------------------------------------------------------------------
__global__ __launch_bounds__(256)
void conv2max_kernel(const float* __restrict__ xin, const float* __restrict__ w,
                     const float* __restrict__ bias, float* __restrict__ pmax)
{
    __shared__ __align__(16) float Xs[128 * 68];
    __shared__ __align__(16) float Ws[128 * 68];
    const int chunk = blockIdx.x, g = blockIdx.y, b = blockIdx.z;
    const int tid = threadIdx.x;
    const int pq = tid >> 4, cq = tid & 15;

    float acc[8][8];
#pragma unroll
    for (int i = 0; i < 8; ++i)
#pragma unroll
        for (int j = 0; j < 8; ++j) acc[i][j] = 0.f;

    for (int h = 0; h < 2; ++h) {
        __syncthreads();   // protect previous-half LDS reads
        for (int i = tid; i < 128 * 16; i += 256) {
            int p = i >> 4, k4 = i & 15;
            ((float4*)(Xs + p * 68))[k4] = *(const float4*)
                (xin + ((size_t)b * NPTS + chunk * 128 + p) * 128 + h * 64 + k4 * 4);
            ((float4*)(Ws + p * 68))[k4] = *(const float4*)
                (w + (size_t)(g * 128 + p) * 128 + h * 64 + k4 * 4);
        }
        __syncthreads();

        const float4* X4 = (const float4*)Xs;   // row stride 17 float4
        const float4* W4 = (const float4*)Ws;

        float4 xA[8], wA[8], xB[8], wB[8];
#pragma unroll
        for (int i = 0; i < 8; ++i) {
            xA[i] = X4[(pq + 16 * i) * 17];
            wA[i] = W4[(cq + 16 * i) * 17];
        }
        for (int k4 = 0; k4 < 16; k4 += 2) {
#pragma unroll
            for (int i = 0; i < 8; ++i) {       // prefetch k4+1
                xB[i] = X4[(pq + 16 * i) * 17 + k4 + 1];
                wB[i] = W4[(cq + 16 * i) * 17 + k4 + 1];
            }
#pragma unroll
            for (int i = 0; i < 8; ++i)
#pragma unroll
                for (int j = 0; j < 8; ++j)
                    acc[i][j] += xA[i].x * wA[j].x + xA[i].y * wA[j].y
                               + xA[i].z * wA[j].z + xA[i].w * wA[j].w;
#pragma unroll
            for (int i = 0; i < 8; ++i) {       // prefetch k4+2 (pad on last)
                xA[i] = X4[(pq + 16 * i) * 17 + k4 + 2];
                wA[i] = W4[(cq + 16 * i) * 17 + k4 + 2];
            }
#pragma unroll
            for (int i = 0; i < 8; ++i)
#pragma unroll
                for (int j = 0; j < 8; ++j)
                    acc[i][j] += xB[i].x * wB[j].x + xB[i].y * wB[j].y
                               + xB[i].z * wB[j].z + xB[i].w * wB[j].w;
        }
    }

    // reduce max over the 128 points of this chunk
    __syncthreads();
    float* smax = Xs;                       // reuse: [16][132]
#pragma unroll
    for (int j = 0; j < 8; ++j) {
        float m = acc[0][j];
#pragma unroll
        for (int i = 1; i < 8; ++i) m = fmaxf(m, acc[i][j]);
        smax[pq * 132 + cq + 16 * j] = m;
    }
    __syncthreads();
    if (tid < 128) {
        float v = smax[tid];
#pragma unroll
        for (int q = 1; q < 16; ++q) v = fmaxf(v, smax[q * 132 + tid]);
        int c = g * 128 + tid;
        pmax[((size_t)b * 32 + chunk) * 1024 + c] = v + bias[c];
    }
}

// ---------------------------------------------------------------------------
// K8: reduce partial maxes over 32 chunks -> gmax [B][1024]
// ---------------------------------------------------------------------------
__global__ __launch_bounds__(256)
void gmax_kernel(const float* __restrict__ pmax, float* __restrict__ gmax)
{
    int t = blockIdx.x * 256 + threadIdx.x;
    int b = t >> 10, ch = t & 1023;
    const float* pp = pmax + (size_t)b * 32 * 1024 + ch;
    float v = -FLT_MAX;
    for (int c = 0; c < 32; ++c) v = fmaxf(v, pp[c * 1024]);
    gmax[t] = v;
}

// ---------------------------------------------------------------------------
// K9a/K9b: mlp2 split wide. grid (4, 8), block 128.
// ---------------------------------------------------------------------------
__global__ __launch_bounds__(128)
void mlp2a_kernel(const float* __restrict__ g, const float* __restrict__ w1,
                  const float* __restrict__ b1, float* __restrict__ h)
{
    __shared__ __align__(16) float sg[1024];
    const int b = blockIdx.y, tid = threadIdx.x;
    for (int i = tid; i < 1024; i += 128) sg[i] = g[b * 1024 + i];
    __syncthreads();
    const int ch = blockIdx.x * 128 + tid;
    const float4* xr = (const float4*)sg;
    const float4* wr = (const float4*)(w1 + (size_t)ch * 1024);
    float a0 = 0.f, a1 = 0.f, a2 = 0.f, a3 = 0.f;
    for (int k = 0; k < 256; ++k) {
        float4 w = wr[k], x = xr[k];
        a0 += w.x * x.x; a1 += w.y * x.y; a2 += w.z * x.z; a3 += w.w * x.w;
    }
    h[b * 512 + ch] = relu_f(b1[ch] + ((a0 + a1) + (a2 + a3)));
}

__global__ __launch_bounds__(128)
void mlp2b_kernel(const float* __restrict__ h, const float* __restrict__ w2,
                  const float* __restrict__ b2, float* __restrict__ out)
{
    __shared__ __align__(16) float sh[512];
    const int b = blockIdx.y, tid = threadIdx.x;
    for (int i = tid; i < 512; i += 128) sh[i] = h[b * 512 + i];
    __syncthreads();
    const int ch = blockIdx.x * 128 + tid;
    const float4* xr = (const float4*)sh;
    const float4* wr = (const float4*)(w2 + (size_t)ch * 512);
    float a0 = 0.f, a1 = 0.f, a2 = 0.f, a3 = 0.f;
    for (int k = 0; k < 128; ++k) {
        float4 w = wr[k], x = xr[k];
        a0 += w.x * x.x; a1 += w.y * x.y; a2 += w.z * x.z; a3 += w.w * x.w;
    }
    out[b * 512 + ch] = b2[ch] + ((a0 + a1) + (a2 + a3));
}

// ---------------------------------------------------------------------------
extern "C" void kernel_launch(void* const* d_in, const int* in_sizes, int n_in,
                              void* d_out, int out_size, void* d_ws, size_t ws_size,
                              hipStream_t stream)
{
    const float* pts  = (const float*)d_in[0];
    const float* m1w1 = (const float*)d_in[1];
    const float* m1b1 = (const float*)d_in[2];
    const float* m1w2 = (const float*)d_in[3];
    const float* m1b2 = (const float*)d_in[4];
    const float* m1w3 = (const float*)d_in[5];
    const float* m1b3 = (const float*)d_in[6];
    const float* l1w  = (const float*)d_in[7];
    const float* l1b  = (const float*)d_in[8];
    const float* c1w  = (const float*)d_in[9];
    const float* c1b  = (const float*)d_in[10];
    const float* l2w  = (const float*)d_in[11];
    const float* l2b  = (const float*)d_in[12];
    const float* c2w  = (const float*)d_in[13];
    const float* c2b  = (const float*)d_in[14];
    const float* m2w1 = (const float*)d_in[15];
    const float* m2b1 = (const float*)d_in[16];
    const float* m2w2 = (const float*)d_in[17];
    const float* m2b2 = (const float*)d_in[18];

    char* ws = (char*)d_ws;
    size_t off = 0;
    int*   idx   = (int*)(ws + off);   off += (size_t)NBATCH * NPTS * KNN * 4;
    float* h3    = (float*)(ws + off); off += (size_t)NBATCH * NPTS * 64 * 4;
    float* mp1   = (float*)(ws + off); off += (size_t)NBATCH * NPTS * 64 * 4;
    float* y1    = (float*)(ws + off); off += (size_t)NBATCH * NPTS * 128 * 4;
    float* mp2   = (float*)(ws + off); off += (size_t)NBATCH * NPTS * 128 * 4;
    float* pmaxb = (float*)(ws + off); off += (size_t)NBATCH * 64 * 1024 * 4;
    float* gmx   = (float*)(ws + off); off += (size_t)NBATCH * 1024 * 4;
    float* hbuf  = (float*)(ws + off); off += (size_t)NBATCH * 512 * 4;
    float* t2    = y1;  // y1 dead after maxpool128; reuse its space

    knn_kernel<<<dim3(NPTS / PPB, NBATCH), 256, 0, stream>>>(pts, idx);
    cov_mlp1_kernel<<<dim3(64, NBATCH), 256, 0, stream>>>(pts, idx, m1w1, m1b1,
                                                          m1w2, m1b2, m1w3, m1b3, h3);
    maxpool4_kernel<16><<<dim3(NBATCH * NPTS * 16 / 256), 256, 0, stream>>>(
        (const float4*)h3, idx, (float4*)mp1);
    lin_conv1_kernel<<<dim3(64, NBATCH), 256, 0, stream>>>(mp1, l1w, l1b, c1w, c1b, y1);
    maxpool4_kernel<32><<<dim3(NBATCH * NPTS * 32 / 256), 256, 0, stream>>>(
        (const float4*)y1, idx, (float4*)mp2);
    lin2_kernel<<<dim3(64, 2, NBATCH), 256, 0, stream>>>(mp2, l2w, l2b, t2);
    conv2max_kernel<<<dim3(32, 8, NBATCH), 256, 0, stream>>>(t2, c2w, c2b, pmaxb);
    gmax_kernel<<<dim3(32), 256, 0, stream>>>(pmaxb, gmx);
    mlp2a_kernel<<<dim3(4, NBATCH), 128, 0, stream>>>(gmx, m2w1, m2b1, hbuf);
    mlp2b_kernel<<<dim3(4, NBATCH), 128, 0, stream>>>(hbuf, m2w2, m2b2, (float*)d_out);
}

// Round 7
// 319.077 us; speedup vs baseline: 5.5334x; 1.0999x over previous
//
#include <hip/hip_runtime.h>
#include <cfloat>

#define NBATCH 8
#define NPTS   4096
#define KNN    16
#define PPB    32   // points per knn block
#define NSL    8    // j-slices per point
#define CAP    24   // pass-2 collection capacity per point

typedef unsigned short u16;
typedef __attribute__((ext_vector_type(8))) short short8;
typedef __attribute__((ext_vector_type(4))) float f32x4;

__device__ __forceinline__ float relu_f(float x) { return x > 0.f ? x : 0.f; }

// round-to-nearest-even bf16 split: x = hi + lo (+ O(2^-16 x))
__device__ __forceinline__ void bf16_split(float v, u16& hi, u16& lo)
{
    unsigned u = __float_as_uint(v);
    unsigned hb = (u + 0x7FFFu + ((u >> 16) & 1u)) >> 16;
    float hf = __uint_as_float(hb << 16);
    float l = v - hf;                      // exact (Sterbenz)
    unsigned ul = __float_as_uint(l);
    unsigned lb = (ul + 0x7FFFu + ((ul >> 16) & 1u)) >> 16;
    hi = (u16)hb; lo = (u16)lb;
}

// ---------------------------------------------------------------------------
// K1: KNN top-16, exact two-pass (top-8 med3 chain + safe threshold rescan
// with serial-scan fallback on CAP overflow). (unchanged from R6)
// ---------------------------------------------------------------------------
__global__ __launch_bounds__(256)
void knn_kernel(const float* __restrict__ pts, int* __restrict__ idxout)
{
    __shared__ __align__(16) float4 tile[NSL * 129];      // 16.5KB
    __shared__ float  kl[PPB * NSL * 8];                  // 8KB; aliased pass2
    __shared__ float  thr[PPB];
    __shared__ int    cnt[PPB];

    const int b = blockIdx.y, tid = threadIdx.x;
    const int ptl = tid >> 3, r = tid & 7;
    const int n = blockIdx.x * PPB + ptl;
    const float* pb = pts + (size_t)b * 3 * NPTS;

    const float sx = pb[n], sy = pb[NPTS + n], sz = pb[2 * NPTS + n];

    float k8[8];
#pragma unroll
    for (int s = 0; s < 8; ++s) k8[s] = -FLT_MAX;

    const float4* slice = tile + r * 129;

    for (int t = 0; t < 4; ++t) {
        if (t) __syncthreads();
        for (int i = tid; i < 1024; i += 256) {
            int j = t * 1024 + i;
            float x = pb[j], y = pb[NPTS + j], z = pb[2 * NPTS + j];
            float xx = __fadd_rn(__fadd_rn(__fmul_rn(x, x), __fmul_rn(y, y)),
                                 __fmul_rn(z, z));
            tile[(i >> 7) * 129 + (i & 127)] = make_float4(x, y, z, xx);
        }
        __syncthreads();
#pragma unroll 8
        for (int ii = 0; ii < 128; ++ii) {
            float4 c = slice[ii];
            float dt = __fmaf_rn(sx, c.x, __fmaf_rn(sy, c.y, __fmul_rn(sz, c.z)));
            float pd = __fmaf_rn(2.f, dt, -c.w);
            float old0 = k8[0];
#pragma unroll
            for (int s = 7; s >= 1; --s)
                k8[s] = __builtin_amdgcn_fmed3f(k8[s - 1], k8[s], pd);
            k8[0] = fmaxf(old0, pd);
        }
    }

#pragma unroll
    for (int s = 0; s < 8; ++s) kl[(ptl * NSL + r) * 8 + s] = k8[s];
    __syncthreads();

    if (r == 0) {
        const float* L = kl + ptl * 64;
        int p0 = 0, p1 = 0, p2 = 0, p3 = 0, p4 = 0, p5 = 0, p6 = 0, p7 = 0;
        float tv = 0.f;
        for (int o = 0; o < 16; ++o) {
            float v0 = (p0 < 8) ? L[p0]      : -FLT_MAX;
            float v1 = (p1 < 8) ? L[8 + p1]  : -FLT_MAX;
            float v2 = (p2 < 8) ? L[16 + p2] : -FLT_MAX;
            float v3 = (p3 < 8) ? L[24 + p3] : -FLT_MAX;
            float v4 = (p4 < 8) ? L[32 + p4] : -FLT_MAX;
            float v5 = (p5 < 8) ? L[40 + p5] : -FLT_MAX;
            float v6 = (p6 < 8) ? L[48 + p6] : -FLT_MAX;
            float v7 = (p7 < 8) ? L[56 + p7] : -FLT_MAX;
            float m = fmaxf(fmaxf(fmaxf(v0, v1), fmaxf(v2, v3)),
                            fmaxf(fmaxf(v4, v5), fmaxf(v6, v7)));
            tv = m;
            if      (v0 == m) ++p0;
            else if (v1 == m) ++p1;
            else if (v2 == m) ++p2;
            else if (v3 == m) ++p3;
            else if (v4 == m) ++p4;
            else if (v5 == m) ++p5;
            else if (v6 == m) ++p6;
            else              ++p7;
        }
        thr[ptl] = tv;
        cnt[ptl] = 0;
    }
    __syncthreads();
    const float myThr = thr[ptl];

    float* pv = kl;
    int*   pi = (int*)(kl + PPB * CAP);

    for (int tt = 0; tt < 4; ++tt) {
        int t = 3 - tt;
        if (tt) {
            __syncthreads();
            for (int i = tid; i < 1024; i += 256) {
                int j = t * 1024 + i;
                float x = pb[j], y = pb[NPTS + j], z = pb[2 * NPTS + j];
                float xx = __fadd_rn(__fadd_rn(__fmul_rn(x, x), __fmul_rn(y, y)),
                                     __fmul_rn(z, z));
                tile[(i >> 7) * 129 + (i & 127)] = make_float4(x, y, z, xx);
            }
            __syncthreads();
        }
#pragma unroll 8
        for (int ii = 0; ii < 128; ++ii) {
            float4 c = slice[ii];
            float dt = __fmaf_rn(sx, c.x, __fmaf_rn(sy, c.y, __fmul_rn(sz, c.z)));
            float pd = __fmaf_rn(2.f, dt, -c.w);
            if (pd >= myThr) {
                int pos = atomicAdd(&cnt[ptl], 1);
                if (pos < CAP) {
                    pv[ptl * CAP + pos] = pd;
                    pi[ptl * CAP + pos] = t * 1024 + r * 128 + ii;
                }
            }
        }
    }
    __syncthreads();

    if (tid < PPB) {
        const int np = blockIdx.x * PPB + tid;
        int* out = idxout + ((size_t)b * NPTS + np) * KNN;
        int c = cnt[tid];
        if (c <= CAP) {
            float* v  = pv + tid * CAP;
            int*   ix = pi + tid * CAP;
            for (int o = 0; o < 16; ++o) {
                int best = o;
                for (int q = o + 1; q < c; ++q) {
                    float vq = v[q], vb = v[best];
                    if (vq > vb || (vq == vb && ix[q] < ix[best])) best = q;
                }
                float tv = v[o]; v[o] = v[best]; v[best] = tv;
                int   ti = ix[o]; ix[o] = ix[best]; ix[best] = ti;
                out[o] = ix[o];
            }
        } else {
            float qx = pb[np], qy = pb[NPTS + np], qz = pb[2 * NPTS + np];
            float v16[16]; int i16[16];
#pragma unroll
            for (int s = 0; s < 16; ++s) { v16[s] = -FLT_MAX; i16[s] = 0; }
            for (int j = 0; j < NPTS; ++j) {
                float x = pb[j], y = pb[NPTS + j], z = pb[2 * NPTS + j];
                float xx = __fadd_rn(__fadd_rn(__fmul_rn(x, x), __fmul_rn(y, y)),
                                     __fmul_rn(z, z));
                float dt = __fmaf_rn(qx, x, __fmaf_rn(qy, y, __fmul_rn(qz, z)));
                float pd = __fmaf_rn(2.f, dt, -xx);
                if (pd > v16[15]) {
                    int s = 15;
                    while (s > 0 && pd > v16[s - 1]) {
                        v16[s] = v16[s - 1]; i16[s] = i16[s - 1]; --s;
                    }
                    v16[s] = pd; i16[s] = j;
                }
            }
            for (int o = 0; o < 16; ++o) out[o] = i16[o];
        }
    }
}

// ---------------------------------------------------------------------------
// K2: local_cov + mlp1 (12->64->64->64), weights in LDS, 4x4 tiles. (unchanged)
// ---------------------------------------------------------------------------
__global__ __launch_bounds__(256)
void cov_mlp1_kernel(const float* __restrict__ pts, const int* __restrict__ idx,
                     const float* __restrict__ w1, const float* __restrict__ b1,
                     const float* __restrict__ w2, const float* __restrict__ b2,
                     const float* __restrict__ w3, const float* __restrict__ b3,
                     float* __restrict__ h3out)
{
    __shared__ __align__(16) float cov[64 * 16];
    __shared__ __align__(16) float w1s[64 * 16];
    __shared__ __align__(16) float w2s[64 * 68];
    __shared__ __align__(16) float w3s[64 * 68];
    __shared__ __align__(16) float hA[64 * 68];
    __shared__ __align__(16) float hB[64 * 68];

    const int b = blockIdx.y, tid = threadIdx.x;
    const int n0 = blockIdx.x * 64;
    const int pq = tid >> 4, cq = tid & 15;

    for (int i = tid; i < 64 * 4; i += 256) {
        int p = i >> 2, k4 = i & 3;
        float4 v = make_float4(0.f, 0.f, 0.f, 0.f);
        if (k4 < 3) v = *(const float4*)(w1 + p * 12 + k4 * 4);
        ((float4*)(w1s + p * 16))[k4] = v;
    }
    for (int i = tid; i < 64 * 16; i += 256) {
        int p = i >> 4, k4 = i & 15;
        ((float4*)(w2s + p * 68))[k4] = ((const float4*)(w2 + p * 64))[k4];
        ((float4*)(w3s + p * 68))[k4] = ((const float4*)(w3 + p * 64))[k4];
    }
    if (tid < 64) {
        const int n = n0 + tid;
        const int* ip = idx + ((size_t)b * NPTS + n) * KNN;
        int j0 = ip[0], j1 = ip[1];
        const float* pb = pts + (size_t)b * 3 * NPTS;
        float px = pb[n],  py = pb[NPTS + n],  pz = pb[2 * NPTS + n];
        float ax = pb[j0], ay = pb[NPTS + j0], az = pb[2 * NPTS + j0];
        float bx = pb[j1], by = pb[NPTS + j1], bz = pb[2 * NPTS + j1];
        float* cv = cov + tid * 16;
        cv[0] = px; cv[1] = py; cv[2] = pz;
        cv[3] = ax * bx; cv[4]  = ax * by; cv[5]  = ax * bz;
        cv[6] = ay * bx; cv[7]  = ay * by; cv[8]  = ay * bz;
        cv[9] = az * bx; cv[10] = az * by; cv[11] = az * bz;
        cv[12] = 0.f; cv[13] = 0.f; cv[14] = 0.f; cv[15] = 0.f;
    }
    __syncthreads();

    {   // layer1: 12(16)->64
        float acc[4][4];
#pragma unroll
        for (int i = 0; i < 4; ++i)
#pragma unroll
            for (int j = 0; j < 4; ++j) acc[i][j] = 0.f;
        const float4* X4 = (const float4*)cov;
        const float4* W4 = (const float4*)w1s;
#pragma unroll
        for (int k4 = 0; k4 < 4; ++k4) {
            float4 xa[4], wb[4];
#pragma unroll
            for (int i = 0; i < 4; ++i) xa[i] = X4[(pq * 4 + i) * 4 + k4];
#pragma unroll
            for (int j = 0; j < 4; ++j) wb[j] = W4[(cq + 16 * j) * 4 + k4];
#pragma unroll
            for (int i = 0; i < 4; ++i)
#pragma unroll
                for (int j = 0; j < 4; ++j)
                    acc[i][j] += xa[i].x * wb[j].x + xa[i].y * wb[j].y
                               + xa[i].z * wb[j].z + xa[i].w * wb[j].w;
        }
#pragma unroll
        for (int j = 0; j < 4; ++j) {
            int c = cq + 16 * j;
            float bias = b1[c];
#pragma unroll
            for (int i = 0; i < 4; ++i)
                hA[(pq * 4 + i) * 68 + c] = relu_f(acc[i][j] + bias);
        }
    }
    __syncthreads();

    {   // layer2: 64->64
        float acc[4][4];
#pragma unroll
        for (int i = 0; i < 4; ++i)
#pragma unroll
            for (int j = 0; j < 4; ++j) acc[i][j] = 0.f;
        const float4* X4 = (const float4*)hA;
        const float4* W4 = (const float4*)w2s;
        for (int k4 = 0; k4 < 16; ++k4) {
            float4 xa[4], wb[4];
#pragma unroll
            for (int i = 0; i < 4; ++i) xa[i] = X4[(pq * 4 + i) * 17 + k4];
#pragma unroll
            for (int j = 0; j < 4; ++j) wb[j] = W4[(cq + 16 * j) * 17 + k4];
#pragma unroll
            for (int i = 0; i < 4; ++i)
#pragma unroll
                for (int j = 0; j < 4; ++j)
                    acc[i][j] += xa[i].x * wb[j].x + xa[i].y * wb[j].y
                               + xa[i].z * wb[j].z + xa[i].w * wb[j].w;
        }
#pragma unroll
        for (int j = 0; j < 4; ++j) {
            int c = cq + 16 * j;
            float bias = b2[c];
#pragma unroll
            for (int i = 0; i < 4; ++i)
                hB[(pq * 4 + i) * 68 + c] = relu_f(acc[i][j] + bias);
        }
    }
    __syncthreads();

    {   // layer3: 64->64 -> global
        float acc[4][4];
#pragma unroll
        for (int i = 0; i < 4; ++i)
#pragma unroll
            for (int j = 0; j < 4; ++j) acc[i][j] = 0.f;
        const float4* X4 = (const float4*)hB;
        const float4* W4 = (const float4*)w3s;
        for (int k4 = 0; k4 < 16; ++k4) {
            float4 xa[4], wb[4];
#pragma unroll
            for (int i = 0; i < 4; ++i) xa[i] = X4[(pq * 4 + i) * 17 + k4];
#pragma unroll
            for (int j = 0; j < 4; ++j) wb[j] = W4[(cq + 16 * j) * 17 + k4];
#pragma unroll
            for (int i = 0; i < 4; ++i)
#pragma unroll
                for (int j = 0; j < 4; ++j)
                    acc[i][j] += xa[i].x * wb[j].x + xa[i].y * wb[j].y
                               + xa[i].z * wb[j].z + xa[i].w * wb[j].w;
        }
#pragma unroll
        for (int j = 0; j < 4; ++j) {
            int c = cq + 16 * j;
            float bias = b3[c];
#pragma unroll
            for (int i = 0; i < 4; ++i)
                h3out[((size_t)b * NPTS + n0 + pq * 4 + i) * 64 + c] =
                    relu_f(acc[i][j] + bias);
        }
    }
}

// ---------------------------------------------------------------------------
// K3/K5: neighbor max-pool, float4 per thread. DV4 = D/4 (16 or 32).
// ---------------------------------------------------------------------------
template <int DV4>
__global__ __launch_bounds__(256)
void maxpool4_kernel(const float4* __restrict__ f, const int* __restrict__ idx,
                     float4* __restrict__ out)
{
    constexpr int SH = (DV4 == 16) ? 4 : 5;
    int t = blockIdx.x * 256 + threadIdx.x;
    int d4 = t & (DV4 - 1);
    int n  = (t >> SH) & (NPTS - 1);
    int b  = t >> (SH + 12);
    const int* ip = idx + ((size_t)b * NPTS + n) * KNN;
    const float4* fb = f + (size_t)b * NPTS * DV4;
    float4 v = make_float4(-FLT_MAX, -FLT_MAX, -FLT_MAX, -FLT_MAX);
#pragma unroll
    for (int k = 0; k < KNN; ++k) {
        float4 c = fb[(size_t)ip[k] * DV4 + d4];
        v.x = fmaxf(v.x, c.x); v.y = fmaxf(v.y, c.y);
        v.z = fmaxf(v.z, c.z); v.w = fmaxf(v.w, c.w);
    }
    out[t] = v;
}

// ---------------------------------------------------------------------------
// K4: t1 = L1(64->64) (no relu); y1 = relu(C1(64->128)) (unchanged)
// ---------------------------------------------------------------------------
__global__ __launch_bounds__(256)
void lin_conv1_kernel(const float* __restrict__ xin,
                      const float* __restrict__ l1w, const float* __restrict__ l1b,
                      const float* __restrict__ c1w, const float* __restrict__ c1b,
                      float* __restrict__ yout)
{
    __shared__ __align__(16) float sx[64 * 68];
    __shared__ __align__(16) float wbuf[64 * 68];
    __shared__ __align__(16) float t1[64 * 68];
    const int b = blockIdx.y, tid = threadIdx.x;
    const int n0 = blockIdx.x * 64;
    const int pq = tid >> 4, cq = tid & 15;

    for (int i = tid; i < 64 * 16; i += 256) {
        int p = i >> 4, k4 = i & 15;
        ((float4*)(sx + p * 68))[k4] =
            ((const float4*)(xin + ((size_t)b * NPTS + n0 + p) * 64))[k4];
        ((float4*)(wbuf + p * 68))[k4] = ((const float4*)(l1w + p * 64))[k4];
    }
    __syncthreads();

    {   // L1: 64->64, no relu, +bias -> t1
        float acc[4][4];
#pragma unroll
        for (int i = 0; i < 4; ++i)
#pragma unroll
            for (int j = 0; j < 4; ++j) acc[i][j] = 0.f;
        const float4* X4 = (const float4*)sx;
        const float4* W4 = (const float4*)wbuf;
        for (int k4 = 0; k4 < 16; ++k4) {
            float4 xa[4], wb[4];
#pragma unroll
            for (int i = 0; i < 4; ++i) xa[i] = X4[(pq * 4 + i) * 17 + k4];
#pragma unroll
            for (int j = 0; j < 4; ++j) wb[j] = W4[(cq + 16 * j) * 17 + k4];
#pragma unroll
            for (int i = 0; i < 4; ++i)
#pragma unroll
                for (int j = 0; j < 4; ++j)
                    acc[i][j] += xa[i].x * wb[j].x + xa[i].y * wb[j].y
                               + xa[i].z * wb[j].z + xa[i].w * wb[j].w;
        }
#pragma unroll
        for (int j = 0; j < 4; ++j) {
            int c = cq + 16 * j;
            float bias = l1b[c];
#pragma unroll
            for (int i = 0; i < 4; ++i)
                t1[(pq * 4 + i) * 68 + c] = acc[i][j] + bias;
        }
    }

    for (int g = 0; g < 2; ++g) {
        __syncthreads();
        for (int i = tid; i < 64 * 16; i += 256) {
            int p = i >> 4, k4 = i & 15;
            ((float4*)(wbuf + p * 68))[k4] =
                ((const float4*)(c1w + (size_t)(g * 64 + p) * 64))[k4];
        }
        __syncthreads();
        float acc[4][4];
#pragma unroll
        for (int i = 0; i < 4; ++i)
#pragma unroll
            for (int j = 0; j < 4; ++j) acc[i][j] = 0.f;
        const float4* X4 = (const float4*)t1;
        const float4* W4 = (const float4*)wbuf;
        for (int k4 = 0; k4 < 16; ++k4) {
            float4 xa[4], wb[4];
#pragma unroll
            for (int i = 0; i < 4; ++i) xa[i] = X4[(pq * 4 + i) * 17 + k4];
#pragma unroll
            for (int j = 0; j < 4; ++j) wb[j] = W4[(cq + 16 * j) * 17 + k4];
#pragma unroll
            for (int i = 0; i < 4; ++i)
#pragma unroll
                for (int j = 0; j < 4; ++j)
                    acc[i][j] += xa[i].x * wb[j].x + xa[i].y * wb[j].y
                               + xa[i].z * wb[j].z + xa[i].w * wb[j].w;
        }
#pragma unroll
        for (int j = 0; j < 4; ++j) {
            int c = g * 64 + cq + 16 * j;
            float bias = c1b[c];
#pragma unroll
            for (int i = 0; i < 4; ++i)
                yout[((size_t)b * NPTS + n0 + pq * 4 + i) * 128 + c] =
                    relu_f(acc[i][j] + bias);
        }
    }
}

// ---------------------------------------------------------------------------
// K6: t2 = L2(128->128) (no relu), emitted as bf16 hi/lo split pair.
// grid (64, 2, 8), block 256.
// ---------------------------------------------------------------------------
__global__ __launch_bounds__(256)
void lin2_kernel(const float* __restrict__ xin, const float* __restrict__ w,
                 const float* __restrict__ bias,
                 u16* __restrict__ xhi, u16* __restrict__ xlo)
{
    __shared__ __align__(16) float Xs[64 * 132];
    __shared__ __align__(16) float Ws[64 * 132];
    const int chunk = blockIdx.x, g = blockIdx.y, b = blockIdx.z;
    const int tid = threadIdx.x;

    for (int i = tid; i < 64 * 32; i += 256) {
        int p = i >> 5, k4 = i & 31;
        ((float4*)(Xs + p * 132))[k4] =
            ((const float4*)(xin + ((size_t)b * NPTS + chunk * 64 + p) * 128))[k4];
        ((float4*)(Ws + p * 132))[k4] =
            ((const float4*)(w + (size_t)(g * 64 + p) * 128))[k4];
    }
    __syncthreads();

    const int pq = tid >> 4, cq = tid & 15;
    const float4* X4 = (const float4*)Xs;
    const float4* W4 = (const float4*)Ws;
    float acc[4][4];
#pragma unroll
    for (int i = 0; i < 4; ++i)
#pragma unroll
        for (int j = 0; j < 4; ++j) acc[i][j] = 0.f;

    for (int k4 = 0; k4 < 32; ++k4) {
        float4 xa[4], wb[4];
#pragma unroll
        for (int i = 0; i < 4; ++i) xa[i] = X4[(pq * 4 + i) * 33 + k4];
#pragma unroll
        for (int j = 0; j < 4; ++j) wb[j] = W4[(cq + 16 * j) * 33 + k4];
#pragma unroll
        for (int i = 0; i < 4; ++i)
#pragma unroll
            for (int j = 0; j < 4; ++j)
                acc[i][j] += xa[i].x * wb[j].x + xa[i].y * wb[j].y
                           + xa[i].z * wb[j].z + xa[i].w * wb[j].w;
    }
#pragma unroll
    for (int j = 0; j < 4; ++j) {
        int c = g * 64 + cq + 16 * j;
        float bv = bias[c];
#pragma unroll
        for (int i = 0; i < 4; ++i) {
            float v = acc[i][j] + bv;
            size_t oidx = ((size_t)b * NPTS + chunk * 64 + pq * 4 + i) * 128 + c;
            u16 h, l;
            bf16_split(v, h, l);
            xhi[oidx] = h; xlo[oidx] = l;
        }
    }
}

// ---------------------------------------------------------------------------
// K6b: split c2w (1024x128 f32) into bf16 hi/lo. One-time, tiny.
// ---------------------------------------------------------------------------
__global__ __launch_bounds__(256)
void wsplit_kernel(const float* __restrict__ w, u16* __restrict__ whi,
                   u16* __restrict__ wlo)
{
    int t = blockIdx.x * 256 + threadIdx.x;   // 0 .. 131071
    u16 h, l;
    bf16_split(w[t], h, l);
    whi[t] = h; wlo[t] = l;
}

// ---------------------------------------------------------------------------
// K7: conv2 (128->1024) via split-bf16 MFMA (Whi*Xhi + Whi*Xlo + Wlo*Xhi),
// fused max over 128 points. grid (32 ptchunks, 8 chgroups, 8 batch),
// block 256 = 4 waves; each wave computes a 64ch x 64pt quadrant as
// 4x4 mfma_f32_16x16x32_bf16 tiles over K=128 (4 k-blocks).
// LDS layout per buffer: [16 k-seg][128 row][8 bf16] -- conflict-free
// ds_read_b128 fragment loads, no padding. 4 buffers = 128 KB.
// A/B loaded with identical k-convention, so any HW k-permutation cancels.
// C/D: col(point)=lane&15, row(ch)=4*(lane>>4)+reg  [m89-verified].
// ---------------------------------------------------------------------------
__global__ __launch_bounds__(256)
void conv2max_mfma(const u16* __restrict__ xhi, const u16* __restrict__ xlo,
                   const u16* __restrict__ whi, const u16* __restrict__ wlo,
                   const float* __restrict__ bias, float* __restrict__ pmax)
{
    __shared__ __align__(16) u16 lds[4 * 16384];   // 128 KB
    u16* Wh = lds;
    u16* Wl = lds + 16384;
    u16* Xh = lds + 2 * 16384;
    u16* Xl = lds + 3 * 16384;

    const int chunk = blockIdx.x, g = blockIdx.y, b = blockIdx.z;
    const int tid = threadIdx.x;
    const int lane = tid & 63, wave = tid >> 6;
    const int l15 = lane & 15, l4 = lane >> 4;
    const int wm = wave >> 1, wn = wave & 1;     // 2x2 wave grid (M x N)

    const u16* wh_g = whi + (size_t)g * 128 * 128;
    const u16* wl_g = wlo + (size_t)g * 128 * 128;
    const u16* xh_g = xhi + ((size_t)b * NPTS + chunk * 128) * 128;
    const u16* xl_g = xlo + ((size_t)b * NPTS + chunk * 128) * 128;

    // stage: global [row][128] -> LDS [seg][row][8]
    for (int u = tid; u < 2048; u += 256) {
        int row = u & 127, seg = u >> 7;
        int lo_ = seg * 1024 + row * 8;
        int go_ = row * 128 + seg * 8;
        *(short8*)&Wh[lo_] = *(const short8*)&wh_g[go_];
        *(short8*)&Wl[lo_] = *(const short8*)&wl_g[go_];
        *(short8*)&Xh[lo_] = *(const short8*)&xh_g[go_];
        *(short8*)&Xl[lo_] = *(const short8*)&xl_g[go_];
    }
    __syncthreads();

    f32x4 acc[4][4];
#pragma unroll
    for (int mt = 0; mt < 4; ++mt)
#pragma unroll
        for (int nt = 0; nt < 4; ++nt)
            acc[mt][nt] = (f32x4){0.f, 0.f, 0.f, 0.f};

    for (int kb = 0; kb < 4; ++kb) {
        const int seg = kb * 4 + l4;             // k = seg*8 + j
        short8 Ah[4], Al[4], Bh[4], Bl[4];
#pragma unroll
        for (int mt = 0; mt < 4; ++mt) {
            int off = seg * 1024 + (wm * 64 + mt * 16 + l15) * 8;
            Ah[mt] = *(const short8*)&Wh[off];
            Al[mt] = *(const short8*)&Wl[off];
        }
#pragma unroll
        for (int nt = 0; nt < 4; ++nt) {
            int off = seg * 1024 + (wn * 64 + nt * 16 + l15) * 8;
            Bh[nt] = *(const short8*)&Xh[off];
            Bl[nt] = *(const short8*)&Xl[off];
        }
#pragma unroll
        for (int mt = 0; mt < 4; ++mt)
#pragma unroll
            for (int nt = 0; nt < 4; ++nt) {
                acc[mt][nt] = __builtin_amdgcn_mfma_f32_16x16x32_bf16(
                    Ah[mt], Bh[nt], acc[mt][nt], 0, 0, 0);
                acc[mt][nt] = __builtin_amdgcn_mfma_f32_16x16x32_bf16(
                    Ah[mt], Bl[nt], acc[mt][nt], 0, 0, 0);
                acc[mt][nt] = __builtin_amdgcn_mfma_f32_16x16x32_bf16(
                    Al[mt], Bh[nt], acc[mt][nt], 0, 0, 0);
            }
    }

    __syncthreads();                 // all frag reads done; reuse LDS
    float* smax = (float*)lds;       // [128 ch][33 cols]
#pragma unroll
    for (int mt = 0; mt < 4; ++mt)
#pragma unroll
        for (int r = 0; r < 4; ++r) {
            float m = fmaxf(fmaxf(acc[mt][0][r], acc[mt][1][r]),
                            fmaxf(acc[mt][2][r], acc[mt][3][r]));
            int c = wm * 64 + mt * 16 + 4 * l4 + r;
            smax[c * 33 + wn * 16 + l15] = m;
        }
    __syncthreads();
    if (tid < 128) {
        const float* row = smax + tid * 33;
        float v = row[0];
#pragma unroll
        for (int j = 1; j < 32; ++j) v = fmaxf(v, row[j]);
        int c = g * 128 + tid;
        pmax[((size_t)b * 32 + chunk) * 1024 + c] = v + bias[c];
    }
}

// ---------------------------------------------------------------------------
// K8: reduce partial maxes over 32 chunks -> gmax [B][1024]
// ---------------------------------------------------------------------------
__global__ __launch_bounds__(256)
void gmax_kernel(const float* __restrict__ pmax, float* __restrict__ gmax)
{
    int t = blockIdx.x * 256 + threadIdx.x;
    int b = t >> 10, ch = t & 1023;
    const float* pp = pmax + (size_t)b * 32 * 1024 + ch;
    float v = -FLT_MAX;
    for (int c = 0; c < 32; ++c) v = fmaxf(v, pp[c * 1024]);
    gmax[t] = v;
}

// ---------------------------------------------------------------------------
// K9a/K9b: mlp2 split wide. grid (4, 8), block 128.
// ---------------------------------------------------------------------------
__global__ __launch_bounds__(128)
void mlp2a_kernel(const float* __restrict__ g, const float* __restrict__ w1,
                  const float* __restrict__ b1, float* __restrict__ h)
{
    __shared__ __align__(16) float sg[1024];
    const int b = blockIdx.y, tid = threadIdx.x;
    for (int i = tid; i < 1024; i += 128) sg[i] = g[b * 1024 + i];
    __syncthreads();
    const int ch = blockIdx.x * 128 + tid;
    const float4* xr = (const float4*)sg;
    const float4* wr = (const float4*)(w1 + (size_t)ch * 1024);
    float a0 = 0.f, a1 = 0.f, a2 = 0.f, a3 = 0.f;
    for (int k = 0; k < 256; ++k) {
        float4 w = wr[k], x = xr[k];
        a0 += w.x * x.x; a1 += w.y * x.y; a2 += w.z * x.z; a3 += w.w * x.w;
    }
    h[b * 512 + ch] = relu_f(b1[ch] + ((a0 + a1) + (a2 + a3)));
}

__global__ __launch_bounds__(128)
void mlp2b_kernel(const float* __restrict__ h, const float* __restrict__ w2,
                  const float* __restrict__ b2, float* __restrict__ out)
{
    __shared__ __align__(16) float sh[512];
    const int b = blockIdx.y, tid = threadIdx.x;
    for (int i = tid; i < 512; i += 128) sh[i] = h[b * 512 + i];
    __syncthreads();
    const int ch = blockIdx.x * 128 + tid;
    const float4* xr = (const float4*)sh;
    const float4* wr = (const float4*)(w2 + (size_t)ch * 512);
    float a0 = 0.f, a1 = 0.f, a2 = 0.f, a3 = 0.f;
    for (int k = 0; k < 128; ++k) {
        float4 w = wr[k], x = xr[k];
        a0 += w.x * x.x; a1 += w.y * x.y; a2 += w.z * x.z; a3 += w.w * x.w;
    }
    out[b * 512 + ch] = b2[ch] + ((a0 + a1) + (a2 + a3));
}

// ---------------------------------------------------------------------------
extern "C" void kernel_launch(void* const* d_in, const int* in_sizes, int n_in,
                              void* d_out, int out_size, void* d_ws, size_t ws_size,
                              hipStream_t stream)
{
    const float* pts  = (const float*)d_in[0];
    const float* m1w1 = (const float*)d_in[1];
    const float* m1b1 = (const float*)d_in[2];
    const float* m1w2 = (const float*)d_in[3];
    const float* m1b2 = (const float*)d_in[4];
    const float* m1w3 = (const float*)d_in[5];
    const float* m1b3 = (const float*)d_in[6];
    const float* l1w  = (const float*)d_in[7];
    const float* l1b  = (const float*)d_in[8];
    const float* c1w  = (const float*)d_in[9];
    const float* c1b  = (const float*)d_in[10];
    const float* l2w  = (const float*)d_in[11];
    const float* l2b  = (const float*)d_in[12];
    const float* c2w  = (const float*)d_in[13];
    const float* c2b  = (const float*)d_in[14];
    const float* m2w1 = (const float*)d_in[15];
    const float* m2b1 = (const float*)d_in[16];
    const float* m2w2 = (const float*)d_in[17];
    const float* m2b2 = (const float*)d_in[18];

    char* ws = (char*)d_ws;
    size_t off = 0;
    int*   idx   = (int*)(ws + off);   off += (size_t)NBATCH * NPTS * KNN * 4;
    float* h3    = (float*)(ws + off); off += (size_t)NBATCH * NPTS * 64 * 4;
    float* mp1   = (float*)(ws + off); off += (size_t)NBATCH * NPTS * 64 * 4;
    float* y1    = (float*)(ws + off); off += (size_t)NBATCH * NPTS * 128 * 4;
    float* mp2   = (float*)(ws + off); off += (size_t)NBATCH * NPTS * 128 * 4;
    float* pmaxb = (float*)(ws + off); off += (size_t)NBATCH * 64 * 1024 * 4;
    float* gmx   = (float*)(ws + off); off += (size_t)NBATCH * 1024 * 4;
    float* hbuf  = (float*)(ws + off); off += (size_t)NBATCH * 512 * 4;
    u16*   whi   = (u16*)(ws + off);   off += (size_t)1024 * 128 * 2;
    u16*   wlo   = (u16*)(ws + off);   off += (size_t)1024 * 128 * 2;
    // xhi/xlo alias y1 (dead after maxpool<32>): 8 MB + 8 MB = y1's 16 MB
    u16*   xhi   = (u16*)y1;
    u16*   xlo   = (u16*)((char*)y1 + (size_t)NBATCH * NPTS * 128 * 2);

    wsplit_kernel<<<dim3(512), 256, 0, stream>>>(c2w, whi, wlo);
    knn_kernel<<<dim3(NPTS / PPB, NBATCH), 256, 0, stream>>>(pts, idx);
    cov_mlp1_kernel<<<dim3(64, NBATCH), 256, 0, stream>>>(pts, idx, m1w1, m1b1,
                                                          m1w2, m1b2, m1w3, m1b3, h3);
    maxpool4_kernel<16><<<dim3(NBATCH * NPTS * 16 / 256), 256, 0, stream>>>(
        (const float4*)h3, idx, (float4*)mp1);
    lin_conv1_kernel<<<dim3(64, NBATCH), 256, 0, stream>>>(mp1, l1w, l1b, c1w, c1b, y1);
    maxpool4_kernel<32><<<dim3(NBATCH * NPTS * 32 / 256), 256, 0, stream>>>(
        (const float4*)y1, idx, (float4*)mp2);
    lin2_kernel<<<dim3(64, 2, NBATCH), 256, 0, stream>>>(mp2, l2w, l2b, xhi, xlo);
    conv2max_mfma<<<dim3(32, 8, NBATCH), 256, 0, stream>>>(xhi, xlo, whi, wlo,
                                                           c2b, pmaxb);
    gmax_kernel<<<dim3(32), 256, 0, stream>>>(pmaxb, gmx);
    mlp2a_kernel<<<dim3(4, NBATCH), 128, 0, stream>>>(gmx, m2w1, m2b1, hbuf);
    mlp2b_kernel<<<dim3(4, NBATCH), 128, 0, stream>>>(hbuf, m2w2, m2b2, (float*)d_out);
}